// Round 4
// baseline (9744.025 us; speedup 1.0000x reference)
//
#include <hip/hip_runtime.h>
#include <hip/hip_bf16.h>

// Money_former MLA DINT — round 4: OUTPUT DTYPE FIX (d_out is float32, not bf16).
// Pipeline = round-2 optimized kernels (proven numerically identical to the
// all-naive round-3 rewrite). T=2056, D=512, 2 layers, 16 logical heads of 48.

#define Tn 2056
#define LPn 257
#define Dn 512

static constexpr float SCALING_C = 0.14433756729740643f;   // 48^-0.5
static constexpr float EPS_C     = 1.1920928955078125e-07f;

// ---------------- sentinel ----------------
__global__ __launch_bounds__(256) void k_fill42(float* __restrict__ out, int n) {
  int i = blockIdx.x * 256 + threadIdx.x;
  if (i < n) out[i] = 42.0f;
}

// ---------------- RoPE tables ----------------
__global__ __launch_bounds__(256) void k_freqs(float* __restrict__ cosb, float* __restrict__ sinb) {
  int idx = blockIdx.x * 256 + threadIdx.x;
  if (idx >= 256 * 8) return;
  int pos = idx >> 3, j = idx & 7;
  float fb = powf(10000.f, -(float)j * 0.125f);            // 1/10000^(j/8)
  float ramp = fminf(fmaxf((float)j * 0.25f, 0.f), 1.f);   // low=0, high=4
  float sm = 1.f - ramp;
  float fr = fb * (1.f / 40.f) * (1.f - sm) + fb * sm;
  float ang = (float)pos * fr;
  cosb[idx] = cosf(ang);
  sinb[idx] = sinf(ang);
}

// ---------------- Embedding ----------------
__global__ __launch_bounds__(256) void k_embed(const float* __restrict__ x,
                                               const float* __restrict__ ticker_emb,
                                               const float* __restrict__ sep_emb,
                                               const float* __restrict__ shared_W,
                                               const float* __restrict__ unique_W,
                                               const int* __restrict__ sep_idx,
                                               const int* __restrict__ tickers,
                                               float* __restrict__ h) {
  int t = blockIdx.x;
  int c = blockIdx.y * 256 + threadIdx.x;
  int l = t >> 3, s = t & 7;
  float val;
  if (l == 0) {
    val = sep_emb[sep_idx[0] * Dn + c];
  } else {
    const float* xr = x + ((size_t)(l - 1) * 8 + s) * 32;
    const float* w = (c < 384) ? (shared_W + (size_t)c * 32)
                               : (unique_W + ((size_t)s * 128 + (c - 384)) * 32);
    float acc = 0.f;
#pragma unroll
    for (int f = 0; f < 32; f++) acc = fmaf(xr[f], w[f], acc);
    val = acc;
  }
  val += ticker_emb[(size_t)tickers[s] * Dn + c];
  h[(size_t)t * Dn + c] = val;
}

// ---------------- Generic row RMSNorm (in-place safe) ----------------
__global__ __launch_bounds__(256) void k_rmsnorm(const float* __restrict__ in,
                                                 const float* __restrict__ w,
                                                 float* __restrict__ out,
                                                 int ncols, int in_stride, float eps) {
  int row = blockIdx.x;
  const float* xr = in + (size_t)row * in_stride;
  float ss = 0.f;
  for (int c = threadIdx.x; c < ncols; c += 256) { float v = xr[c]; ss = fmaf(v, v, ss); }
  for (int off = 1; off < 64; off <<= 1) ss += __shfl_xor(ss, off);
  __shared__ float red[4];
  if ((threadIdx.x & 63) == 0) red[threadIdx.x >> 6] = ss;
  __syncthreads();
  float tot = red[0] + red[1] + red[2] + red[3];
  float scale = rsqrtf(tot / (float)ncols + eps);
  for (int c = threadIdx.x; c < ncols; c += 256)
    out[(size_t)row * ncols + c] = xr[c] * scale * w[c];
}

// ---------------- Tiled GEMM: C[M,N] (+)= A[M,K] @ B[N,K]^T ----------------
template <int MODE>
__global__ __launch_bounds__(256) void k_gemm(const float* __restrict__ A,
                                              const float* __restrict__ B,
                                              float* __restrict__ C,
                                              int M, int N, int K) {
  __shared__ float As[64][17];
  __shared__ float Bs[64][17];
  int bm = blockIdx.y * 64, bn = blockIdx.x * 64;
  int tx = threadIdx.x & 15, ty = threadIdx.x >> 4;
  float acc[4][4] = {};
  for (int k0 = 0; k0 < K; k0 += 16) {
    for (int i = threadIdx.x; i < 1024; i += 256) {
      int m = i >> 4, kk = i & 15;
      int gm = bm + m;
      As[m][kk] = (gm < M) ? A[(size_t)gm * K + k0 + kk] : 0.f;
      int gn = bn + m;
      Bs[m][kk] = (gn < N) ? B[(size_t)gn * K + k0 + kk] : 0.f;
    }
    __syncthreads();
#pragma unroll
    for (int kk = 0; kk < 16; kk++) {
      float a[4], b[4];
#pragma unroll
      for (int i = 0; i < 4; i++) a[i] = As[ty * 4 + i][kk];
#pragma unroll
      for (int j = 0; j < 4; j++) b[j] = Bs[tx * 4 + j][kk];
#pragma unroll
      for (int i = 0; i < 4; i++)
#pragma unroll
        for (int j = 0; j < 4; j++) acc[i][j] = fmaf(a[i], b[j], acc[i][j]);
    }
    __syncthreads();
  }
#pragma unroll
  for (int i = 0; i < 4; i++) {
    int gm = bm + ty * 4 + i;
    if (gm >= M) continue;
#pragma unroll
    for (int j = 0; j < 4; j++) {
      int gn = bn + tx * 4 + j;
      if (gn >= N) continue;
      if (MODE) C[(size_t)gm * N + gn] += acc[i][j];
      else      C[(size_t)gm * N + gn] = acc[i][j];
    }
  }
}

// ---------------- Assemble q/k (partial RoPE) and v ----------------
__global__ __launch_bounds__(256) void k_qkv(const float* __restrict__ qf,
                                             const float* __restrict__ kvb,
                                             const float* __restrict__ ckv,
                                             const float* __restrict__ cosb,
                                             const float* __restrict__ sinb,
                                             float* __restrict__ qh,
                                             float* __restrict__ kh,
                                             float* __restrict__ vb) {
  int t = blockIdx.x;
  int l = t >> 3;
  for (int idx = threadIdx.x; idx < 768; idx += 256) {
    int hh = idx / 48, dc = idx % 48;
    int hd = hh >> 1, e = hh & 1;
    float qv, kvv;
    if (dc < 32) {
      qv  = qf [(size_t)t * 768  + hd * 96  + e * 32 + dc];
      kvv = kvb[(size_t)t * 1024 + hd * 128 + e * 32 + dc];
    } else {
      int rj = dc - 32;            // 0..15
      int p = rj >> 1; int isim = rj & 1;
      float xr_q = qf[(size_t)t * 768 + hd * 96 + 64 + e * 16 + p * 2];
      float xi_q = qf[(size_t)t * 768 + hd * 96 + 64 + e * 16 + p * 2 + 1];
      float xr_k = ckv[(size_t)t * 160 + 128 + e * 16 + p * 2];
      float xi_k = ckv[(size_t)t * 160 + 128 + e * 16 + p * 2 + 1];
      if (l == 0) {
        qv  = isim ? xi_q : xr_q;
        kvv = isim ? xi_k : xr_k;
      } else {
        float c = cosb[(l - 1) * 8 + p], s = sinb[(l - 1) * 8 + p];
        if (!isim) { qv = xr_q * c - xi_q * s; kvv = xr_k * c - xi_k * s; }
        else       { qv = xr_q * s + xi_q * c; kvv = xr_k * s + xi_k * c; }
      }
    }
    qh[(size_t)t * 768 + idx] = qv;
    kh[(size_t)t * 768 + idx] = kvv;
  }
  for (int idx = threadIdx.x; idx < 512; idx += 256) {
    int hd = idx >> 6, dv = idx & 63;
    vb[(size_t)t * 512 + idx] = kvb[(size_t)t * 1024 + hd * 128 + 64 + dv];
  }
}

// ---------------- lambda scalar ----------------
__global__ void k_lam(const float* __restrict__ lq1, const float* __restrict__ lk1,
                      const float* __restrict__ lq2, const float* __restrict__ lk2,
                      float lamc, float* __restrict__ out) {
  float d1 = 0.f, d2 = 0.f;
  for (int k = 0; k < 32; k++) { d1 = fmaf(lq1[k], lk1[k], d1); d2 = fmaf(lq2[k], lk2[k], d2); }
  out[0] = expf(d1) - expf(d2) + lamc;
}

// ---------------- Scores GEMM (head pair; both heads via blockIdx.z) ----------------
__global__ __launch_bounds__(256) void k_scores_gemm(const float* __restrict__ qh,
                                                     const float* __restrict__ kh,
                                                     float* __restrict__ probs, int hh0) {
  int e = blockIdx.z;
  int hh = hh0 + e;
  const float* A = qh + hh * 48;
  const float* Bm = kh + hh * 48;
  float* C = probs + (size_t)e * Tn * Tn;
  __shared__ float As[64][17];
  __shared__ float Bs[64][17];
  int bm = blockIdx.y * 64, bn = blockIdx.x * 64;
  int tx = threadIdx.x & 15, ty = threadIdx.x >> 4;
  float acc[4][4] = {};
  for (int k0 = 0; k0 < 48; k0 += 16) {
    for (int i = threadIdx.x; i < 1024; i += 256) {
      int m = i >> 4, kk = i & 15;
      int gm = bm + m;
      As[m][kk] = (gm < Tn) ? A[(size_t)gm * 768 + k0 + kk] : 0.f;
      int gn = bn + m;
      Bs[m][kk] = (gn < Tn) ? Bm[(size_t)gn * 768 + k0 + kk] : 0.f;
    }
    __syncthreads();
#pragma unroll
    for (int kk = 0; kk < 16; kk++) {
      float a[4], b[4];
#pragma unroll
      for (int i = 0; i < 4; i++) a[i] = As[ty * 4 + i][kk];
#pragma unroll
      for (int j = 0; j < 4; j++) b[j] = Bs[tx * 4 + j][kk];
#pragma unroll
      for (int i = 0; i < 4; i++)
#pragma unroll
        for (int j = 0; j < 4; j++) acc[i][j] = fmaf(a[i], b[j], acc[i][j]);
    }
    __syncthreads();
  }
#pragma unroll
  for (int i = 0; i < 4; i++) {
    int gm = bm + ty * 4 + i;
    if (gm >= Tn) continue;
    int imod = gm % LPn;
#pragma unroll
    for (int j = 0; j < 4; j++) {
      int gn = bn + tx * 4 + j;
      if (gn >= Tn) continue;
      float sv = ((gn % LPn) > imod) ? -1e9f : acc[i][j] * SCALING_C;
      C[(size_t)gm * Tn + gn] = sv;
    }
  }
}

// ---------------- Row softmax in-place (2 heads) ----------------
__global__ __launch_bounds__(256) void k_softmax_rows(float* __restrict__ probs) {
  float* prow = probs + ((size_t)blockIdx.y * Tn + blockIdx.x) * Tn;
  int tid = threadIdx.x;
  float v[9];
  float lmax = -3.4e38f;
#pragma unroll
  for (int it = 0; it < 9; it++) {
    int j = tid + it * 256;
    v[it] = (j < Tn) ? prow[j] : -3.4e38f;
    lmax = fmaxf(lmax, v[it]);
  }
  for (int off = 1; off < 64; off <<= 1) lmax = fmaxf(lmax, __shfl_xor(lmax, off));
  __shared__ float red[4];
  if ((tid & 63) == 0) red[tid >> 6] = lmax;
  __syncthreads();
  float gmax = fmaxf(fmaxf(red[0], red[1]), fmaxf(red[2], red[3]));
  __syncthreads();
  float lsum = 0.f;
#pragma unroll
  for (int it = 0; it < 9; it++) { v[it] = expf(v[it] - gmax); lsum += v[it]; }
  for (int off = 1; off < 64; off <<= 1) lsum += __shfl_xor(lsum, off);
  if ((tid & 63) == 0) red[tid >> 6] = lsum;
  __syncthreads();
  float inv = 1.f / (red[0] + red[1] + red[2] + red[3]);
#pragma unroll
  for (int it = 0; it < 9; it++) {
    int j = tid + it * 256;
    if (j < Tn) prow[j] = v[it] * inv;
  }
}

// ---------------- Column mean of a1 (two-stage) ----------------
__global__ __launch_bounds__(256) void k_colmean_part(const float* __restrict__ a1,
                                                      float* __restrict__ partial) {
  int j = blockIdx.x * 256 + threadIdx.x;
  int ib = blockIdx.y;
  if (j >= Tn) return;
  int i0 = ib * 64, i1 = min(i0 + 64, Tn);
  float acc = 0.f;
  for (int i = i0; i < i1; i++) acc += a1[(size_t)i * Tn + j];
  partial[(size_t)ib * Tn + j] = acc;
}

__global__ __launch_bounds__(256) void k_colmean2(const float* __restrict__ partial,
                                                  float* __restrict__ g) {
  int j = blockIdx.x * 256 + threadIdx.x;
  if (j >= Tn) return;
  float acc = 0.f;
  for (int ib = 0; ib < 33; ib++) acc += partial[(size_t)ib * Tn + j];
  g[j] = acc * (1.f / (float)Tn);
}

// ---------------- a = a1 - lam*a2 + lam*g, mask->0 ----------------
__global__ __launch_bounds__(256) void k_combine(float* __restrict__ probs,
                                                 const float* __restrict__ g,
                                                 const float* __restrict__ lamp) {
  int i = blockIdx.x;
  int j = blockIdx.y * 256 + threadIdx.x;
  if (j >= Tn) return;
  float lam = lamp[0];
  size_t idx = (size_t)i * Tn + j;
  float a1 = probs[idx];
  float a2 = probs[(size_t)Tn * Tn + idx];
  float av = ((j % LPn) > (i % LPn)) ? 0.f : (a1 - lam * a2 + lam * g[j]);
  probs[idx] = av;
}

// ---------------- o_raw = a @ v_ph  (M=T, N=64, K=T) ----------------
__global__ __launch_bounds__(256) void k_attnout_gemm(const float* __restrict__ Aa,
                                                      const float* __restrict__ vb,
                                                      float* __restrict__ oraw, int ph) {
  __shared__ float As[64][17];
  __shared__ float Bs[64][17];
  int bm = blockIdx.x * 64;
  int tx = threadIdx.x & 15, ty = threadIdx.x >> 4;
  float acc[4][4] = {};
  for (int k0 = 0; k0 < Tn; k0 += 16) {
    for (int i = threadIdx.x; i < 1024; i += 256) {
      int m = i >> 4, kk = i & 15;
      int gm = bm + m;
      As[m][kk] = (gm < Tn && (k0 + kk) < Tn) ? Aa[(size_t)gm * Tn + k0 + kk] : 0.f;
    }
    for (int i = threadIdx.x; i < 1024; i += 256) {
      int kk = i >> 6, n = i & 63;
      int gk = k0 + kk;
      Bs[n][kk] = (gk < Tn) ? vb[(size_t)gk * 512 + ph * 64 + n] : 0.f;
    }
    __syncthreads();
#pragma unroll
    for (int kk = 0; kk < 16; kk++) {
      float a[4], b[4];
#pragma unroll
      for (int i = 0; i < 4; i++) a[i] = As[ty * 4 + i][kk];
#pragma unroll
      for (int j = 0; j < 4; j++) b[j] = Bs[tx * 4 + j][kk];
#pragma unroll
      for (int i = 0; i < 4; i++)
#pragma unroll
        for (int j = 0; j < 4; j++) acc[i][j] = fmaf(a[i], b[j], acc[i][j]);
    }
    __syncthreads();
  }
#pragma unroll
  for (int i = 0; i < 4; i++) {
    int gm = bm + ty * 4 + i;
    if (gm >= Tn) continue;
#pragma unroll
    for (int j = 0; j < 4; j++)
      oraw[((size_t)ph * Tn + gm) * 64 + tx * 4 + j] = acc[i][j];
  }
}

// ---------------- SwiGLU ----------------
__global__ __launch_bounds__(256) void k_swiglu(const float* __restrict__ uv,
                                                float* __restrict__ gated) {
  size_t idx = (size_t)blockIdx.x * 256 + threadIdx.x;
  if (idx >= (size_t)Tn * 2048) return;
  size_t t = idx / 2048, f = idx % 2048;
  float u = uv[t * 4096 + f];
  float vv = uv[t * 4096 + 2048 + f];
  float sv = vv / (1.f + expf(-vv));
  gated[idx] = u * sv;
}

// ---------------- final head (FLOAT32 out) ----------------
__global__ __launch_bounds__(192) void k_final(const float* __restrict__ z,
                                               const float* __restrict__ outW,
                                               float* __restrict__ out) {
  int t = blockIdx.x;
  int p = threadIdx.x >> 6, lane = threadIdx.x & 63;
  float acc = 0.f;
  for (int m = lane; m < 512; m += 64) acc = fmaf(z[(size_t)t * 512 + m], outW[(size_t)p * 512 + m], acc);
  for (int off = 1; off < 64; off <<= 1) acc += __shfl_xor(acc, off);
  if (lane == 0) out[(size_t)t * 3 + p] = acc;
}

extern "C" void kernel_launch(void* const* d_in, const int* in_sizes, int n_in,
                              void* d_out, int out_size, void* d_ws, size_t ws_size,
                              hipStream_t stream) {
  const float* x          = (const float*)d_in[0];
  const float* ticker_emb = (const float*)d_in[1];
  const float* sep_emb    = (const float*)d_in[2];
  const float* shared_W   = (const float*)d_in[3];
  const float* unique_W   = (const float*)d_in[4];
  const float* norm1_w    = (const float*)d_in[5];
  const float* norm2_w    = (const float*)d_in[6];
  const float* kv_down_W  = (const float*)d_in[7];
  const float* q_down_W   = (const float*)d_in[8];
  const float* kv_up_W    = (const float*)d_in[9];
  const float* q_up_W     = (const float*)d_in[10];
  const float* kv_norm_w  = (const float*)d_in[11];
  const float* q_norm_w   = (const float*)d_in[12];
  const float* o_W        = (const float*)d_in[13];
  const float* lam_q1     = (const float*)d_in[14];
  const float* lam_k1     = (const float*)d_in[15];
  const float* lam_q2     = (const float*)d_in[16];
  const float* lam_k2     = (const float*)d_in[17];
  const float* head_norm_w= (const float*)d_in[18];
  const float* ff_in_W    = (const float*)d_in[19];
  const float* ff_out_W   = (const float*)d_in[20];
  const float* final_norm = (const float*)d_in[21];
  const float* out_W      = (const float*)d_in[22];
  const int*   seperator  = (const int*)d_in[23];
  const int*   tickers    = (const int*)d_in[24];
  (void)in_sizes; (void)n_in;

  float* W = (float*)d_ws;
  size_t off = 0;
  auto alloc = [&](size_t n) { float* p = W + off; off += n; return p; };
  float* cosb  = alloc(256 * 8);
  float* sinb  = alloc(256 * 8);
  float* h     = alloc((size_t)Tn * Dn);
  float* xn    = alloc((size_t)Tn * Dn);          // also z
  float* ckv   = alloc((size_t)Tn * 160);         // region also hosts onorm later
  float* ckvn  = alloc((size_t)Tn * 128);
  float* qlat  = alloc((size_t)Tn * 192);
  float* qlatn = alloc((size_t)Tn * 192);
  float* kvb   = alloc((size_t)Tn * 1024);        // region also hosts gated later
  float* qf    = alloc((size_t)Tn * 768);
  float* qh    = alloc((size_t)Tn * 768);
  float* kh    = alloc((size_t)Tn * 768);
  float* vb    = alloc((size_t)Tn * 512);
  float* g     = alloc(Tn);
  float* lam   = alloc(1);
  float* partial = alloc((size_t)33 * Tn);
  float* probs = alloc((size_t)2 * Tn * Tn);      // also hosts uv
  // overlays (disjoint lifetimes):
  float* onorm = ckv;    // (8, T, 64) flat; ckv+ckvn+qlat+qlatn region >= 8*T*64
  float* z     = xn;
  float* uv    = probs;
  float* gated = kvb;

  size_t needed = off * sizeof(float);            // ~79.6 MB (guard proven ok in r2)
  if (ws_size < needed) {
    k_fill42<<<(out_size + 255) / 256, 256, 0, stream>>>((float*)d_out, out_size);
    return;
  }

  k_freqs<<<8, 256, 0, stream>>>(cosb, sinb);
  k_embed<<<dim3(Tn, 2), 256, 0, stream>>>(x, ticker_emb, sep_emb, shared_W, unique_W,
                                           seperator, tickers, h);

  for (int d = 0; d < 2; d++) {
    const float* n1   = norm1_w + d * 512;
    const float* n2   = norm2_w + d * 512;
    const float* kvd  = kv_down_W + (size_t)d * 160 * 512;
    const float* qd   = q_down_W + (size_t)d * 192 * 512;
    const float* kvu  = kv_up_W + (size_t)d * 1024 * 128;
    const float* qu   = q_up_W + (size_t)d * 768 * 192;
    const float* kvnw = kv_norm_w + d * 128;
    const float* qnw  = q_norm_w + d * 192;
    const float* oW   = o_W + (size_t)d * 512 * 512;
    const float* hnw  = head_norm_w + d * 64;
    const float* ffi  = ff_in_W + (size_t)d * 4096 * 512;
    const float* ffo  = ff_out_W + (size_t)d * 512 * 2048;
    float lamc = 0.8f - 0.6f * expf(-0.3f * (float)d);

    k_rmsnorm<<<Tn, 256, 0, stream>>>(h, n1, xn, 512, 512, EPS_C);
    k_gemm<0><<<dim3(3, 33), 256, 0, stream>>>(xn, kvd, ckv, Tn, 160, 512);
    k_rmsnorm<<<Tn, 256, 0, stream>>>(ckv, kvnw, ckvn, 128, 160, EPS_C);
    k_gemm<0><<<dim3(16, 33), 256, 0, stream>>>(ckvn, kvu, kvb, Tn, 1024, 128);
    k_gemm<0><<<dim3(3, 33), 256, 0, stream>>>(xn, qd, qlat, Tn, 192, 512);
    k_rmsnorm<<<Tn, 256, 0, stream>>>(qlat, qnw, qlatn, 192, 192, EPS_C);
    k_gemm<0><<<dim3(12, 33), 256, 0, stream>>>(qlatn, qu, qf, Tn, 768, 192);
    k_qkv<<<Tn, 256, 0, stream>>>(qf, kvb, ckv, cosb, sinb, qh, kh, vb);
    k_lam<<<1, 1, 0, stream>>>(lam_q1 + d * 32, lam_k1 + d * 32,
                               lam_q2 + d * 32, lam_k2 + d * 32, lamc, lam);

    for (int ph = 0; ph < 8; ph++) {
      k_scores_gemm<<<dim3(33, 33, 2), 256, 0, stream>>>(qh, kh, probs, 2 * ph);
      k_softmax_rows<<<dim3(Tn, 2), 256, 0, stream>>>(probs);
      k_colmean_part<<<dim3(9, 33), 256, 0, stream>>>(probs, partial);
      k_colmean2<<<9, 256, 0, stream>>>(partial, g);
      k_combine<<<dim3(Tn, 9), 256, 0, stream>>>(probs, g, lam);
      k_attnout_gemm<<<33, 256, 0, stream>>>(probs, vb, onorm, ph);  // raw o
    }
    // per-head RMSNorm over (8*T) rows of 64, in place, eps 1e-5
    k_rmsnorm<<<8 * Tn, 256, 0, stream>>>(onorm, hnw, onorm, 64, 64, 1e-5f);

    k_gemm<1><<<dim3(8, 33), 256, 0, stream>>>(onorm, oW, h, Tn, 512, 512);   // h += o-proj
    k_rmsnorm<<<Tn, 256, 0, stream>>>(h, n2, z, 512, 512, EPS_C);
    k_gemm<0><<<dim3(64, 33), 256, 0, stream>>>(z, ffi, uv, Tn, 4096, 512);
    k_swiglu<<<16448, 256, 0, stream>>>(uv, gated);
    k_gemm<1><<<dim3(8, 33), 256, 0, stream>>>(gated, ffo, h, Tn, 512, 2048); // h += ffn
  }

  k_rmsnorm<<<Tn, 256, 0, stream>>>(h, final_norm, z, 512, 512, EPS_C);
  k_final<<<Tn, 192, 0, stream>>>(z, out_W, (float*)d_out);
}

// Round 5
// 8893.909 us; speedup vs baseline: 1.0956x; 1.0956x over previous
//
#include <hip/hip_runtime.h>
#include <hip/hip_bf16.h>

// Money_former MLA DINT — round 5: kill the 33-block PV GEMM (69% of runtime).
// k_pv_fused = combine(a1,a2,g,lam,mask) + PV + head-RMSNorm in one kernel,
// one wave per output row, shfl-broadcast inner product, masked-j skipping.
// T=2056, D=512, 2 layers, 16 logical heads (8 pairs) of 48.

#define Tn 2056
#define LPn 257
#define Dn 512

static constexpr float SCALING_C = 0.14433756729740643f;   // 48^-0.5
static constexpr float EPS_C     = 1.1920928955078125e-07f;

// ---------------- sentinel ----------------
__global__ __launch_bounds__(256) void k_fill42(float* __restrict__ out, int n) {
  int i = blockIdx.x * 256 + threadIdx.x;
  if (i < n) out[i] = 42.0f;
}

// ---------------- RoPE tables ----------------
__global__ __launch_bounds__(256) void k_freqs(float* __restrict__ cosb, float* __restrict__ sinb) {
  int idx = blockIdx.x * 256 + threadIdx.x;
  if (idx >= 256 * 8) return;
  int pos = idx >> 3, j = idx & 7;
  float fb = powf(10000.f, -(float)j * 0.125f);            // 1/10000^(j/8)
  float ramp = fminf(fmaxf((float)j * 0.25f, 0.f), 1.f);   // low=0, high=4
  float sm = 1.f - ramp;
  float fr = fb * (1.f / 40.f) * (1.f - sm) + fb * sm;
  float ang = (float)pos * fr;
  cosb[idx] = cosf(ang);
  sinb[idx] = sinf(ang);
}

// ---------------- Embedding ----------------
__global__ __launch_bounds__(256) void k_embed(const float* __restrict__ x,
                                               const float* __restrict__ ticker_emb,
                                               const float* __restrict__ sep_emb,
                                               const float* __restrict__ shared_W,
                                               const float* __restrict__ unique_W,
                                               const int* __restrict__ sep_idx,
                                               const int* __restrict__ tickers,
                                               float* __restrict__ h) {
  int t = blockIdx.x;
  int c = blockIdx.y * 256 + threadIdx.x;
  int l = t >> 3, s = t & 7;
  float val;
  if (l == 0) {
    val = sep_emb[sep_idx[0] * Dn + c];
  } else {
    const float* xr = x + ((size_t)(l - 1) * 8 + s) * 32;
    const float* w = (c < 384) ? (shared_W + (size_t)c * 32)
                               : (unique_W + ((size_t)s * 128 + (c - 384)) * 32);
    float acc = 0.f;
#pragma unroll
    for (int f = 0; f < 32; f++) acc = fmaf(xr[f], w[f], acc);
    val = acc;
  }
  val += ticker_emb[(size_t)tickers[s] * Dn + c];
  h[(size_t)t * Dn + c] = val;
}

// ---------------- Generic row RMSNorm (in-place safe) ----------------
__global__ __launch_bounds__(256) void k_rmsnorm(const float* __restrict__ in,
                                                 const float* __restrict__ w,
                                                 float* __restrict__ out,
                                                 int ncols, int in_stride, float eps) {
  int row = blockIdx.x;
  const float* xr = in + (size_t)row * in_stride;
  float ss = 0.f;
  for (int c = threadIdx.x; c < ncols; c += 256) { float v = xr[c]; ss = fmaf(v, v, ss); }
  for (int off = 1; off < 64; off <<= 1) ss += __shfl_xor(ss, off);
  __shared__ float red[4];
  if ((threadIdx.x & 63) == 0) red[threadIdx.x >> 6] = ss;
  __syncthreads();
  float tot = red[0] + red[1] + red[2] + red[3];
  float scale = rsqrtf(tot / (float)ncols + eps);
  for (int c = threadIdx.x; c < ncols; c += 256)
    out[(size_t)row * ncols + c] = xr[c] * scale * w[c];
}

// ---------------- Tiled GEMM: C[M,N] (+)= A[M,K] @ B[N,K]^T ----------------
template <int MODE>
__global__ __launch_bounds__(256) void k_gemm(const float* __restrict__ A,
                                              const float* __restrict__ B,
                                              float* __restrict__ C,
                                              int M, int N, int K) {
  __shared__ float As[64][17];
  __shared__ float Bs[64][17];
  int bm = blockIdx.y * 64, bn = blockIdx.x * 64;
  int tx = threadIdx.x & 15, ty = threadIdx.x >> 4;
  float acc[4][4] = {};
  for (int k0 = 0; k0 < K; k0 += 16) {
    for (int i = threadIdx.x; i < 1024; i += 256) {
      int m = i >> 4, kk = i & 15;
      int gm = bm + m;
      As[m][kk] = (gm < M) ? A[(size_t)gm * K + k0 + kk] : 0.f;
      int gn = bn + m;
      Bs[m][kk] = (gn < N) ? B[(size_t)gn * K + k0 + kk] : 0.f;
    }
    __syncthreads();
#pragma unroll
    for (int kk = 0; kk < 16; kk++) {
      float a[4], b[4];
#pragma unroll
      for (int i = 0; i < 4; i++) a[i] = As[ty * 4 + i][kk];
#pragma unroll
      for (int j = 0; j < 4; j++) b[j] = Bs[tx * 4 + j][kk];
#pragma unroll
      for (int i = 0; i < 4; i++)
#pragma unroll
        for (int j = 0; j < 4; j++) acc[i][j] = fmaf(a[i], b[j], acc[i][j]);
    }
    __syncthreads();
  }
#pragma unroll
  for (int i = 0; i < 4; i++) {
    int gm = bm + ty * 4 + i;
    if (gm >= M) continue;
#pragma unroll
    for (int j = 0; j < 4; j++) {
      int gn = bn + tx * 4 + j;
      if (gn >= N) continue;
      if (MODE) C[(size_t)gm * N + gn] += acc[i][j];
      else      C[(size_t)gm * N + gn] = acc[i][j];
    }
  }
}

// ---------------- Assemble q/k (partial RoPE) and v ----------------
__global__ __launch_bounds__(256) void k_qkv(const float* __restrict__ qf,
                                             const float* __restrict__ kvb,
                                             const float* __restrict__ ckv,
                                             const float* __restrict__ cosb,
                                             const float* __restrict__ sinb,
                                             float* __restrict__ qh,
                                             float* __restrict__ kh,
                                             float* __restrict__ vb) {
  int t = blockIdx.x;
  int l = t >> 3;
  for (int idx = threadIdx.x; idx < 768; idx += 256) {
    int hh = idx / 48, dc = idx % 48;
    int hd = hh >> 1, e = hh & 1;
    float qv, kvv;
    if (dc < 32) {
      qv  = qf [(size_t)t * 768  + hd * 96  + e * 32 + dc];
      kvv = kvb[(size_t)t * 1024 + hd * 128 + e * 32 + dc];
    } else {
      int rj = dc - 32;            // 0..15
      int p = rj >> 1; int isim = rj & 1;
      float xr_q = qf[(size_t)t * 768 + hd * 96 + 64 + e * 16 + p * 2];
      float xi_q = qf[(size_t)t * 768 + hd * 96 + 64 + e * 16 + p * 2 + 1];
      float xr_k = ckv[(size_t)t * 160 + 128 + e * 16 + p * 2];
      float xi_k = ckv[(size_t)t * 160 + 128 + e * 16 + p * 2 + 1];
      if (l == 0) {
        qv  = isim ? xi_q : xr_q;
        kvv = isim ? xi_k : xr_k;
      } else {
        float c = cosb[(l - 1) * 8 + p], s = sinb[(l - 1) * 8 + p];
        if (!isim) { qv = xr_q * c - xi_q * s; kvv = xr_k * c - xi_k * s; }
        else       { qv = xr_q * s + xi_q * c; kvv = xr_k * s + xi_k * c; }
      }
    }
    qh[(size_t)t * 768 + idx] = qv;
    kh[(size_t)t * 768 + idx] = kvv;
  }
  for (int idx = threadIdx.x; idx < 512; idx += 256) {
    int hd = idx >> 6, dv = idx & 63;
    vb[(size_t)t * 512 + idx] = kvb[(size_t)t * 1024 + hd * 128 + 64 + dv];
  }
}

// ---------------- lambda scalar ----------------
__global__ void k_lam(const float* __restrict__ lq1, const float* __restrict__ lk1,
                      const float* __restrict__ lq2, const float* __restrict__ lk2,
                      float lamc, float* __restrict__ out) {
  float d1 = 0.f, d2 = 0.f;
  for (int k = 0; k < 32; k++) { d1 = fmaf(lq1[k], lk1[k], d1); d2 = fmaf(lq2[k], lk2[k], d2); }
  out[0] = expf(d1) - expf(d2) + lamc;
}

// ---------------- Scores GEMM (head pair; both heads via blockIdx.z) ----------------
__global__ __launch_bounds__(256) void k_scores_gemm(const float* __restrict__ qh,
                                                     const float* __restrict__ kh,
                                                     float* __restrict__ probs, int hh0) {
  int e = blockIdx.z;
  int hh = hh0 + e;
  const float* A = qh + hh * 48;
  const float* Bm = kh + hh * 48;
  float* C = probs + (size_t)e * Tn * Tn;
  __shared__ float As[64][17];
  __shared__ float Bs[64][17];
  int bm = blockIdx.y * 64, bn = blockIdx.x * 64;
  int tx = threadIdx.x & 15, ty = threadIdx.x >> 4;
  float acc[4][4] = {};
  for (int k0 = 0; k0 < 48; k0 += 16) {
    for (int i = threadIdx.x; i < 1024; i += 256) {
      int m = i >> 4, kk = i & 15;
      int gm = bm + m;
      As[m][kk] = (gm < Tn) ? A[(size_t)gm * 768 + k0 + kk] : 0.f;
      int gn = bn + m;
      Bs[m][kk] = (gn < Tn) ? Bm[(size_t)gn * 768 + k0 + kk] : 0.f;
    }
    __syncthreads();
#pragma unroll
    for (int kk = 0; kk < 16; kk++) {
      float a[4], b[4];
#pragma unroll
      for (int i = 0; i < 4; i++) a[i] = As[ty * 4 + i][kk];
#pragma unroll
      for (int j = 0; j < 4; j++) b[j] = Bs[tx * 4 + j][kk];
#pragma unroll
      for (int i = 0; i < 4; i++)
#pragma unroll
        for (int j = 0; j < 4; j++) acc[i][j] = fmaf(a[i], b[j], acc[i][j]);
    }
    __syncthreads();
  }
#pragma unroll
  for (int i = 0; i < 4; i++) {
    int gm = bm + ty * 4 + i;
    if (gm >= Tn) continue;
    int imod = gm % LPn;
#pragma unroll
    for (int j = 0; j < 4; j++) {
      int gn = bn + tx * 4 + j;
      if (gn >= Tn) continue;
      float sv = ((gn % LPn) > imod) ? -1e9f : acc[i][j] * SCALING_C;
      C[(size_t)gm * Tn + gn] = sv;
    }
  }
}

// ---------------- Row softmax in-place (2 heads) ----------------
__global__ __launch_bounds__(256) void k_softmax_rows(float* __restrict__ probs) {
  float* prow = probs + ((size_t)blockIdx.y * Tn + blockIdx.x) * Tn;
  int tid = threadIdx.x;
  float v[9];
  float lmax = -3.4e38f;
#pragma unroll
  for (int it = 0; it < 9; it++) {
    int j = tid + it * 256;
    v[it] = (j < Tn) ? prow[j] : -3.4e38f;
    lmax = fmaxf(lmax, v[it]);
  }
  for (int off = 1; off < 64; off <<= 1) lmax = fmaxf(lmax, __shfl_xor(lmax, off));
  __shared__ float red[4];
  if ((tid & 63) == 0) red[tid >> 6] = lmax;
  __syncthreads();
  float gmax = fmaxf(fmaxf(red[0], red[1]), fmaxf(red[2], red[3]));
  __syncthreads();
  float lsum = 0.f;
#pragma unroll
  for (int it = 0; it < 9; it++) { v[it] = expf(v[it] - gmax); lsum += v[it]; }
  for (int off = 1; off < 64; off <<= 1) lsum += __shfl_xor(lsum, off);
  if ((tid & 63) == 0) red[tid >> 6] = lsum;
  __syncthreads();
  float inv = 1.f / (red[0] + red[1] + red[2] + red[3]);
#pragma unroll
  for (int it = 0; it < 9; it++) {
    int j = tid + it * 256;
    if (j < Tn) prow[j] = v[it] * inv;
  }
}

// ---------------- Column mean of a1 (two-stage) ----------------
__global__ __launch_bounds__(256) void k_colmean_part(const float* __restrict__ a1,
                                                      float* __restrict__ partial) {
  int j = blockIdx.x * 256 + threadIdx.x;
  int ib = blockIdx.y;
  if (j >= Tn) return;
  int i0 = ib * 64, i1 = min(i0 + 64, Tn);
  float acc = 0.f;
  for (int i = i0; i < i1; i++) acc += a1[(size_t)i * Tn + j];
  partial[(size_t)ib * Tn + j] = acc;
}

// writes g[j] = lam * mean_i(a1[i][j])   (lam folded in)
__global__ __launch_bounds__(256) void k_colmean2(const float* __restrict__ partial,
                                                  const float* __restrict__ lamp,
                                                  float* __restrict__ g) {
  int j = blockIdx.x * 256 + threadIdx.x;
  if (j >= Tn) return;
  float acc = 0.f;
  for (int ib = 0; ib < 33; ib++) acc += partial[(size_t)ib * Tn + j];
  g[j] = acc * (1.f / (float)Tn) * lamp[0];
}

// ---------------- Fused combine + PV + head-RMSNorm ----------------
// One wave per output row i (lane = dv). a = a1 - lam*a2 + g  (g pre-scaled by lam),
// masked (j%257 > i%257) -> 0. o[i][dv] = sum_j a * V[j][ph*64+dv]; then rmsnorm.
__global__ __launch_bounds__(256) void k_pv_fused(const float* __restrict__ probs,
                                                  const float* __restrict__ vb,
                                                  const float* __restrict__ g,
                                                  const float* __restrict__ lamp,
                                                  const float* __restrict__ hnw,
                                                  float* __restrict__ onorm, int ph) {
  int w = threadIdx.x >> 6, lane = threadIdx.x & 63;
  int i = blockIdx.x * 4 + w;            // grid = 514 -> i in [0, 2056)
  int imod = i % LPn;
  float lam = lamp[0];
  const float* a1r = probs + (size_t)i * Tn;
  const float* a2r = probs + (size_t)Tn * Tn + (size_t)i * Tn;
  const float* vcol = vb + ph * 64 + lane;
  float acc = 0.f;
  for (int c0 = 0; c0 < Tn; c0 += 64) {
    int j = c0 + lane;
    float av = 0.f;
    if (j < Tn) {
      int jmod = j % LPn;
      if (jmod <= imod) {
        av = fmaf(-lam, a2r[j], a1r[j]) + g[j];
      }
    }
    // broadcast each lane's av; skip masked/zero j (wave-uniform branch)
    int jjmax = min(64, Tn - c0);
    for (int jj = 0; jj < jjmax; jj++) {
      float a = __shfl(av, jj);
      if (a != 0.f)
        acc = fmaf(a, vcol[(size_t)(c0 + jj) * 512], acc);
    }
  }
  // head rmsnorm over 64 lanes (eps 1e-5)
  float ss = acc * acc;
  for (int off = 1; off < 64; off <<= 1) ss += __shfl_xor(ss, off);
  float scale = rsqrtf(ss * (1.f / 64.f) + 1e-5f);
  onorm[((size_t)ph * Tn + i) * 64 + lane] = acc * scale * hnw[lane];
}

// ---------------- SwiGLU ----------------
__global__ __launch_bounds__(256) void k_swiglu(const float* __restrict__ uv,
                                                float* __restrict__ gated) {
  size_t idx = (size_t)blockIdx.x * 256 + threadIdx.x;
  if (idx >= (size_t)Tn * 2048) return;
  size_t t = idx / 2048, f = idx % 2048;
  float u = uv[t * 4096 + f];
  float vv = uv[t * 4096 + 2048 + f];
  float sv = vv / (1.f + expf(-vv));
  gated[idx] = u * sv;
}

// ---------------- final head (float32 out) ----------------
__global__ __launch_bounds__(192) void k_final(const float* __restrict__ z,
                                               const float* __restrict__ outW,
                                               float* __restrict__ out) {
  int t = blockIdx.x;
  int p = threadIdx.x >> 6, lane = threadIdx.x & 63;
  float acc = 0.f;
  for (int m = lane; m < 512; m += 64) acc = fmaf(z[(size_t)t * 512 + m], outW[(size_t)p * 512 + m], acc);
  for (int off = 1; off < 64; off <<= 1) acc += __shfl_xor(acc, off);
  if (lane == 0) out[(size_t)t * 3 + p] = acc;
}

extern "C" void kernel_launch(void* const* d_in, const int* in_sizes, int n_in,
                              void* d_out, int out_size, void* d_ws, size_t ws_size,
                              hipStream_t stream) {
  const float* x          = (const float*)d_in[0];
  const float* ticker_emb = (const float*)d_in[1];
  const float* sep_emb    = (const float*)d_in[2];
  const float* shared_W   = (const float*)d_in[3];
  const float* unique_W   = (const float*)d_in[4];
  const float* norm1_w    = (const float*)d_in[5];
  const float* norm2_w    = (const float*)d_in[6];
  const float* kv_down_W  = (const float*)d_in[7];
  const float* q_down_W   = (const float*)d_in[8];
  const float* kv_up_W    = (const float*)d_in[9];
  const float* q_up_W     = (const float*)d_in[10];
  const float* kv_norm_w  = (const float*)d_in[11];
  const float* q_norm_w   = (const float*)d_in[12];
  const float* o_W        = (const float*)d_in[13];
  const float* lam_q1     = (const float*)d_in[14];
  const float* lam_k1     = (const float*)d_in[15];
  const float* lam_q2     = (const float*)d_in[16];
  const float* lam_k2     = (const float*)d_in[17];
  const float* head_norm_w= (const float*)d_in[18];
  const float* ff_in_W    = (const float*)d_in[19];
  const float* ff_out_W   = (const float*)d_in[20];
  const float* final_norm = (const float*)d_in[21];
  const float* out_W      = (const float*)d_in[22];
  const int*   seperator  = (const int*)d_in[23];
  const int*   tickers    = (const int*)d_in[24];
  (void)in_sizes; (void)n_in;

  float* W = (float*)d_ws;
  size_t off = 0;
  auto alloc = [&](size_t n) { float* p = W + off; off += n; return p; };
  float* cosb  = alloc(256 * 8);
  float* sinb  = alloc(256 * 8);
  float* h     = alloc((size_t)Tn * Dn);
  float* xn    = alloc((size_t)Tn * Dn);          // also z
  float* ckv   = alloc((size_t)Tn * 160);         // region also hosts onorm later
  float* ckvn  = alloc((size_t)Tn * 128);
  float* qlat  = alloc((size_t)Tn * 192);
  float* qlatn = alloc((size_t)Tn * 192);
  float* kvb   = alloc((size_t)Tn * 1024);        // region also hosts gated later
  float* qf    = alloc((size_t)Tn * 768);
  float* qh    = alloc((size_t)Tn * 768);
  float* kh    = alloc((size_t)Tn * 768);
  float* vb    = alloc((size_t)Tn * 512);
  float* g     = alloc(Tn);
  float* lam   = alloc(1);
  float* partial = alloc((size_t)33 * Tn);
  float* probs = alloc((size_t)2 * Tn * Tn);      // also hosts uv
  // overlays (disjoint lifetimes):
  float* onorm = ckv;    // (8, T, 64) flat; ckv+ckvn+qlat+qlatn region >= 8*T*64
  float* z     = xn;
  float* uv    = probs;
  float* gated = kvb;

  size_t needed = off * sizeof(float);            // ~79.6 MB (proven available)
  if (ws_size < needed) {
    k_fill42<<<(out_size + 255) / 256, 256, 0, stream>>>((float*)d_out, out_size);
    return;
  }

  k_freqs<<<8, 256, 0, stream>>>(cosb, sinb);
  k_embed<<<dim3(Tn, 2), 256, 0, stream>>>(x, ticker_emb, sep_emb, shared_W, unique_W,
                                           seperator, tickers, h);

  for (int d = 0; d < 2; d++) {
    const float* n1   = norm1_w + d * 512;
    const float* n2   = norm2_w + d * 512;
    const float* kvd  = kv_down_W + (size_t)d * 160 * 512;
    const float* qd   = q_down_W + (size_t)d * 192 * 512;
    const float* kvu  = kv_up_W + (size_t)d * 1024 * 128;
    const float* qu   = q_up_W + (size_t)d * 768 * 192;
    const float* kvnw = kv_norm_w + d * 128;
    const float* qnw  = q_norm_w + d * 192;
    const float* oW   = o_W + (size_t)d * 512 * 512;
    const float* hnw  = head_norm_w + d * 64;
    const float* ffi  = ff_in_W + (size_t)d * 4096 * 512;
    const float* ffo  = ff_out_W + (size_t)d * 512 * 2048;
    float lamc = 0.8f - 0.6f * expf(-0.3f * (float)d);

    k_rmsnorm<<<Tn, 256, 0, stream>>>(h, n1, xn, 512, 512, EPS_C);
    k_gemm<0><<<dim3(3, 33), 256, 0, stream>>>(xn, kvd, ckv, Tn, 160, 512);
    k_rmsnorm<<<Tn, 256, 0, stream>>>(ckv, kvnw, ckvn, 128, 160, EPS_C);
    k_gemm<0><<<dim3(16, 33), 256, 0, stream>>>(ckvn, kvu, kvb, Tn, 1024, 128);
    k_gemm<0><<<dim3(3, 33), 256, 0, stream>>>(xn, qd, qlat, Tn, 192, 512);
    k_rmsnorm<<<Tn, 256, 0, stream>>>(qlat, qnw, qlatn, 192, 192, EPS_C);
    k_gemm<0><<<dim3(12, 33), 256, 0, stream>>>(qlatn, qu, qf, Tn, 768, 192);
    k_qkv<<<Tn, 256, 0, stream>>>(qf, kvb, ckv, cosb, sinb, qh, kh, vb);
    k_lam<<<1, 1, 0, stream>>>(lam_q1 + d * 32, lam_k1 + d * 32,
                               lam_q2 + d * 32, lam_k2 + d * 32, lamc, lam);

    for (int ph = 0; ph < 8; ph++) {
      k_scores_gemm<<<dim3(33, 33, 2), 256, 0, stream>>>(qh, kh, probs, 2 * ph);
      k_softmax_rows<<<dim3(Tn, 2), 256, 0, stream>>>(probs);
      k_colmean_part<<<dim3(9, 33), 256, 0, stream>>>(probs, partial);
      k_colmean2<<<9, 256, 0, stream>>>(partial, lam, g);
      k_pv_fused<<<514, 256, 0, stream>>>(probs, vb, g, lam, hnw, onorm, ph);
    }

    k_gemm<1><<<dim3(8, 33), 256, 0, stream>>>(onorm, oW, h, Tn, 512, 512);   // h += o-proj
    k_rmsnorm<<<Tn, 256, 0, stream>>>(h, n2, z, 512, 512, EPS_C);
    k_gemm<0><<<dim3(64, 33), 256, 0, stream>>>(z, ffi, uv, Tn, 4096, 512);
    k_swiglu<<<16448, 256, 0, stream>>>(uv, gated);
    k_gemm<1><<<dim3(8, 33), 256, 0, stream>>>(gated, ffo, h, Tn, 512, 2048); // h += ffn
  }

  k_rmsnorm<<<Tn, 256, 0, stream>>>(h, final_norm, z, 512, 512, EPS_C);
  k_final<<<Tn, 192, 0, stream>>>(z, out_W, (float*)d_out);
}

// Round 7
// 4978.048 us; speedup vs baseline: 1.9574x; 1.7866x over previous
//
#include <hip/hip_runtime.h>
#include <hip/hip_bf16.h>

// Money_former MLA DINT — round 7: fix round-6 overlay collision.
// Wb/Gb moved from qlat (inside onorm overlay!) to the partial region
// (disjoint lifetime within each ph iteration). PV = K-split tiled GEMM
// (a1 - lam*a2 staged on the fly; mask-free since masked softmax = exactly 0)
// + prefix-sum G-term (lam*g depends only on i%257) + fused reduce/RMSNorm.
// T=2056, D=512, 2 layers, 16 logical heads (8 pairs) of 48.

#define Tn 2056
#define LPn 257
#define Dn 512

static constexpr float SCALING_C = 0.14433756729740643f;   // 48^-0.5
static constexpr float EPS_C     = 1.1920928955078125e-07f;

// ---------------- sentinel ----------------
__global__ __launch_bounds__(256) void k_fill42(float* __restrict__ out, int n) {
  int i = blockIdx.x * 256 + threadIdx.x;
  if (i < n) out[i] = 42.0f;
}

// ---------------- RoPE tables ----------------
__global__ __launch_bounds__(256) void k_freqs(float* __restrict__ cosb, float* __restrict__ sinb) {
  int idx = blockIdx.x * 256 + threadIdx.x;
  if (idx >= 256 * 8) return;
  int pos = idx >> 3, j = idx & 7;
  float fb = powf(10000.f, -(float)j * 0.125f);            // 1/10000^(j/8)
  float ramp = fminf(fmaxf((float)j * 0.25f, 0.f), 1.f);   // low=0, high=4
  float sm = 1.f - ramp;
  float fr = fb * (1.f / 40.f) * (1.f - sm) + fb * sm;
  float ang = (float)pos * fr;
  cosb[idx] = cosf(ang);
  sinb[idx] = sinf(ang);
}

// ---------------- Embedding ----------------
__global__ __launch_bounds__(256) void k_embed(const float* __restrict__ x,
                                               const float* __restrict__ ticker_emb,
                                               const float* __restrict__ sep_emb,
                                               const float* __restrict__ shared_W,
                                               const float* __restrict__ unique_W,
                                               const int* __restrict__ sep_idx,
                                               const int* __restrict__ tickers,
                                               float* __restrict__ h) {
  int t = blockIdx.x;
  int c = blockIdx.y * 256 + threadIdx.x;
  int l = t >> 3, s = t & 7;
  float val;
  if (l == 0) {
    val = sep_emb[sep_idx[0] * Dn + c];
  } else {
    const float* xr = x + ((size_t)(l - 1) * 8 + s) * 32;
    const float* w = (c < 384) ? (shared_W + (size_t)c * 32)
                               : (unique_W + ((size_t)s * 128 + (c - 384)) * 32);
    float acc = 0.f;
#pragma unroll
    for (int f = 0; f < 32; f++) acc = fmaf(xr[f], w[f], acc);
    val = acc;
  }
  val += ticker_emb[(size_t)tickers[s] * Dn + c];
  h[(size_t)t * Dn + c] = val;
}

// ---------------- Generic row RMSNorm (in-place safe) ----------------
__global__ __launch_bounds__(256) void k_rmsnorm(const float* __restrict__ in,
                                                 const float* __restrict__ w,
                                                 float* __restrict__ out,
                                                 int ncols, int in_stride, float eps) {
  int row = blockIdx.x;
  const float* xr = in + (size_t)row * in_stride;
  float ss = 0.f;
  for (int c = threadIdx.x; c < ncols; c += 256) { float v = xr[c]; ss = fmaf(v, v, ss); }
  for (int off = 1; off < 64; off <<= 1) ss += __shfl_xor(ss, off);
  __shared__ float red[4];
  if ((threadIdx.x & 63) == 0) red[threadIdx.x >> 6] = ss;
  __syncthreads();
  float tot = red[0] + red[1] + red[2] + red[3];
  float scale = rsqrtf(tot / (float)ncols + eps);
  for (int c = threadIdx.x; c < ncols; c += 256)
    out[(size_t)row * ncols + c] = xr[c] * scale * w[c];
}

// ---------------- Tiled GEMM: C[M,N] (+)= A[M,K] @ B[N,K]^T ----------------
template <int MODE>
__global__ __launch_bounds__(256) void k_gemm(const float* __restrict__ A,
                                              const float* __restrict__ B,
                                              float* __restrict__ C,
                                              int M, int N, int K) {
  __shared__ float As[64][17];
  __shared__ float Bs[64][17];
  int bm = blockIdx.y * 64, bn = blockIdx.x * 64;
  int tx = threadIdx.x & 15, ty = threadIdx.x >> 4;
  float acc[4][4] = {};
  for (int k0 = 0; k0 < K; k0 += 16) {
    for (int i = threadIdx.x; i < 1024; i += 256) {
      int m = i >> 4, kk = i & 15;
      int gm = bm + m;
      As[m][kk] = (gm < M) ? A[(size_t)gm * K + k0 + kk] : 0.f;
      int gn = bn + m;
      Bs[m][kk] = (gn < N) ? B[(size_t)gn * K + k0 + kk] : 0.f;
    }
    __syncthreads();
#pragma unroll
    for (int kk = 0; kk < 16; kk++) {
      float a[4], b[4];
#pragma unroll
      for (int i = 0; i < 4; i++) a[i] = As[ty * 4 + i][kk];
#pragma unroll
      for (int j = 0; j < 4; j++) b[j] = Bs[tx * 4 + j][kk];
#pragma unroll
      for (int i = 0; i < 4; i++)
#pragma unroll
        for (int j = 0; j < 4; j++) acc[i][j] = fmaf(a[i], b[j], acc[i][j]);
    }
    __syncthreads();
  }
#pragma unroll
  for (int i = 0; i < 4; i++) {
    int gm = bm + ty * 4 + i;
    if (gm >= M) continue;
#pragma unroll
    for (int j = 0; j < 4; j++) {
      int gn = bn + tx * 4 + j;
      if (gn >= N) continue;
      if (MODE) C[(size_t)gm * N + gn] += acc[i][j];
      else      C[(size_t)gm * N + gn] = acc[i][j];
    }
  }
}

// ---------------- Assemble q/k (partial RoPE) and v ----------------
__global__ __launch_bounds__(256) void k_qkv(const float* __restrict__ qf,
                                             const float* __restrict__ kvb,
                                             const float* __restrict__ ckv,
                                             const float* __restrict__ cosb,
                                             const float* __restrict__ sinb,
                                             float* __restrict__ qh,
                                             float* __restrict__ kh,
                                             float* __restrict__ vb) {
  int t = blockIdx.x;
  int l = t >> 3;
  for (int idx = threadIdx.x; idx < 768; idx += 256) {
    int hh = idx / 48, dc = idx % 48;
    int hd = hh >> 1, e = hh & 1;
    float qv, kvv;
    if (dc < 32) {
      qv  = qf [(size_t)t * 768  + hd * 96  + e * 32 + dc];
      kvv = kvb[(size_t)t * 1024 + hd * 128 + e * 32 + dc];
    } else {
      int rj = dc - 32;            // 0..15
      int p = rj >> 1; int isim = rj & 1;
      float xr_q = qf[(size_t)t * 768 + hd * 96 + 64 + e * 16 + p * 2];
      float xi_q = qf[(size_t)t * 768 + hd * 96 + 64 + e * 16 + p * 2 + 1];
      float xr_k = ckv[(size_t)t * 160 + 128 + e * 16 + p * 2];
      float xi_k = ckv[(size_t)t * 160 + 128 + e * 16 + p * 2 + 1];
      if (l == 0) {
        qv  = isim ? xi_q : xr_q;
        kvv = isim ? xi_k : xr_k;
      } else {
        float c = cosb[(l - 1) * 8 + p], s = sinb[(l - 1) * 8 + p];
        if (!isim) { qv = xr_q * c - xi_q * s; kvv = xr_k * c - xi_k * s; }
        else       { qv = xr_q * s + xi_q * c; kvv = xr_k * s + xi_k * c; }
      }
    }
    qh[(size_t)t * 768 + idx] = qv;
    kh[(size_t)t * 768 + idx] = kvv;
  }
  for (int idx = threadIdx.x; idx < 512; idx += 256) {
    int hd = idx >> 6, dv = idx & 63;
    vb[(size_t)t * 512 + idx] = kvb[(size_t)t * 1024 + hd * 128 + 64 + dv];
  }
}

// ---------------- lambda scalar ----------------
__global__ void k_lam(const float* __restrict__ lq1, const float* __restrict__ lk1,
                      const float* __restrict__ lq2, const float* __restrict__ lk2,
                      float lamc, float* __restrict__ out) {
  float d1 = 0.f, d2 = 0.f;
  for (int k = 0; k < 32; k++) { d1 = fmaf(lq1[k], lk1[k], d1); d2 = fmaf(lq2[k], lk2[k], d2); }
  out[0] = expf(d1) - expf(d2) + lamc;
}

// ---------------- Scores GEMM (head pair; both heads via blockIdx.z) ----------------
__global__ __launch_bounds__(256) void k_scores_gemm(const float* __restrict__ qh,
                                                     const float* __restrict__ kh,
                                                     float* __restrict__ probs, int hh0) {
  int e = blockIdx.z;
  int hh = hh0 + e;
  const float* A = qh + hh * 48;
  const float* Bm = kh + hh * 48;
  float* C = probs + (size_t)e * Tn * Tn;
  __shared__ float As[64][17];
  __shared__ float Bs[64][17];
  int bm = blockIdx.y * 64, bn = blockIdx.x * 64;
  int tx = threadIdx.x & 15, ty = threadIdx.x >> 4;
  float acc[4][4] = {};
  for (int k0 = 0; k0 < 48; k0 += 16) {
    for (int i = threadIdx.x; i < 1024; i += 256) {
      int m = i >> 4, kk = i & 15;
      int gm = bm + m;
      As[m][kk] = (gm < Tn) ? A[(size_t)gm * 768 + k0 + kk] : 0.f;
      int gn = bn + m;
      Bs[m][kk] = (gn < Tn) ? Bm[(size_t)gn * 768 + k0 + kk] : 0.f;
    }
    __syncthreads();
#pragma unroll
    for (int kk = 0; kk < 16; kk++) {
      float a[4], b[4];
#pragma unroll
      for (int i = 0; i < 4; i++) a[i] = As[ty * 4 + i][kk];
#pragma unroll
      for (int j = 0; j < 4; j++) b[j] = Bs[tx * 4 + j][kk];
#pragma unroll
      for (int i = 0; i < 4; i++)
#pragma unroll
        for (int j = 0; j < 4; j++) acc[i][j] = fmaf(a[i], b[j], acc[i][j]);
    }
    __syncthreads();
  }
#pragma unroll
  for (int i = 0; i < 4; i++) {
    int gm = bm + ty * 4 + i;
    if (gm >= Tn) continue;
    int imod = gm % LPn;
#pragma unroll
    for (int j = 0; j < 4; j++) {
      int gn = bn + tx * 4 + j;
      if (gn >= Tn) continue;
      float sv = ((gn % LPn) > imod) ? -1e9f : acc[i][j] * SCALING_C;
      C[(size_t)gm * Tn + gn] = sv;
    }
  }
}

// ---------------- Row softmax in-place (2 heads) ----------------
__global__ __launch_bounds__(256) void k_softmax_rows(float* __restrict__ probs) {
  float* prow = probs + ((size_t)blockIdx.y * Tn + blockIdx.x) * Tn;
  int tid = threadIdx.x;
  float v[9];
  float lmax = -3.4e38f;
#pragma unroll
  for (int it = 0; it < 9; it++) {
    int j = tid + it * 256;
    v[it] = (j < Tn) ? prow[j] : -3.4e38f;
    lmax = fmaxf(lmax, v[it]);
  }
  for (int off = 1; off < 64; off <<= 1) lmax = fmaxf(lmax, __shfl_xor(lmax, off));
  __shared__ float red[4];
  if ((tid & 63) == 0) red[tid >> 6] = lmax;
  __syncthreads();
  float gmax = fmaxf(fmaxf(red[0], red[1]), fmaxf(red[2], red[3]));
  __syncthreads();
  float lsum = 0.f;
#pragma unroll
  for (int it = 0; it < 9; it++) { v[it] = expf(v[it] - gmax); lsum += v[it]; }
  for (int off = 1; off < 64; off <<= 1) lsum += __shfl_xor(lsum, off);
  if ((tid & 63) == 0) red[tid >> 6] = lsum;
  __syncthreads();
  float inv = 1.f / (red[0] + red[1] + red[2] + red[3]);
#pragma unroll
  for (int it = 0; it < 9; it++) {
    int j = tid + it * 256;
    if (j < Tn) prow[j] = v[it] * inv;
  }
}

// ---------------- Column mean of a1 (two-stage) ----------------
__global__ __launch_bounds__(256) void k_colmean_part(const float* __restrict__ a1,
                                                      float* __restrict__ partial) {
  int j = blockIdx.x * 256 + threadIdx.x;
  int ib = blockIdx.y;
  if (j >= Tn) return;
  int i0 = ib * 64, i1 = min(i0 + 64, Tn);
  float acc = 0.f;
  for (int i = i0; i < i1; i++) acc += a1[(size_t)i * Tn + j];
  partial[(size_t)ib * Tn + j] = acc;
}

// writes g[j] = lam * mean_i(a1[i][j])   (lam folded in)
__global__ __launch_bounds__(256) void k_colmean2(const float* __restrict__ partial,
                                                  const float* __restrict__ lamp,
                                                  float* __restrict__ g) {
  int j = blockIdx.x * 256 + threadIdx.x;
  if (j >= Tn) return;
  float acc = 0.f;
  for (int ib = 0; ib < 33; ib++) acc += partial[(size_t)ib * Tn + j];
  g[j] = acc * (1.f / (float)Tn) * lamp[0];
}

// ---------------- W[jmod][dv] = sum_{k} g[jmod+257k] * V[jmod+257k][dv] ----------------
__global__ __launch_bounds__(64) void k_wv(const float* __restrict__ g,
                                           const float* __restrict__ vb,
                                           float* __restrict__ Wb, int ph) {
  int jmod = blockIdx.x;        // 0..256
  int lane = threadIdx.x;       // 0..63
  float acc = 0.f;
#pragma unroll
  for (int k = 0; k < 8; k++) {
    int j = jmod + 257 * k;
    acc = fmaf(g[j], vb[(size_t)j * 512 + ph * 64 + lane], acc);
  }
  Wb[jmod * 64 + lane] = acc;
}

// ---------------- G[imod][dv] = sum_{m<=imod} W[m][dv] ----------------
__global__ __launch_bounds__(64) void k_gprefix(const float* __restrict__ Wb,
                                                float* __restrict__ G) {
  int imod = blockIdx.x;        // 0..256
  int lane = threadIdx.x;
  float acc = 0.f;
  for (int m = 0; m <= imod; m++) acc += Wb[m * 64 + lane];
  G[imod * 64 + lane] = acc;
}

// ---------------- PV partial GEMM: K-split; A staged as a1 - lam*a2 ----------------
__global__ __launch_bounds__(256) void k_pv_part(const float* __restrict__ probs,
                                                 const float* __restrict__ vb,
                                                 const float* __restrict__ lamp,
                                                 float* __restrict__ pvpart, int ph) {
  __shared__ float As[64][17];
  __shared__ float Bs[64][17];
  int bm = blockIdx.x * 64;
  int kc = blockIdx.y;                 // 0..7
  int kbase = kc * 257;
  float lam = lamp[0];
  const float* p0 = probs;
  const float* p1 = probs + (size_t)Tn * Tn;
  int tx = threadIdx.x & 15, ty = threadIdx.x >> 4;
  float acc[4][4] = {};
  for (int k0 = 0; k0 < 257; k0 += 16) {
    for (int i = threadIdx.x; i < 1024; i += 256) {
      int m = i >> 4, kk = i & 15;
      int gm = bm + m;
      int gk = kbase + k0 + kk;
      bool ok = (gm < Tn) && (k0 + kk < 257);
      As[m][kk] = ok ? fmaf(-lam, p1[(size_t)gm * Tn + gk], p0[(size_t)gm * Tn + gk]) : 0.f;
    }
    for (int i = threadIdx.x; i < 1024; i += 256) {
      int kk = i >> 6, nn = i & 63;
      int gk = kbase + k0 + kk;
      Bs[nn][kk] = (k0 + kk < 257) ? vb[(size_t)gk * 512 + ph * 64 + nn] : 0.f;
    }
    __syncthreads();
#pragma unroll
    for (int kk = 0; kk < 16; kk++) {
      float a[4], b[4];
#pragma unroll
      for (int i = 0; i < 4; i++) a[i] = As[ty * 4 + i][kk];
#pragma unroll
      for (int j = 0; j < 4; j++) b[j] = Bs[tx * 4 + j][kk];
#pragma unroll
      for (int i = 0; i < 4; i++)
#pragma unroll
        for (int j = 0; j < 4; j++) acc[i][j] = fmaf(a[i], b[j], acc[i][j]);
    }
    __syncthreads();
  }
#pragma unroll
  for (int i = 0; i < 4; i++) {
    int gm = bm + ty * 4 + i;
    if (gm >= Tn) continue;
#pragma unroll
    for (int j = 0; j < 4; j++)
      pvpart[((size_t)kc * Tn + gm) * 64 + tx * 4 + j] = acc[i][j];
  }
}

// ---------------- reduce K-split partials + G-term + head-RMSNorm ----------------
__global__ __launch_bounds__(256) void k_pv_reduce(const float* __restrict__ pvpart,
                                                   const float* __restrict__ G,
                                                   const float* __restrict__ hnw,
                                                   float* __restrict__ onorm, int ph) {
  int w = threadIdx.x >> 6, lane = threadIdx.x & 63;
  int i = blockIdx.x * 4 + w;          // grid 514 -> 2056 rows
  float s = G[(i % LPn) * 64 + lane];
#pragma unroll
  for (int kc = 0; kc < 8; kc++) s += pvpart[((size_t)kc * Tn + i) * 64 + lane];
  float ss = s * s;
  for (int off = 1; off < 64; off <<= 1) ss += __shfl_xor(ss, off);
  float scale = rsqrtf(ss * (1.f / 64.f) + 1e-5f);
  onorm[((size_t)ph * Tn + i) * 64 + lane] = s * scale * hnw[lane];
}

// ---------------- SwiGLU ----------------
__global__ __launch_bounds__(256) void k_swiglu(const float* __restrict__ uv,
                                                float* __restrict__ gated) {
  size_t idx = (size_t)blockIdx.x * 256 + threadIdx.x;
  if (idx >= (size_t)Tn * 2048) return;
  size_t t = idx / 2048, f = idx % 2048;
  float u = uv[t * 4096 + f];
  float vv = uv[t * 4096 + 2048 + f];
  float sv = vv / (1.f + expf(-vv));
  gated[idx] = u * sv;
}

// ---------------- final head (float32 out) ----------------
__global__ __launch_bounds__(192) void k_final(const float* __restrict__ z,
                                               const float* __restrict__ outW,
                                               float* __restrict__ out) {
  int t = blockIdx.x;
  int p = threadIdx.x >> 6, lane = threadIdx.x & 63;
  float acc = 0.f;
  for (int m = lane; m < 512; m += 64) acc = fmaf(z[(size_t)t * 512 + m], outW[(size_t)p * 512 + m], acc);
  for (int off = 1; off < 64; off <<= 1) acc += __shfl_xor(acc, off);
  if (lane == 0) out[(size_t)t * 3 + p] = acc;
}

extern "C" void kernel_launch(void* const* d_in, const int* in_sizes, int n_in,
                              void* d_out, int out_size, void* d_ws, size_t ws_size,
                              hipStream_t stream) {
  const float* x          = (const float*)d_in[0];
  const float* ticker_emb = (const float*)d_in[1];
  const float* sep_emb    = (const float*)d_in[2];
  const float* shared_W   = (const float*)d_in[3];
  const float* unique_W   = (const float*)d_in[4];
  const float* norm1_w    = (const float*)d_in[5];
  const float* norm2_w    = (const float*)d_in[6];
  const float* kv_down_W  = (const float*)d_in[7];
  const float* q_down_W   = (const float*)d_in[8];
  const float* kv_up_W    = (const float*)d_in[9];
  const float* q_up_W     = (const float*)d_in[10];
  const float* kv_norm_w  = (const float*)d_in[11];
  const float* q_norm_w   = (const float*)d_in[12];
  const float* o_W        = (const float*)d_in[13];
  const float* lam_q1     = (const float*)d_in[14];
  const float* lam_k1     = (const float*)d_in[15];
  const float* lam_q2     = (const float*)d_in[16];
  const float* lam_k2     = (const float*)d_in[17];
  const float* head_norm_w= (const float*)d_in[18];
  const float* ff_in_W    = (const float*)d_in[19];
  const float* ff_out_W   = (const float*)d_in[20];
  const float* final_norm = (const float*)d_in[21];
  const float* out_W      = (const float*)d_in[22];
  const int*   seperator  = (const int*)d_in[23];
  const int*   tickers    = (const int*)d_in[24];
  (void)in_sizes; (void)n_in;

  float* W = (float*)d_ws;
  size_t off = 0;
  auto alloc = [&](size_t n) { float* p = W + off; off += n; return p; };
  float* cosb  = alloc(256 * 8);
  float* sinb  = alloc(256 * 8);
  float* h     = alloc((size_t)Tn * Dn);
  float* xn    = alloc((size_t)Tn * Dn);          // also z
  float* ckv   = alloc((size_t)Tn * 160);         // region also hosts onorm later
  float* ckvn  = alloc((size_t)Tn * 128);
  float* qlat  = alloc((size_t)Tn * 192);
  float* qlatn = alloc((size_t)Tn * 192);
  float* kvb   = alloc((size_t)Tn * 1024);        // region also hosts gated later
  float* qf    = alloc((size_t)Tn * 768);         // also hosts pvpart in attn loop
  float* qh    = alloc((size_t)Tn * 768);
  float* kh    = alloc((size_t)Tn * 768);
  float* vb    = alloc((size_t)Tn * 512);
  float* g     = alloc(Tn);
  float* lam   = alloc(1);
  float* partial = alloc((size_t)33 * Tn);        // also hosts Wb/Gb (disjoint in-iter lifetime)
  float* probs = alloc((size_t)2 * Tn * Tn);      // also hosts uv
  // overlays (disjoint lifetimes, all OUTSIDE the onorm region):
  float* onorm = ckv;        // (8, T, 64) = 1.05M floats over ckv..qlatn (all dead in attn loop)
  float* z     = xn;
  float* uv    = probs;
  float* gated = kvb;
  float* pvpart = qf;        // [8][T][64] = 1.05M <= 1.58M floats (qf dead post-k_qkv)
  float* Wb    = partial;             // 257*64 = 16448 floats
  float* Gb    = partial + 257 * 64;  // 257*64; total 32896 <= 33*Tn = 67848 floats

  size_t needed = off * sizeof(float);            // ~79.5 MB (proven available)
  if (ws_size < needed) {
    k_fill42<<<(out_size + 255) / 256, 256, 0, stream>>>((float*)d_out, out_size);
    return;
  }

  k_freqs<<<8, 256, 0, stream>>>(cosb, sinb);
  k_embed<<<dim3(Tn, 2), 256, 0, stream>>>(x, ticker_emb, sep_emb, shared_W, unique_W,
                                           seperator, tickers, h);

  for (int d = 0; d < 2; d++) {
    const float* n1   = norm1_w + d * 512;
    const float* n2   = norm2_w + d * 512;
    const float* kvd  = kv_down_W + (size_t)d * 160 * 512;
    const float* qd   = q_down_W + (size_t)d * 192 * 512;
    const float* kvu  = kv_up_W + (size_t)d * 1024 * 128;
    const float* qu   = q_up_W + (size_t)d * 768 * 192;
    const float* kvnw = kv_norm_w + d * 128;
    const float* qnw  = q_norm_w + d * 192;
    const float* oW   = o_W + (size_t)d * 512 * 512;
    const float* hnw  = head_norm_w + d * 64;
    const float* ffi  = ff_in_W + (size_t)d * 4096 * 512;
    const float* ffo  = ff_out_W + (size_t)d * 512 * 2048;
    float lamc = 0.8f - 0.6f * expf(-0.3f * (float)d);

    k_rmsnorm<<<Tn, 256, 0, stream>>>(h, n1, xn, 512, 512, EPS_C);
    k_gemm<0><<<dim3(3, 33), 256, 0, stream>>>(xn, kvd, ckv, Tn, 160, 512);
    k_rmsnorm<<<Tn, 256, 0, stream>>>(ckv, kvnw, ckvn, 128, 160, EPS_C);
    k_gemm<0><<<dim3(16, 33), 256, 0, stream>>>(ckvn, kvu, kvb, Tn, 1024, 128);
    k_gemm<0><<<dim3(3, 33), 256, 0, stream>>>(xn, qd, qlat, Tn, 192, 512);
    k_rmsnorm<<<Tn, 256, 0, stream>>>(qlat, qnw, qlatn, 192, 192, EPS_C);
    k_gemm<0><<<dim3(12, 33), 256, 0, stream>>>(qlatn, qu, qf, Tn, 768, 192);
    k_qkv<<<Tn, 256, 0, stream>>>(qf, kvb, ckv, cosb, sinb, qh, kh, vb);
    k_lam<<<1, 1, 0, stream>>>(lam_q1 + d * 32, lam_k1 + d * 32,
                               lam_q2 + d * 32, lam_k2 + d * 32, lamc, lam);

    for (int ph = 0; ph < 8; ph++) {
      k_scores_gemm<<<dim3(33, 33, 2), 256, 0, stream>>>(qh, kh, probs, 2 * ph);
      k_softmax_rows<<<dim3(Tn, 2), 256, 0, stream>>>(probs);
      k_colmean_part<<<dim3(9, 33), 256, 0, stream>>>(probs, partial);
      k_colmean2<<<9, 256, 0, stream>>>(partial, lam, g);
      k_wv<<<257, 64, 0, stream>>>(g, vb, Wb, ph);
      k_gprefix<<<257, 64, 0, stream>>>(Wb, Gb);
      k_pv_part<<<dim3(33, 8), 256, 0, stream>>>(probs, vb, lam, pvpart, ph);
      k_pv_reduce<<<514, 256, 0, stream>>>(pvpart, Gb, hnw, onorm, ph);
    }

    k_gemm<1><<<dim3(8, 33), 256, 0, stream>>>(onorm, oW, h, Tn, 512, 512);   // h += o-proj
    k_rmsnorm<<<Tn, 256, 0, stream>>>(h, n2, z, 512, 512, EPS_C);
    k_gemm<0><<<dim3(64, 33), 256, 0, stream>>>(z, ffi, uv, Tn, 4096, 512);
    k_swiglu<<<16448, 256, 0, stream>>>(uv, gated);
    k_gemm<1><<<dim3(8, 33), 256, 0, stream>>>(gated, ffo, h, Tn, 512, 2048); // h += ffn
  }

  k_rmsnorm<<<Tn, 256, 0, stream>>>(h, final_norm, z, 512, 512, EPS_C);
  k_final<<<Tn, 192, 0, stream>>>(z, out_W, (float*)d_out);
}

// Round 8
// 3536.308 us; speedup vs baseline: 2.7554x; 1.4077x over previous
//
#include <hip/hip_runtime.h>
#include <hip/hip_bf16.h>

// Money_former MLA DINT — round 8: weight GEMMs -> bf16 MFMA (16x16x32, f32 acc).
// rmsnorm/swiglu/pv_reduce write bf16 A-operands directly; weights converted
// per layer (k_tobf16). Attention scores/softmax/PV cluster stays f32.
// Arena 77.1 MB (overlays: gatedb->kvb, late weights->qh+kh, onormb->ckv,
// zb->xnb, zfin->vb). T=2056, D=512, 2 layers, 16 logical heads of 48.

#define Tn 2056
#define LPn 257
#define Dn 512

static constexpr float SCALING_C = 0.14433756729740643f;   // 48^-0.5
static constexpr float EPS_C     = 1.1920928955078125e-07f;

typedef float f32x4 __attribute__((ext_vector_type(4)));
typedef short bf16x8 __attribute__((ext_vector_type(8)));
typedef unsigned short u16x8 __attribute__((ext_vector_type(8)));

// ---------------- sentinel ----------------
__global__ __launch_bounds__(256) void k_fill42(float* __restrict__ out, int n) {
  int i = blockIdx.x * 256 + threadIdx.x;
  if (i < n) out[i] = 42.0f;
}

// ---------------- f32 -> bf16 convert (grid-stride) ----------------
__global__ __launch_bounds__(256) void k_tobf16(const float* __restrict__ src,
                                                __hip_bfloat16* __restrict__ dst, long n) {
  long i = (long)blockIdx.x * 256 + threadIdx.x;
  long stride = (long)gridDim.x * 256;
  for (; i < n; i += stride) dst[i] = __float2bfloat16(src[i]);
}

// ---------------- RoPE tables ----------------
__global__ __launch_bounds__(256) void k_freqs(float* __restrict__ cosb, float* __restrict__ sinb) {
  int idx = blockIdx.x * 256 + threadIdx.x;
  if (idx >= 256 * 8) return;
  int pos = idx >> 3, j = idx & 7;
  float fb = powf(10000.f, -(float)j * 0.125f);            // 1/10000^(j/8)
  float ramp = fminf(fmaxf((float)j * 0.25f, 0.f), 1.f);   // low=0, high=4
  float sm = 1.f - ramp;
  float fr = fb * (1.f / 40.f) * (1.f - sm) + fb * sm;
  float ang = (float)pos * fr;
  cosb[idx] = cosf(ang);
  sinb[idx] = sinf(ang);
}

// ---------------- Embedding ----------------
__global__ __launch_bounds__(256) void k_embed(const float* __restrict__ x,
                                               const float* __restrict__ ticker_emb,
                                               const float* __restrict__ sep_emb,
                                               const float* __restrict__ shared_W,
                                               const float* __restrict__ unique_W,
                                               const int* __restrict__ sep_idx,
                                               const int* __restrict__ tickers,
                                               float* __restrict__ h) {
  int t = blockIdx.x;
  int c = blockIdx.y * 256 + threadIdx.x;
  int l = t >> 3, s = t & 7;
  float val;
  if (l == 0) {
    val = sep_emb[sep_idx[0] * Dn + c];
  } else {
    const float* xr = x + ((size_t)(l - 1) * 8 + s) * 32;
    const float* w = (c < 384) ? (shared_W + (size_t)c * 32)
                               : (unique_W + ((size_t)s * 128 + (c - 384)) * 32);
    float acc = 0.f;
#pragma unroll
    for (int f = 0; f < 32; f++) acc = fmaf(xr[f], w[f], acc);
    val = acc;
  }
  val += ticker_emb[(size_t)tickers[s] * Dn + c];
  h[(size_t)t * Dn + c] = val;
}

// ---------------- Row RMSNorm, f32 out ----------------
__global__ __launch_bounds__(256) void k_rmsnorm(const float* __restrict__ in,
                                                 const float* __restrict__ w,
                                                 float* __restrict__ out,
                                                 int ncols, int in_stride, float eps) {
  int row = blockIdx.x;
  const float* xr = in + (size_t)row * in_stride;
  float ss = 0.f;
  for (int c = threadIdx.x; c < ncols; c += 256) { float v = xr[c]; ss = fmaf(v, v, ss); }
  for (int off = 1; off < 64; off <<= 1) ss += __shfl_xor(ss, off);
  __shared__ float red[4];
  if ((threadIdx.x & 63) == 0) red[threadIdx.x >> 6] = ss;
  __syncthreads();
  float tot = red[0] + red[1] + red[2] + red[3];
  float scale = rsqrtf(tot / (float)ncols + eps);
  for (int c = threadIdx.x; c < ncols; c += 256)
    out[(size_t)row * ncols + c] = xr[c] * scale * w[c];
}

// ---------------- Row RMSNorm, bf16 out ----------------
__global__ __launch_bounds__(256) void k_rmsnorm_b(const float* __restrict__ in,
                                                   const float* __restrict__ w,
                                                   __hip_bfloat16* __restrict__ out,
                                                   int ncols, int in_stride, float eps) {
  int row = blockIdx.x;
  const float* xr = in + (size_t)row * in_stride;
  float ss = 0.f;
  for (int c = threadIdx.x; c < ncols; c += 256) { float v = xr[c]; ss = fmaf(v, v, ss); }
  for (int off = 1; off < 64; off <<= 1) ss += __shfl_xor(ss, off);
  __shared__ float red[4];
  if ((threadIdx.x & 63) == 0) red[threadIdx.x >> 6] = ss;
  __syncthreads();
  float tot = red[0] + red[1] + red[2] + red[3];
  float scale = rsqrtf(tot / (float)ncols + eps);
  for (int c = threadIdx.x; c < ncols; c += 256)
    out[(size_t)row * ncols + c] = __float2bfloat16(xr[c] * scale * w[c]);
}

// ---------------- MFMA GEMM: C[M,N] (+)= A[M,K] @ B[N,K]^T  (bf16 in, f32 acc) ----------------
// Block 256 = 4 waves; tile 128(M) x 64(N); wave w covers rows w*32..+31.
// LDS rows padded to 40 shorts (bank-friendly). Verified C/D map:
// col = lane&15, row = (lane>>4)*4 + reg.
template <int MODE>
__global__ __launch_bounds__(256) void k_gemm_mfma(const __hip_bfloat16* __restrict__ A,
                                                   const __hip_bfloat16* __restrict__ B,
                                                   float* __restrict__ C,
                                                   int M, int N, int K) {
  __shared__ unsigned short Als[128][40];
  __shared__ unsigned short Bls[64][40];
  int bm = blockIdx.y * 128, bn = blockIdx.x * 64;
  int tid = threadIdx.x;
  int wave = tid >> 6, lane = tid & 63;
  int lrow = lane & 15, lgrp = lane >> 4;
  f32x4 acc[2][4] = {};
  for (int k0 = 0; k0 < K; k0 += 32) {
#pragma unroll
    for (int i = 0; i < 2; i++) {          // A: 512 x 16B vectors, 2 per thread
      int vecIdx = tid + i * 256;
      int row = vecIdx >> 2, cg = vecIdx & 3;
      u16x8 v = {0, 0, 0, 0, 0, 0, 0, 0};
      int grow = bm + row;
      if (grow < M) v = *reinterpret_cast<const u16x8*>(A + (size_t)grow * K + k0 + cg * 8);
      *reinterpret_cast<u16x8*>(&Als[row][cg * 8]) = v;
    }
    {                                      // B: 256 x 16B vectors, 1 per thread
      int row = tid >> 2, cg = tid & 3;
      u16x8 v = {0, 0, 0, 0, 0, 0, 0, 0};
      int gcol = bn + row;
      if (gcol < N) v = *reinterpret_cast<const u16x8*>(B + (size_t)gcol * K + k0 + cg * 8);
      *reinterpret_cast<u16x8*>(&Bls[row][cg * 8]) = v;
    }
    __syncthreads();
    bf16x8 af[2], bfr[4];
#pragma unroll
    for (int mi = 0; mi < 2; mi++)
      af[mi] = *reinterpret_cast<const bf16x8*>(&Als[wave * 32 + mi * 16 + lrow][lgrp * 8]);
#pragma unroll
    for (int ni = 0; ni < 4; ni++)
      bfr[ni] = *reinterpret_cast<const bf16x8*>(&Bls[ni * 16 + lrow][lgrp * 8]);
#pragma unroll
    for (int mi = 0; mi < 2; mi++)
#pragma unroll
      for (int ni = 0; ni < 4; ni++)
        acc[mi][ni] = __builtin_amdgcn_mfma_f32_16x16x32_bf16(af[mi], bfr[ni], acc[mi][ni], 0, 0, 0);
    __syncthreads();
  }
#pragma unroll
  for (int mi = 0; mi < 2; mi++)
#pragma unroll
    for (int ni = 0; ni < 4; ni++)
#pragma unroll
      for (int r = 0; r < 4; r++) {
        int row = bm + wave * 32 + mi * 16 + lgrp * 4 + r;
        int col = bn + ni * 16 + lrow;
        if (row < M && col < N) {
          if (MODE) C[(size_t)row * N + col] += acc[mi][ni][r];
          else      C[(size_t)row * N + col] = acc[mi][ni][r];
        }
      }
}

// ---------------- Assemble q/k (partial RoPE) and v ----------------
__global__ __launch_bounds__(256) void k_qkv(const float* __restrict__ qf,
                                             const float* __restrict__ kvb,
                                             const float* __restrict__ ckv,
                                             const float* __restrict__ cosb,
                                             const float* __restrict__ sinb,
                                             float* __restrict__ qh,
                                             float* __restrict__ kh,
                                             float* __restrict__ vb) {
  int t = blockIdx.x;
  int l = t >> 3;
  for (int idx = threadIdx.x; idx < 768; idx += 256) {
    int hh = idx / 48, dc = idx % 48;
    int hd = hh >> 1, e = hh & 1;
    float qv, kvv;
    if (dc < 32) {
      qv  = qf [(size_t)t * 768  + hd * 96  + e * 32 + dc];
      kvv = kvb[(size_t)t * 1024 + hd * 128 + e * 32 + dc];
    } else {
      int rj = dc - 32;            // 0..15
      int p = rj >> 1; int isim = rj & 1;
      float xr_q = qf[(size_t)t * 768 + hd * 96 + 64 + e * 16 + p * 2];
      float xi_q = qf[(size_t)t * 768 + hd * 96 + 64 + e * 16 + p * 2 + 1];
      float xr_k = ckv[(size_t)t * 160 + 128 + e * 16 + p * 2];
      float xi_k = ckv[(size_t)t * 160 + 128 + e * 16 + p * 2 + 1];
      if (l == 0) {
        qv  = isim ? xi_q : xr_q;
        kvv = isim ? xi_k : xr_k;
      } else {
        float c = cosb[(l - 1) * 8 + p], s = sinb[(l - 1) * 8 + p];
        if (!isim) { qv = xr_q * c - xi_q * s; kvv = xr_k * c - xi_k * s; }
        else       { qv = xr_q * s + xi_q * c; kvv = xr_k * s + xi_k * c; }
      }
    }
    qh[(size_t)t * 768 + idx] = qv;
    kh[(size_t)t * 768 + idx] = kvv;
  }
  for (int idx = threadIdx.x; idx < 512; idx += 256) {
    int hd = idx >> 6, dv = idx & 63;
    vb[(size_t)t * 512 + idx] = kvb[(size_t)t * 1024 + hd * 128 + 64 + dv];
  }
}

// ---------------- lambda scalar ----------------
__global__ void k_lam(const float* __restrict__ lq1, const float* __restrict__ lk1,
                      const float* __restrict__ lq2, const float* __restrict__ lk2,
                      float lamc, float* __restrict__ out) {
  float d1 = 0.f, d2 = 0.f;
  for (int k = 0; k < 32; k++) { d1 = fmaf(lq1[k], lk1[k], d1); d2 = fmaf(lq2[k], lk2[k], d2); }
  out[0] = expf(d1) - expf(d2) + lamc;
}

// ---------------- Scores GEMM (head pair; both heads via blockIdx.z) ----------------
__global__ __launch_bounds__(256) void k_scores_gemm(const float* __restrict__ qh,
                                                     const float* __restrict__ kh,
                                                     float* __restrict__ probs, int hh0) {
  int e = blockIdx.z;
  int hh = hh0 + e;
  const float* A = qh + hh * 48;
  const float* Bm = kh + hh * 48;
  float* C = probs + (size_t)e * Tn * Tn;
  __shared__ float As[64][17];
  __shared__ float Bs[64][17];
  int bm = blockIdx.y * 64, bn = blockIdx.x * 64;
  int tx = threadIdx.x & 15, ty = threadIdx.x >> 4;
  float acc[4][4] = {};
  for (int k0 = 0; k0 < 48; k0 += 16) {
    for (int i = threadIdx.x; i < 1024; i += 256) {
      int m = i >> 4, kk = i & 15;
      int gm = bm + m;
      As[m][kk] = (gm < Tn) ? A[(size_t)gm * 768 + k0 + kk] : 0.f;
      int gn = bn + m;
      Bs[m][kk] = (gn < Tn) ? Bm[(size_t)gn * 768 + k0 + kk] : 0.f;
    }
    __syncthreads();
#pragma unroll
    for (int kk = 0; kk < 16; kk++) {
      float a[4], b[4];
#pragma unroll
      for (int i = 0; i < 4; i++) a[i] = As[ty * 4 + i][kk];
#pragma unroll
      for (int j = 0; j < 4; j++) b[j] = Bs[tx * 4 + j][kk];
#pragma unroll
      for (int i = 0; i < 4; i++)
#pragma unroll
        for (int j = 0; j < 4; j++) acc[i][j] = fmaf(a[i], b[j], acc[i][j]);
    }
    __syncthreads();
  }
#pragma unroll
  for (int i = 0; i < 4; i++) {
    int gm = bm + ty * 4 + i;
    if (gm >= Tn) continue;
    int imod = gm % LPn;
#pragma unroll
    for (int j = 0; j < 4; j++) {
      int gn = bn + tx * 4 + j;
      if (gn >= Tn) continue;
      float sv = ((gn % LPn) > imod) ? -1e9f : acc[i][j] * SCALING_C;
      C[(size_t)gm * Tn + gn] = sv;
    }
  }
}

// ---------------- Row softmax in-place (2 heads) ----------------
__global__ __launch_bounds__(256) void k_softmax_rows(float* __restrict__ probs) {
  float* prow = probs + ((size_t)blockIdx.y * Tn + blockIdx.x) * Tn;
  int tid = threadIdx.x;
  float v[9];
  float lmax = -3.4e38f;
#pragma unroll
  for (int it = 0; it < 9; it++) {
    int j = tid + it * 256;
    v[it] = (j < Tn) ? prow[j] : -3.4e38f;
    lmax = fmaxf(lmax, v[it]);
  }
  for (int off = 1; off < 64; off <<= 1) lmax = fmaxf(lmax, __shfl_xor(lmax, off));
  __shared__ float red[4];
  if ((tid & 63) == 0) red[tid >> 6] = lmax;
  __syncthreads();
  float gmax = fmaxf(fmaxf(red[0], red[1]), fmaxf(red[2], red[3]));
  __syncthreads();
  float lsum = 0.f;
#pragma unroll
  for (int it = 0; it < 9; it++) { v[it] = expf(v[it] - gmax); lsum += v[it]; }
  for (int off = 1; off < 64; off <<= 1) lsum += __shfl_xor(lsum, off);
  if ((tid & 63) == 0) red[tid >> 6] = lsum;
  __syncthreads();
  float inv = 1.f / (red[0] + red[1] + red[2] + red[3]);
#pragma unroll
  for (int it = 0; it < 9; it++) {
    int j = tid + it * 256;
    if (j < Tn) prow[j] = v[it] * inv;
  }
}

// ---------------- Column mean of a1 (two-stage) ----------------
__global__ __launch_bounds__(256) void k_colmean_part(const float* __restrict__ a1,
                                                      float* __restrict__ partial) {
  int j = blockIdx.x * 256 + threadIdx.x;
  int ib = blockIdx.y;
  if (j >= Tn) return;
  int i0 = ib * 64, i1 = min(i0 + 64, Tn);
  float acc = 0.f;
  for (int i = i0; i < i1; i++) acc += a1[(size_t)i * Tn + j];
  partial[(size_t)ib * Tn + j] = acc;
}

// writes g[j] = lam * mean_i(a1[i][j])
__global__ __launch_bounds__(256) void k_colmean2(const float* __restrict__ partial,
                                                  const float* __restrict__ lamp,
                                                  float* __restrict__ g) {
  int j = blockIdx.x * 256 + threadIdx.x;
  if (j >= Tn) return;
  float acc = 0.f;
  for (int ib = 0; ib < 33; ib++) acc += partial[(size_t)ib * Tn + j];
  g[j] = acc * (1.f / (float)Tn) * lamp[0];
}

// ---------------- W[jmod][dv] = sum_k g[jmod+257k] * V[jmod+257k][dv] ----------------
__global__ __launch_bounds__(64) void k_wv(const float* __restrict__ g,
                                           const float* __restrict__ vb,
                                           float* __restrict__ Wb, int ph) {
  int jmod = blockIdx.x;
  int lane = threadIdx.x;
  float acc = 0.f;
#pragma unroll
  for (int k = 0; k < 8; k++) {
    int j = jmod + 257 * k;
    acc = fmaf(g[j], vb[(size_t)j * 512 + ph * 64 + lane], acc);
  }
  Wb[jmod * 64 + lane] = acc;
}

// ---------------- G[imod][dv] = sum_{m<=imod} W[m][dv] ----------------
__global__ __launch_bounds__(64) void k_gprefix(const float* __restrict__ Wb,
                                                float* __restrict__ G) {
  int imod = blockIdx.x;
  int lane = threadIdx.x;
  float acc = 0.f;
  for (int m = 0; m <= imod; m++) acc += Wb[m * 64 + lane];
  G[imod * 64 + lane] = acc;
}

// ---------------- PV partial GEMM: K-split; A staged as a1 - lam*a2 ----------------
__global__ __launch_bounds__(256) void k_pv_part(const float* __restrict__ probs,
                                                 const float* __restrict__ vb,
                                                 const float* __restrict__ lamp,
                                                 float* __restrict__ pvpart, int ph) {
  __shared__ float As[64][17];
  __shared__ float Bs[64][17];
  int bm = blockIdx.x * 64;
  int kc = blockIdx.y;                 // 0..7
  int kbase = kc * 257;
  float lam = lamp[0];
  const float* p0 = probs;
  const float* p1 = probs + (size_t)Tn * Tn;
  int tx = threadIdx.x & 15, ty = threadIdx.x >> 4;
  float acc[4][4] = {};
  for (int k0 = 0; k0 < 257; k0 += 16) {
    for (int i = threadIdx.x; i < 1024; i += 256) {
      int m = i >> 4, kk = i & 15;
      int gm = bm + m;
      int gk = kbase + k0 + kk;
      bool ok = (gm < Tn) && (k0 + kk < 257);
      As[m][kk] = ok ? fmaf(-lam, p1[(size_t)gm * Tn + gk], p0[(size_t)gm * Tn + gk]) : 0.f;
    }
    for (int i = threadIdx.x; i < 1024; i += 256) {
      int kk = i >> 6, nn = i & 63;
      int gk = kbase + k0 + kk;
      Bs[nn][kk] = (k0 + kk < 257) ? vb[(size_t)gk * 512 + ph * 64 + nn] : 0.f;
    }
    __syncthreads();
#pragma unroll
    for (int kk = 0; kk < 16; kk++) {
      float a[4], b[4];
#pragma unroll
      for (int i = 0; i < 4; i++) a[i] = As[ty * 4 + i][kk];
#pragma unroll
      for (int j = 0; j < 4; j++) b[j] = Bs[tx * 4 + j][kk];
#pragma unroll
      for (int i = 0; i < 4; i++)
#pragma unroll
        for (int j = 0; j < 4; j++) acc[i][j] = fmaf(a[i], b[j], acc[i][j]);
    }
    __syncthreads();
  }
#pragma unroll
  for (int i = 0; i < 4; i++) {
    int gm = bm + ty * 4 + i;
    if (gm >= Tn) continue;
#pragma unroll
    for (int j = 0; j < 4; j++)
      pvpart[((size_t)kc * Tn + gm) * 64 + tx * 4 + j] = acc[i][j];
  }
}

// ---------------- reduce partials + G-term + head-RMSNorm -> bf16 ----------------
__global__ __launch_bounds__(256) void k_pv_reduce(const float* __restrict__ pvpart,
                                                   const float* __restrict__ G,
                                                   const float* __restrict__ hnw,
                                                   __hip_bfloat16* __restrict__ onormb, int ph) {
  int w = threadIdx.x >> 6, lane = threadIdx.x & 63;
  int i = blockIdx.x * 4 + w;          // grid 514 -> 2056 rows
  float s = G[(i % LPn) * 64 + lane];
#pragma unroll
  for (int kc = 0; kc < 8; kc++) s += pvpart[((size_t)kc * Tn + i) * 64 + lane];
  float ss = s * s;
  for (int off = 1; off < 64; off <<= 1) ss += __shfl_xor(ss, off);
  float scale = rsqrtf(ss * (1.f / 64.f) + 1e-5f);
  onormb[((size_t)ph * Tn + i) * 64 + lane] = __float2bfloat16(s * scale * hnw[lane]);
}

// ---------------- SwiGLU -> bf16 ----------------
__global__ __launch_bounds__(256) void k_swiglu(const float* __restrict__ uv,
                                                __hip_bfloat16* __restrict__ gatedb) {
  size_t idx = (size_t)blockIdx.x * 256 + threadIdx.x;
  if (idx >= (size_t)Tn * 2048) return;
  size_t t = idx / 2048, f = idx % 2048;
  float u = uv[t * 4096 + f];
  float vv = uv[t * 4096 + 2048 + f];
  float sv = vv / (1.f + expf(-vv));
  gatedb[idx] = __float2bfloat16(u * sv);
}

// ---------------- final head (float32 out) ----------------
__global__ __launch_bounds__(192) void k_final(const float* __restrict__ z,
                                               const float* __restrict__ outW,
                                               float* __restrict__ out) {
  int t = blockIdx.x;
  int p = threadIdx.x >> 6, lane = threadIdx.x & 63;
  float acc = 0.f;
  for (int m = lane; m < 512; m += 64) acc = fmaf(z[(size_t)t * 512 + m], outW[(size_t)p * 512 + m], acc);
  for (int off = 1; off < 64; off <<= 1) acc += __shfl_xor(acc, off);
  if (lane == 0) out[(size_t)t * 3 + p] = acc;
}

extern "C" void kernel_launch(void* const* d_in, const int* in_sizes, int n_in,
                              void* d_out, int out_size, void* d_ws, size_t ws_size,
                              hipStream_t stream) {
  const float* x          = (const float*)d_in[0];
  const float* ticker_emb = (const float*)d_in[1];
  const float* sep_emb    = (const float*)d_in[2];
  const float* shared_W   = (const float*)d_in[3];
  const float* unique_W   = (const float*)d_in[4];
  const float* norm1_w    = (const float*)d_in[5];
  const float* norm2_w    = (const float*)d_in[6];
  const float* kv_down_W  = (const float*)d_in[7];
  const float* q_down_W   = (const float*)d_in[8];
  const float* kv_up_W    = (const float*)d_in[9];
  const float* q_up_W     = (const float*)d_in[10];
  const float* kv_norm_w  = (const float*)d_in[11];
  const float* q_norm_w   = (const float*)d_in[12];
  const float* o_W        = (const float*)d_in[13];
  const float* lam_q1     = (const float*)d_in[14];
  const float* lam_k1     = (const float*)d_in[15];
  const float* lam_q2     = (const float*)d_in[16];
  const float* lam_k2     = (const float*)d_in[17];
  const float* head_norm_w= (const float*)d_in[18];
  const float* ff_in_W    = (const float*)d_in[19];
  const float* ff_out_W   = (const float*)d_in[20];
  const float* final_norm = (const float*)d_in[21];
  const float* out_W      = (const float*)d_in[22];
  const int*   seperator  = (const int*)d_in[23];
  const int*   tickers    = (const int*)d_in[24];
  (void)in_sizes; (void)n_in;

  float* W = (float*)d_ws;
  size_t off = 0;
  auto alloc = [&](size_t n) { float* p = W + off; off += n; return p; };
  float* cosb  = alloc(2048);
  float* sinb  = alloc(2048);
  float* h     = alloc((size_t)Tn * Dn);
  float* xnb_f = alloc((size_t)Tn * 256);         // bf16 T x 512 (also zb later)
  float* ckv   = alloc((size_t)Tn * 160);         // f32; later onormb (bf16 T x 512) overlay
  float* qlat  = alloc((size_t)Tn * 192);
  float* ckvnb_f = alloc((size_t)Tn * 64);        // bf16 T x 128
  float* qlatnb_f = alloc((size_t)Tn * 96);       // bf16 T x 192
  float* ewb_f = alloc(229376);                   // bf16 early weights (kvd,kvu,qd,qu)
  float* kvb   = alloc((size_t)Tn * 1024);        // later gatedb (bf16 T x 2048) overlay
  float* qf    = alloc((size_t)Tn * 768);         // later pvpart (8 x T x 64)
  float* qh    = alloc((size_t)Tn * 768);         // later latewb (bf16 oW,ffi,ffo) overlay
  float* kh    = alloc((size_t)Tn * 768);         //   (latewb spills into kh; both dead)
  float* vb    = alloc((size_t)Tn * 512);         // later zfin f32
  float* g     = alloc(2056);
  float* lam   = alloc(4);
  float* partial = alloc((size_t)33 * Tn);        // also hosts Wb/Gb
  float* probs = alloc((size_t)2 * Tn * Tn);      // also hosts uv

  __hip_bfloat16* xnb    = (__hip_bfloat16*)xnb_f;   // and zb
  __hip_bfloat16* ckvnb  = (__hip_bfloat16*)ckvnb_f;
  __hip_bfloat16* qlatnb = (__hip_bfloat16*)qlatnb_f;
  __hip_bfloat16* onormb = (__hip_bfloat16*)ckv;     // bf16 T x 512 over ckv+qlat (dead)
  __hip_bfloat16* gatedb = (__hip_bfloat16*)kvb;     // bf16 T x 2048 == kvb size
  __hip_bfloat16* ewb    = (__hip_bfloat16*)ewb_f;
  __hip_bfloat16* kvdb = ewb;                 // 160*512 = 81920
  __hip_bfloat16* kvub = ewb + 81920;         // 1024*128 = 131072
  __hip_bfloat16* qdb  = ewb + 212992;        // 192*512 = 98304
  __hip_bfloat16* qub  = ewb + 311296;        // 768*192 = 147456 (total 458752)
  __hip_bfloat16* latewb = (__hip_bfloat16*)qh;
  __hip_bfloat16* oWb  = latewb;              // 512*512 = 262144
  __hip_bfloat16* ffib = latewb + 262144;     // 4096*512 = 2097152
  __hip_bfloat16* ffob = latewb + 2359296;    // 512*2048 = 1048576 (total 3.4M <= qh+kh)
  float* pvpart = qf;
  float* zfin   = vb;
  float* Wb     = partial;
  float* Gb     = partial + 257 * 64;
  float* uv     = probs;

  size_t needed = off * sizeof(float);            // ~77.1 MB (< 79.5 proven)
  if (ws_size < needed) {
    k_fill42<<<(out_size + 255) / 256, 256, 0, stream>>>((float*)d_out, out_size);
    return;
  }

  k_freqs<<<8, 256, 0, stream>>>(cosb, sinb);
  k_embed<<<dim3(Tn, 2), 256, 0, stream>>>(x, ticker_emb, sep_emb, shared_W, unique_W,
                                           seperator, tickers, h);

  for (int d = 0; d < 2; d++) {
    const float* n1   = norm1_w + d * 512;
    const float* n2   = norm2_w + d * 512;
    const float* kvd  = kv_down_W + (size_t)d * 160 * 512;
    const float* qd   = q_down_W + (size_t)d * 192 * 512;
    const float* kvu  = kv_up_W + (size_t)d * 1024 * 128;
    const float* qu   = q_up_W + (size_t)d * 768 * 192;
    const float* kvnw = kv_norm_w + d * 128;
    const float* qnw  = q_norm_w + d * 192;
    const float* oW   = o_W + (size_t)d * 512 * 512;
    const float* hnw  = head_norm_w + d * 64;
    const float* ffi  = ff_in_W + (size_t)d * 4096 * 512;
    const float* ffo  = ff_out_W + (size_t)d * 512 * 2048;
    float lamc = 0.8f - 0.6f * expf(-0.3f * (float)d);

    // early weight conversions
    k_tobf16<<<320, 256, 0, stream>>>(kvd, kvdb, 81920);
    k_tobf16<<<512, 256, 0, stream>>>(kvu, kvub, 131072);
    k_tobf16<<<384, 256, 0, stream>>>(qd, qdb, 98304);
    k_tobf16<<<576, 256, 0, stream>>>(qu, qub, 147456);

    k_rmsnorm_b<<<Tn, 256, 0, stream>>>(h, n1, xnb, 512, 512, EPS_C);
    k_gemm_mfma<0><<<dim3(3, 17), 256, 0, stream>>>(xnb, kvdb, ckv, Tn, 160, 512);
    k_rmsnorm_b<<<Tn, 256, 0, stream>>>(ckv, kvnw, ckvnb, 128, 160, EPS_C);
    k_gemm_mfma<0><<<dim3(16, 17), 256, 0, stream>>>(ckvnb, kvub, kvb, Tn, 1024, 128);
    k_gemm_mfma<0><<<dim3(3, 17), 256, 0, stream>>>(xnb, qdb, qlat, Tn, 192, 512);
    k_rmsnorm_b<<<Tn, 256, 0, stream>>>(qlat, qnw, qlatnb, 192, 192, EPS_C);
    k_gemm_mfma<0><<<dim3(12, 17), 256, 0, stream>>>(qlatnb, qub, qf, Tn, 768, 192);
    k_qkv<<<Tn, 256, 0, stream>>>(qf, kvb, ckv, cosb, sinb, qh, kh, vb);
    k_lam<<<1, 1, 0, stream>>>(lam_q1 + d * 32, lam_k1 + d * 32,
                               lam_q2 + d * 32, lam_k2 + d * 32, lamc, lam);

    for (int ph = 0; ph < 8; ph++) {
      k_scores_gemm<<<dim3(33, 33, 2), 256, 0, stream>>>(qh, kh, probs, 2 * ph);
      k_softmax_rows<<<dim3(Tn, 2), 256, 0, stream>>>(probs);
      k_colmean_part<<<dim3(9, 33), 256, 0, stream>>>(probs, partial);
      k_colmean2<<<9, 256, 0, stream>>>(partial, lam, g);
      k_wv<<<257, 64, 0, stream>>>(g, vb, Wb, ph);
      k_gprefix<<<257, 64, 0, stream>>>(Wb, Gb);
      k_pv_part<<<dim3(33, 8), 256, 0, stream>>>(probs, vb, lam, pvpart, ph);
      k_pv_reduce<<<514, 256, 0, stream>>>(pvpart, Gb, hnw, onormb, ph);
    }

    // late weight conversions (qh/kh now dead)
    k_tobf16<<<1024, 256, 0, stream>>>(oW, oWb, 262144);
    k_tobf16<<<2048, 256, 0, stream>>>(ffi, ffib, 2097152);
    k_tobf16<<<2048, 256, 0, stream>>>(ffo, ffob, 1048576);

    k_gemm_mfma<1><<<dim3(8, 17), 256, 0, stream>>>(onormb, oWb, h, Tn, 512, 512);
    k_rmsnorm_b<<<Tn, 256, 0, stream>>>(h, n2, xnb /*zb*/, 512, 512, EPS_C);
    k_gemm_mfma<0><<<dim3(64, 17), 256, 0, stream>>>(xnb /*zb*/, ffib, uv, Tn, 4096, 512);
    k_swiglu<<<16448, 256, 0, stream>>>(uv, gatedb);
    k_gemm_mfma<1><<<dim3(8, 17), 256, 0, stream>>>(gatedb, ffob, h, Tn, 512, 2048);
  }

  k_rmsnorm<<<Tn, 256, 0, stream>>>(h, final_norm, zfin, 512, 512, EPS_C);
  k_final<<<Tn, 192, 0, stream>>>(zfin, out_W, (float*)d_out);
}

// Round 9
// 2768.434 us; speedup vs baseline: 3.5197x; 1.2774x over previous
//
#include <hip/hip_runtime.h>
#include <hip/hip_bf16.h>

// Money_former MLA DINT — round 9: scores -> bf16 MFMA; PV K-split re-chunked
// (16 x 128-chunks, 528 blocks, 2/CU). Arena 70.8 MB.
// T=2056, D=512, 2 layers, 16 logical heads (8 pairs) of 48.

#define Tn 2056
#define LPn 257
#define Dn 512

static constexpr float SCALING_C = 0.14433756729740643f;   // 48^-0.5
static constexpr float EPS_C     = 1.1920928955078125e-07f;

typedef float f32x4 __attribute__((ext_vector_type(4)));
typedef short bf16x8 __attribute__((ext_vector_type(8)));
typedef unsigned short u16x8 __attribute__((ext_vector_type(8)));

// ---------------- sentinel ----------------
__global__ __launch_bounds__(256) void k_fill42(float* __restrict__ out, int n) {
  int i = blockIdx.x * 256 + threadIdx.x;
  if (i < n) out[i] = 42.0f;
}

// ---------------- f32 -> bf16 convert ----------------
__global__ __launch_bounds__(256) void k_tobf16(const float* __restrict__ src,
                                                __hip_bfloat16* __restrict__ dst, long n) {
  long i = (long)blockIdx.x * 256 + threadIdx.x;
  long stride = (long)gridDim.x * 256;
  for (; i < n; i += stride) dst[i] = __float2bfloat16(src[i]);
}

// ---------------- RoPE tables ----------------
__global__ __launch_bounds__(256) void k_freqs(float* __restrict__ cosb, float* __restrict__ sinb) {
  int idx = blockIdx.x * 256 + threadIdx.x;
  if (idx >= 256 * 8) return;
  int pos = idx >> 3, j = idx & 7;
  float fb = powf(10000.f, -(float)j * 0.125f);            // 1/10000^(j/8)
  float ramp = fminf(fmaxf((float)j * 0.25f, 0.f), 1.f);   // low=0, high=4
  float sm = 1.f - ramp;
  float fr = fb * (1.f / 40.f) * (1.f - sm) + fb * sm;
  float ang = (float)pos * fr;
  cosb[idx] = cosf(ang);
  sinb[idx] = sinf(ang);
}

// ---------------- Embedding ----------------
__global__ __launch_bounds__(256) void k_embed(const float* __restrict__ x,
                                               const float* __restrict__ ticker_emb,
                                               const float* __restrict__ sep_emb,
                                               const float* __restrict__ shared_W,
                                               const float* __restrict__ unique_W,
                                               const int* __restrict__ sep_idx,
                                               const int* __restrict__ tickers,
                                               float* __restrict__ h) {
  int t = blockIdx.x;
  int c = blockIdx.y * 256 + threadIdx.x;
  int l = t >> 3, s = t & 7;
  float val;
  if (l == 0) {
    val = sep_emb[sep_idx[0] * Dn + c];
  } else {
    const float* xr = x + ((size_t)(l - 1) * 8 + s) * 32;
    const float* w = (c < 384) ? (shared_W + (size_t)c * 32)
                               : (unique_W + ((size_t)s * 128 + (c - 384)) * 32);
    float acc = 0.f;
#pragma unroll
    for (int f = 0; f < 32; f++) acc = fmaf(xr[f], w[f], acc);
    val = acc;
  }
  val += ticker_emb[(size_t)tickers[s] * Dn + c];
  h[(size_t)t * Dn + c] = val;
}

// ---------------- Row RMSNorm, f32 out ----------------
__global__ __launch_bounds__(256) void k_rmsnorm(const float* __restrict__ in,
                                                 const float* __restrict__ w,
                                                 float* __restrict__ out,
                                                 int ncols, int in_stride, float eps) {
  int row = blockIdx.x;
  const float* xr = in + (size_t)row * in_stride;
  float ss = 0.f;
  for (int c = threadIdx.x; c < ncols; c += 256) { float v = xr[c]; ss = fmaf(v, v, ss); }
  for (int off = 1; off < 64; off <<= 1) ss += __shfl_xor(ss, off);
  __shared__ float red[4];
  if ((threadIdx.x & 63) == 0) red[threadIdx.x >> 6] = ss;
  __syncthreads();
  float tot = red[0] + red[1] + red[2] + red[3];
  float scale = rsqrtf(tot / (float)ncols + eps);
  for (int c = threadIdx.x; c < ncols; c += 256)
    out[(size_t)row * ncols + c] = xr[c] * scale * w[c];
}

// ---------------- Row RMSNorm, bf16 out ----------------
__global__ __launch_bounds__(256) void k_rmsnorm_b(const float* __restrict__ in,
                                                   const float* __restrict__ w,
                                                   __hip_bfloat16* __restrict__ out,
                                                   int ncols, int in_stride, float eps) {
  int row = blockIdx.x;
  const float* xr = in + (size_t)row * in_stride;
  float ss = 0.f;
  for (int c = threadIdx.x; c < ncols; c += 256) { float v = xr[c]; ss = fmaf(v, v, ss); }
  for (int off = 1; off < 64; off <<= 1) ss += __shfl_xor(ss, off);
  __shared__ float red[4];
  if ((threadIdx.x & 63) == 0) red[threadIdx.x >> 6] = ss;
  __syncthreads();
  float tot = red[0] + red[1] + red[2] + red[3];
  float scale = rsqrtf(tot / (float)ncols + eps);
  for (int c = threadIdx.x; c < ncols; c += 256)
    out[(size_t)row * ncols + c] = __float2bfloat16(xr[c] * scale * w[c]);
}

// ---------------- MFMA GEMM: C[M,N] (+)= A[M,K] @ B[N,K]^T (bf16 in, f32 acc) ----------------
// Verified fragment map (round 8): A row = lane&15, K-off = (lane>>4)*8;
// C/D row = (lane>>4)*4 + reg, col = lane&15.
template <int MODE>
__global__ __launch_bounds__(256) void k_gemm_mfma(const __hip_bfloat16* __restrict__ A,
                                                   const __hip_bfloat16* __restrict__ B,
                                                   float* __restrict__ C,
                                                   int M, int N, int K) {
  __shared__ unsigned short Als[128][40];
  __shared__ unsigned short Bls[64][40];
  int bm = blockIdx.y * 128, bn = blockIdx.x * 64;
  int tid = threadIdx.x;
  int wave = tid >> 6, lane = tid & 63;
  int lrow = lane & 15, lgrp = lane >> 4;
  f32x4 acc[2][4] = {};
  for (int k0 = 0; k0 < K; k0 += 32) {
#pragma unroll
    for (int i = 0; i < 2; i++) {          // A: 512 x 16B vectors
      int vecIdx = tid + i * 256;
      int row = vecIdx >> 2, cg = vecIdx & 3;
      u16x8 v = {0, 0, 0, 0, 0, 0, 0, 0};
      int grow = bm + row;
      if (grow < M) v = *reinterpret_cast<const u16x8*>(A + (size_t)grow * K + k0 + cg * 8);
      *reinterpret_cast<u16x8*>(&Als[row][cg * 8]) = v;
    }
    {                                      // B: 256 x 16B vectors
      int row = tid >> 2, cg = tid & 3;
      u16x8 v = {0, 0, 0, 0, 0, 0, 0, 0};
      int gcol = bn + row;
      if (gcol < N) v = *reinterpret_cast<const u16x8*>(B + (size_t)gcol * K + k0 + cg * 8);
      *reinterpret_cast<u16x8*>(&Bls[row][cg * 8]) = v;
    }
    __syncthreads();
    bf16x8 af[2], bfr[4];
#pragma unroll
    for (int mi = 0; mi < 2; mi++)
      af[mi] = *reinterpret_cast<const bf16x8*>(&Als[wave * 32 + mi * 16 + lrow][lgrp * 8]);
#pragma unroll
    for (int ni = 0; ni < 4; ni++)
      bfr[ni] = *reinterpret_cast<const bf16x8*>(&Bls[ni * 16 + lrow][lgrp * 8]);
#pragma unroll
    for (int mi = 0; mi < 2; mi++)
#pragma unroll
      for (int ni = 0; ni < 4; ni++)
        acc[mi][ni] = __builtin_amdgcn_mfma_f32_16x16x32_bf16(af[mi], bfr[ni], acc[mi][ni], 0, 0, 0);
    __syncthreads();
  }
#pragma unroll
  for (int mi = 0; mi < 2; mi++)
#pragma unroll
    for (int ni = 0; ni < 4; ni++)
#pragma unroll
      for (int r = 0; r < 4; r++) {
        int row = bm + wave * 32 + mi * 16 + lgrp * 4 + r;
        int col = bn + ni * 16 + lrow;
        if (row < M && col < N) {
          if (MODE) C[(size_t)row * N + col] += acc[mi][ni][r];
          else      C[(size_t)row * N + col] = acc[mi][ni][r];
        }
      }
}

// ---------------- Scores MFMA: S[i,j] for one head pair, masked+scaled f32 out ----------------
// A = qhb[i][hh*48..], B = khb[j][hh*48..], K=48 zero-padded to 64; tile 128x64.
__global__ __launch_bounds__(256) void k_scores_mfma(const __hip_bfloat16* __restrict__ qhb,
                                                     const __hip_bfloat16* __restrict__ khb,
                                                     float* __restrict__ probs, int hh0) {
  __shared__ unsigned short Als[128][72];
  __shared__ unsigned short Bls[64][72];
  int bm = blockIdx.y * 128, bn = blockIdx.x * 64;
  int e = blockIdx.z, hh = hh0 + e;
  const __hip_bfloat16* A = qhb + hh * 48;
  const __hip_bfloat16* B = khb + hh * 48;
  float* C = probs + (size_t)e * Tn * Tn;
  int tid = threadIdx.x;
  int wave = tid >> 6, lane = tid & 63;
  int lrow = lane & 15, lgrp = lane >> 4;
#pragma unroll
  for (int i = 0; i < 4; i++) {            // A: 128 rows x 8 vec8 = 1024 vecs
    int vecIdx = tid + i * 256;
    int row = vecIdx >> 3, cg = vecIdx & 7;
    u16x8 v = {0, 0, 0, 0, 0, 0, 0, 0};
    int grow = bm + row;
    if (grow < Tn && cg < 6) v = *reinterpret_cast<const u16x8*>(A + (size_t)grow * 768 + cg * 8);
    *reinterpret_cast<u16x8*>(&Als[row][cg * 8]) = v;
  }
#pragma unroll
  for (int i = 0; i < 2; i++) {            // B: 64 rows x 8 vec8 = 512 vecs
    int vecIdx = tid + i * 256;
    int row = vecIdx >> 3, cg = vecIdx & 7;
    u16x8 v = {0, 0, 0, 0, 0, 0, 0, 0};
    int gcol = bn + row;
    if (gcol < Tn && cg < 6) v = *reinterpret_cast<const u16x8*>(B + (size_t)gcol * 768 + cg * 8);
    *reinterpret_cast<u16x8*>(&Bls[row][cg * 8]) = v;
  }
  __syncthreads();
  f32x4 acc[2][4] = {};
#pragma unroll
  for (int ks = 0; ks < 2; ks++) {
    bf16x8 af[2], bfr[4];
#pragma unroll
    for (int mi = 0; mi < 2; mi++)
      af[mi] = *reinterpret_cast<const bf16x8*>(&Als[wave * 32 + mi * 16 + lrow][ks * 32 + lgrp * 8]);
#pragma unroll
    for (int ni = 0; ni < 4; ni++)
      bfr[ni] = *reinterpret_cast<const bf16x8*>(&Bls[ni * 16 + lrow][ks * 32 + lgrp * 8]);
#pragma unroll
    for (int mi = 0; mi < 2; mi++)
#pragma unroll
      for (int ni = 0; ni < 4; ni++)
        acc[mi][ni] = __builtin_amdgcn_mfma_f32_16x16x32_bf16(af[mi], bfr[ni], acc[mi][ni], 0, 0, 0);
  }
#pragma unroll
  for (int mi = 0; mi < 2; mi++)
#pragma unroll
    for (int ni = 0; ni < 4; ni++)
#pragma unroll
      for (int r = 0; r < 4; r++) {
        int row = bm + wave * 32 + mi * 16 + lgrp * 4 + r;
        int col = bn + ni * 16 + lrow;
        if (row < Tn && col < Tn) {
          float sv = ((col % LPn) > (row % LPn)) ? -1e9f : acc[mi][ni][r] * SCALING_C;
          C[(size_t)row * Tn + col] = sv;
        }
      }
}

// ---------------- Assemble q/k (partial RoPE, bf16 out) and v (f32) ----------------
__global__ __launch_bounds__(256) void k_qkv(const float* __restrict__ qf,
                                             const float* __restrict__ kvb,
                                             const float* __restrict__ ckv,
                                             const float* __restrict__ cosb,
                                             const float* __restrict__ sinb,
                                             __hip_bfloat16* __restrict__ qhb,
                                             __hip_bfloat16* __restrict__ khb,
                                             float* __restrict__ vb) {
  int t = blockIdx.x;
  int l = t >> 3;
  for (int idx = threadIdx.x; idx < 768; idx += 256) {
    int hh = idx / 48, dc = idx % 48;
    int hd = hh >> 1, e = hh & 1;
    float qv, kvv;
    if (dc < 32) {
      qv  = qf [(size_t)t * 768  + hd * 96  + e * 32 + dc];
      kvv = kvb[(size_t)t * 1024 + hd * 128 + e * 32 + dc];
    } else {
      int rj = dc - 32;            // 0..15
      int p = rj >> 1; int isim = rj & 1;
      float xr_q = qf[(size_t)t * 768 + hd * 96 + 64 + e * 16 + p * 2];
      float xi_q = qf[(size_t)t * 768 + hd * 96 + 64 + e * 16 + p * 2 + 1];
      float xr_k = ckv[(size_t)t * 160 + 128 + e * 16 + p * 2];
      float xi_k = ckv[(size_t)t * 160 + 128 + e * 16 + p * 2 + 1];
      if (l == 0) {
        qv  = isim ? xi_q : xr_q;
        kvv = isim ? xi_k : xr_k;
      } else {
        float c = cosb[(l - 1) * 8 + p], s = sinb[(l - 1) * 8 + p];
        if (!isim) { qv = xr_q * c - xi_q * s; kvv = xr_k * c - xi_k * s; }
        else       { qv = xr_q * s + xi_q * c; kvv = xr_k * s + xi_k * c; }
      }
    }
    qhb[(size_t)t * 768 + idx] = __float2bfloat16(qv);
    khb[(size_t)t * 768 + idx] = __float2bfloat16(kvv);
  }
  for (int idx = threadIdx.x; idx < 512; idx += 256) {
    int hd = idx >> 6, dv = idx & 63;
    vb[(size_t)t * 512 + idx] = kvb[(size_t)t * 1024 + hd * 128 + 64 + dv];
  }
}

// ---------------- lambda scalar ----------------
__global__ void k_lam(const float* __restrict__ lq1, const float* __restrict__ lk1,
                      const float* __restrict__ lq2, const float* __restrict__ lk2,
                      float lamc, float* __restrict__ out) {
  float d1 = 0.f, d2 = 0.f;
  for (int k = 0; k < 32; k++) { d1 = fmaf(lq1[k], lk1[k], d1); d2 = fmaf(lq2[k], lk2[k], d2); }
  out[0] = expf(d1) - expf(d2) + lamc;
}

// ---------------- Row softmax in-place (2 heads) ----------------
__global__ __launch_bounds__(256) void k_softmax_rows(float* __restrict__ probs) {
  float* prow = probs + ((size_t)blockIdx.y * Tn + blockIdx.x) * Tn;
  int tid = threadIdx.x;
  float v[9];
  float lmax = -3.4e38f;
#pragma unroll
  for (int it = 0; it < 9; it++) {
    int j = tid + it * 256;
    v[it] = (j < Tn) ? prow[j] : -3.4e38f;
    lmax = fmaxf(lmax, v[it]);
  }
  for (int off = 1; off < 64; off <<= 1) lmax = fmaxf(lmax, __shfl_xor(lmax, off));
  __shared__ float red[4];
  if ((tid & 63) == 0) red[tid >> 6] = lmax;
  __syncthreads();
  float gmax = fmaxf(fmaxf(red[0], red[1]), fmaxf(red[2], red[3]));
  __syncthreads();
  float lsum = 0.f;
#pragma unroll
  for (int it = 0; it < 9; it++) { v[it] = expf(v[it] - gmax); lsum += v[it]; }
  for (int off = 1; off < 64; off <<= 1) lsum += __shfl_xor(lsum, off);
  if ((tid & 63) == 0) red[tid >> 6] = lsum;
  __syncthreads();
  float inv = 1.f / (red[0] + red[1] + red[2] + red[3]);
#pragma unroll
  for (int it = 0; it < 9; it++) {
    int j = tid + it * 256;
    if (j < Tn) prow[j] = v[it] * inv;
  }
}

// ---------------- Column mean of a1 (two-stage) ----------------
__global__ __launch_bounds__(256) void k_colmean_part(const float* __restrict__ a1,
                                                      float* __restrict__ partial) {
  int j = blockIdx.x * 256 + threadIdx.x;
  int ib = blockIdx.y;
  if (j >= Tn) return;
  int i0 = ib * 64, i1 = min(i0 + 64, Tn);
  float acc = 0.f;
  for (int i = i0; i < i1; i++) acc += a1[(size_t)i * Tn + j];
  partial[(size_t)ib * Tn + j] = acc;
}

__global__ __launch_bounds__(256) void k_colmean2(const float* __restrict__ partial,
                                                  const float* __restrict__ lamp,
                                                  float* __restrict__ g) {
  int j = blockIdx.x * 256 + threadIdx.x;
  if (j >= Tn) return;
  float acc = 0.f;
  for (int ib = 0; ib < 33; ib++) acc += partial[(size_t)ib * Tn + j];
  g[j] = acc * (1.f / (float)Tn) * lamp[0];
}

// ---------------- W[jmod][dv] = sum_k g[jmod+257k] * V[jmod+257k][dv] ----------------
__global__ __launch_bounds__(64) void k_wv(const float* __restrict__ g,
                                           const float* __restrict__ vb,
                                           float* __restrict__ Wb, int ph) {
  int jmod = blockIdx.x;
  int lane = threadIdx.x;
  float acc = 0.f;
#pragma unroll
  for (int k = 0; k < 8; k++) {
    int j = jmod + 257 * k;
    acc = fmaf(g[j], vb[(size_t)j * 512 + ph * 64 + lane], acc);
  }
  Wb[jmod * 64 + lane] = acc;
}

// ---------------- G[imod][dv] = sum_{m<=imod} W[m][dv] ----------------
__global__ __launch_bounds__(64) void k_gprefix(const float* __restrict__ Wb,
                                                float* __restrict__ G) {
  int imod = blockIdx.x;
  int lane = threadIdx.x;
  float acc = 0.f;
  for (int m = 0; m <= imod; m++) acc += Wb[m * 64 + lane];
  G[imod * 64 + lane] = acc;
}

// ---------------- PV partial GEMM: 16 K-chunks of 128 (last 136) ----------------
__global__ __launch_bounds__(256) void k_pv_part(const float* __restrict__ probs,
                                                 const float* __restrict__ vb,
                                                 const float* __restrict__ lamp,
                                                 float* __restrict__ pvpart, int ph) {
  __shared__ float As[64][17];
  __shared__ float Bs[64][17];
  int bm = blockIdx.x * 64;
  int kc = blockIdx.y;                 // 0..15
  int jbase = kc * 128;
  int jcount = (kc == 15) ? 136 : 128;
  float lam = lamp[0];
  const float* p0 = probs;
  const float* p1 = probs + (size_t)Tn * Tn;
  int tx = threadIdx.x & 15, ty = threadIdx.x >> 4;
  float acc[4][4] = {};
  for (int k0 = 0; k0 < jcount; k0 += 16) {
    for (int i = threadIdx.x; i < 1024; i += 256) {
      int m = i >> 4, kk = i & 15;
      int gm = bm + m;
      int gk = jbase + k0 + kk;
      bool ok = (gm < Tn) && (k0 + kk < jcount);
      As[m][kk] = ok ? fmaf(-lam, p1[(size_t)gm * Tn + gk], p0[(size_t)gm * Tn + gk]) : 0.f;
    }
    for (int i = threadIdx.x; i < 1024; i += 256) {
      int kk = i >> 6, nn = i & 63;
      int gk = jbase + k0 + kk;
      Bs[nn][kk] = (k0 + kk < jcount) ? vb[(size_t)gk * 512 + ph * 64 + nn] : 0.f;
    }
    __syncthreads();
#pragma unroll
    for (int kk = 0; kk < 16; kk++) {
      float a[4], b[4];
#pragma unroll
      for (int i = 0; i < 4; i++) a[i] = As[ty * 4 + i][kk];
#pragma unroll
      for (int j = 0; j < 4; j++) b[j] = Bs[tx * 4 + j][kk];
#pragma unroll
      for (int i = 0; i < 4; i++)
#pragma unroll
        for (int j = 0; j < 4; j++) acc[i][j] = fmaf(a[i], b[j], acc[i][j]);
    }
    __syncthreads();
  }
#pragma unroll
  for (int i = 0; i < 4; i++) {
    int gm = bm + ty * 4 + i;
    if (gm >= Tn) continue;
#pragma unroll
    for (int j = 0; j < 4; j++)
      pvpart[((size_t)kc * Tn + gm) * 64 + tx * 4 + j] = acc[i][j];
  }
}

// ---------------- reduce 16 partials + G-term + head-RMSNorm -> bf16 ----------------
__global__ __launch_bounds__(256) void k_pv_reduce(const float* __restrict__ pvpart,
                                                   const float* __restrict__ G,
                                                   const float* __restrict__ hnw,
                                                   __hip_bfloat16* __restrict__ onormb, int ph) {
  int w = threadIdx.x >> 6, lane = threadIdx.x & 63;
  int i = blockIdx.x * 4 + w;
  float s = G[(i % LPn) * 64 + lane];
#pragma unroll
  for (int kc = 0; kc < 16; kc++) s += pvpart[((size_t)kc * Tn + i) * 64 + lane];
  float ss = s * s;
  for (int off = 1; off < 64; off <<= 1) ss += __shfl_xor(ss, off);
  float scale = rsqrtf(ss * (1.f / 64.f) + 1e-5f);
  onormb[((size_t)ph * Tn + i) * 64 + lane] = __float2bfloat16(s * scale * hnw[lane]);
}

// ---------------- SwiGLU -> bf16 ----------------
__global__ __launch_bounds__(256) void k_swiglu(const float* __restrict__ uv,
                                                __hip_bfloat16* __restrict__ gatedb) {
  size_t idx = (size_t)blockIdx.x * 256 + threadIdx.x;
  if (idx >= (size_t)Tn * 2048) return;
  size_t t = idx / 2048, f = idx % 2048;
  float u = uv[t * 4096 + f];
  float vv = uv[t * 4096 + 2048 + f];
  float sv = vv / (1.f + expf(-vv));
  gatedb[idx] = __float2bfloat16(u * sv);
}

// ---------------- final head (float32 out) ----------------
__global__ __launch_bounds__(192) void k_final(const float* __restrict__ z,
                                               const float* __restrict__ outW,
                                               float* __restrict__ out) {
  int t = blockIdx.x;
  int p = threadIdx.x >> 6, lane = threadIdx.x & 63;
  float acc = 0.f;
  for (int m = lane; m < 512; m += 64) acc = fmaf(z[(size_t)t * 512 + m], outW[(size_t)p * 512 + m], acc);
  for (int off = 1; off < 64; off <<= 1) acc += __shfl_xor(acc, off);
  if (lane == 0) out[(size_t)t * 3 + p] = acc;
}

extern "C" void kernel_launch(void* const* d_in, const int* in_sizes, int n_in,
                              void* d_out, int out_size, void* d_ws, size_t ws_size,
                              hipStream_t stream) {
  const float* x          = (const float*)d_in[0];
  const float* ticker_emb = (const float*)d_in[1];
  const float* sep_emb    = (const float*)d_in[2];
  const float* shared_W   = (const float*)d_in[3];
  const float* unique_W   = (const float*)d_in[4];
  const float* norm1_w    = (const float*)d_in[5];
  const float* norm2_w    = (const float*)d_in[6];
  const float* kv_down_W  = (const float*)d_in[7];
  const float* q_down_W   = (const float*)d_in[8];
  const float* kv_up_W    = (const float*)d_in[9];
  const float* q_up_W     = (const float*)d_in[10];
  const float* kv_norm_w  = (const float*)d_in[11];
  const float* q_norm_w   = (const float*)d_in[12];
  const float* o_W        = (const float*)d_in[13];
  const float* lam_q1     = (const float*)d_in[14];
  const float* lam_k1     = (const float*)d_in[15];
  const float* lam_q2     = (const float*)d_in[16];
  const float* lam_k2     = (const float*)d_in[17];
  const float* head_norm_w= (const float*)d_in[18];
  const float* ff_in_W    = (const float*)d_in[19];
  const float* ff_out_W   = (const float*)d_in[20];
  const float* final_norm = (const float*)d_in[21];
  const float* out_W      = (const float*)d_in[22];
  const int*   seperator  = (const int*)d_in[23];
  const int*   tickers    = (const int*)d_in[24];
  (void)in_sizes; (void)n_in;

  float* W = (float*)d_ws;
  size_t off = 0;
  auto alloc = [&](size_t n) { float* p = W + off; off += n; return p; };
  float* cosb  = alloc(2048);
  float* sinb  = alloc(2048);
  float* h     = alloc((size_t)Tn * Dn);
  float* xnb_f = alloc((size_t)Tn * 256);         // bf16 T x 512 (also zb)
  float* ckv   = alloc((size_t)Tn * 160);         // + qlat region hosts onormb later
  float* qlat  = alloc((size_t)Tn * 192);
  float* ckvnb_f = alloc((size_t)Tn * 64);        // bf16 T x 128
  float* qlatnb_f = alloc((size_t)Tn * 96);       // bf16 T x 192
  float* ewb_f = alloc(229376);                   // bf16 early weights
  float* kvb   = alloc((size_t)Tn * 1024);        // pvpart (16*T*64 f32, exact) + gatedb overlays
  float* qf    = alloc((size_t)Tn * 768);         // zfin overlay
  float* qhb_f = alloc((size_t)Tn * 384);         // bf16 T x 768
  float* khb_f = alloc((size_t)Tn * 384);         // bf16 T x 768
  float* vb    = alloc((size_t)Tn * 512);         // latewb overlays qhb_f..vb post-loop
  float* g     = alloc(2056);
  float* lam   = alloc(4);
  float* partial = alloc((size_t)33 * Tn);        // also hosts Wb/Gb
  float* probs = alloc((size_t)2 * Tn * Tn);      // also hosts uv

  __hip_bfloat16* xnb    = (__hip_bfloat16*)xnb_f;
  __hip_bfloat16* ckvnb  = (__hip_bfloat16*)ckvnb_f;
  __hip_bfloat16* qlatnb = (__hip_bfloat16*)qlatnb_f;
  __hip_bfloat16* onormb = (__hip_bfloat16*)ckv;     // bf16 T x 512 over ckv+qlat
  __hip_bfloat16* gatedb = (__hip_bfloat16*)kvb;
  __hip_bfloat16* qhb    = (__hip_bfloat16*)qhb_f;
  __hip_bfloat16* khb    = (__hip_bfloat16*)khb_f;
  __hip_bfloat16* ewb    = (__hip_bfloat16*)ewb_f;
  __hip_bfloat16* kvdb = ewb;                 // 160*512
  __hip_bfloat16* kvub = ewb + 81920;         // 1024*128
  __hip_bfloat16* qdb  = ewb + 212992;        // 192*512
  __hip_bfloat16* qub  = ewb + 311296;        // 768*192
  __hip_bfloat16* latewb = (__hip_bfloat16*)qhb_f;   // post-loop: oWb/ffib/ffob (6.8MB <= 10.5MB)
  __hip_bfloat16* oWb  = latewb;
  __hip_bfloat16* ffib = latewb + 262144;
  __hip_bfloat16* ffob = latewb + 2359296;
  float* pvpart = kvb;       // 16*T*64 f32 == T*1024 f32 exactly
  float* zfin   = qf;
  float* Wb     = partial;
  float* Gb     = partial + 257 * 64;
  float* uv     = probs;

  size_t needed = off * sizeof(float);            // ~70.8 MB (< 79.5 proven)
  if (ws_size < needed) {
    k_fill42<<<(out_size + 255) / 256, 256, 0, stream>>>((float*)d_out, out_size);
    return;
  }

  k_freqs<<<8, 256, 0, stream>>>(cosb, sinb);
  k_embed<<<dim3(Tn, 2), 256, 0, stream>>>(x, ticker_emb, sep_emb, shared_W, unique_W,
                                           seperator, tickers, h);

  for (int d = 0; d < 2; d++) {
    const float* n1   = norm1_w + d * 512;
    const float* n2   = norm2_w + d * 512;
    const float* kvd  = kv_down_W + (size_t)d * 160 * 512;
    const float* qd   = q_down_W + (size_t)d * 192 * 512;
    const float* kvu  = kv_up_W + (size_t)d * 1024 * 128;
    const float* qu   = q_up_W + (size_t)d * 768 * 192;
    const float* kvnw = kv_norm_w + d * 128;
    const float* qnw  = q_norm_w + d * 192;
    const float* oW   = o_W + (size_t)d * 512 * 512;
    const float* hnw  = head_norm_w + d * 64;
    const float* ffi  = ff_in_W + (size_t)d * 4096 * 512;
    const float* ffo  = ff_out_W + (size_t)d * 512 * 2048;
    float lamc = 0.8f - 0.6f * expf(-0.3f * (float)d);

    k_tobf16<<<320, 256, 0, stream>>>(kvd, kvdb, 81920);
    k_tobf16<<<512, 256, 0, stream>>>(kvu, kvub, 131072);
    k_tobf16<<<384, 256, 0, stream>>>(qd, qdb, 98304);
    k_tobf16<<<576, 256, 0, stream>>>(qu, qub, 147456);

    k_rmsnorm_b<<<Tn, 256, 0, stream>>>(h, n1, xnb, 512, 512, EPS_C);
    k_gemm_mfma<0><<<dim3(3, 17), 256, 0, stream>>>(xnb, kvdb, ckv, Tn, 160, 512);
    k_rmsnorm_b<<<Tn, 256, 0, stream>>>(ckv, kvnw, ckvnb, 128, 160, EPS_C);
    k_gemm_mfma<0><<<dim3(16, 17), 256, 0, stream>>>(ckvnb, kvub, kvb, Tn, 1024, 128);
    k_gemm_mfma<0><<<dim3(3, 17), 256, 0, stream>>>(xnb, qdb, qlat, Tn, 192, 512);
    k_rmsnorm_b<<<Tn, 256, 0, stream>>>(qlat, qnw, qlatnb, 192, 192, EPS_C);
    k_gemm_mfma<0><<<dim3(12, 17), 256, 0, stream>>>(qlatnb, qub, qf, Tn, 768, 192);
    k_qkv<<<Tn, 256, 0, stream>>>(qf, kvb, ckv, cosb, sinb, qhb, khb, vb);
    k_lam<<<1, 1, 0, stream>>>(lam_q1 + d * 32, lam_k1 + d * 32,
                               lam_q2 + d * 32, lam_k2 + d * 32, lamc, lam);

    for (int ph = 0; ph < 8; ph++) {
      k_scores_mfma<<<dim3(33, 17, 2), 256, 0, stream>>>(qhb, khb, probs, 2 * ph);
      k_softmax_rows<<<dim3(Tn, 2), 256, 0, stream>>>(probs);
      k_colmean_part<<<dim3(9, 33), 256, 0, stream>>>(probs, partial);
      k_colmean2<<<9, 256, 0, stream>>>(partial, lam, g);
      k_wv<<<257, 64, 0, stream>>>(g, vb, Wb, ph);
      k_gprefix<<<257, 64, 0, stream>>>(Wb, Gb);
      k_pv_part<<<dim3(33, 16), 256, 0, stream>>>(probs, vb, lam, pvpart, ph);
      k_pv_reduce<<<514, 256, 0, stream>>>(pvpart, Gb, hnw, onormb, ph);
    }

    k_tobf16<<<1024, 256, 0, stream>>>(oW, oWb, 262144);
    k_tobf16<<<2048, 256, 0, stream>>>(ffi, ffib, 2097152);
    k_tobf16<<<2048, 256, 0, stream>>>(ffo, ffob, 1048576);

    k_gemm_mfma<1><<<dim3(8, 17), 256, 0, stream>>>(onormb, oWb, h, Tn, 512, 512);
    k_rmsnorm_b<<<Tn, 256, 0, stream>>>(h, n2, xnb, 512, 512, EPS_C);
    k_gemm_mfma<0><<<dim3(64, 17), 256, 0, stream>>>(xnb, ffib, uv, Tn, 4096, 512);
    k_swiglu<<<16448, 256, 0, stream>>>(uv, gatedb);
    k_gemm_mfma<1><<<dim3(8, 17), 256, 0, stream>>>(gatedb, ffob, h, Tn, 512, 2048);
  }

  k_rmsnorm<<<Tn, 256, 0, stream>>>(h, final_norm, zfin, 512, 512, EPS_C);
  k_final<<<Tn, 192, 0, stream>>>(zfin, out_W, (float*)d_out);
}

// Round 10
// 1989.258 us; speedup vs baseline: 4.8983x; 1.3917x over previous
//
#include <hip/hip_runtime.h>
#include <hip/hip_bf16.h>

// Money_former MLA DINT — round 10: kill the serial prefix (k_gprefix, 37% of
// runtime). Two-level scan: k_chunksum (17x64) + inline prefix in k_pv_reduce
// (<=32 wave-uniform adds). Everything else = round 9 (MFMA GEMMs + scores,
// 16-chunk PV split). T=2056, D=512, 2 layers, 16 logical heads of 48.

#define Tn 2056
#define LPn 257
#define Dn 512

static constexpr float SCALING_C = 0.14433756729740643f;   // 48^-0.5
static constexpr float EPS_C     = 1.1920928955078125e-07f;

typedef float f32x4 __attribute__((ext_vector_type(4)));
typedef short bf16x8 __attribute__((ext_vector_type(8)));
typedef unsigned short u16x8 __attribute__((ext_vector_type(8)));

// ---------------- sentinel ----------------
__global__ __launch_bounds__(256) void k_fill42(float* __restrict__ out, int n) {
  int i = blockIdx.x * 256 + threadIdx.x;
  if (i < n) out[i] = 42.0f;
}

// ---------------- f32 -> bf16 convert ----------------
__global__ __launch_bounds__(256) void k_tobf16(const float* __restrict__ src,
                                                __hip_bfloat16* __restrict__ dst, long n) {
  long i = (long)blockIdx.x * 256 + threadIdx.x;
  long stride = (long)gridDim.x * 256;
  for (; i < n; i += stride) dst[i] = __float2bfloat16(src[i]);
}

// ---------------- RoPE tables ----------------
__global__ __launch_bounds__(256) void k_freqs(float* __restrict__ cosb, float* __restrict__ sinb) {
  int idx = blockIdx.x * 256 + threadIdx.x;
  if (idx >= 256 * 8) return;
  int pos = idx >> 3, j = idx & 7;
  float fb = powf(10000.f, -(float)j * 0.125f);            // 1/10000^(j/8)
  float ramp = fminf(fmaxf((float)j * 0.25f, 0.f), 1.f);   // low=0, high=4
  float sm = 1.f - ramp;
  float fr = fb * (1.f / 40.f) * (1.f - sm) + fb * sm;
  float ang = (float)pos * fr;
  cosb[idx] = cosf(ang);
  sinb[idx] = sinf(ang);
}

// ---------------- Embedding ----------------
__global__ __launch_bounds__(256) void k_embed(const float* __restrict__ x,
                                               const float* __restrict__ ticker_emb,
                                               const float* __restrict__ sep_emb,
                                               const float* __restrict__ shared_W,
                                               const float* __restrict__ unique_W,
                                               const int* __restrict__ sep_idx,
                                               const int* __restrict__ tickers,
                                               float* __restrict__ h) {
  int t = blockIdx.x;
  int c = blockIdx.y * 256 + threadIdx.x;
  int l = t >> 3, s = t & 7;
  float val;
  if (l == 0) {
    val = sep_emb[sep_idx[0] * Dn + c];
  } else {
    const float* xr = x + ((size_t)(l - 1) * 8 + s) * 32;
    const float* w = (c < 384) ? (shared_W + (size_t)c * 32)
                               : (unique_W + ((size_t)s * 128 + (c - 384)) * 32);
    float acc = 0.f;
#pragma unroll
    for (int f = 0; f < 32; f++) acc = fmaf(xr[f], w[f], acc);
    val = acc;
  }
  val += ticker_emb[(size_t)tickers[s] * Dn + c];
  h[(size_t)t * Dn + c] = val;
}

// ---------------- Row RMSNorm, f32 out ----------------
__global__ __launch_bounds__(256) void k_rmsnorm(const float* __restrict__ in,
                                                 const float* __restrict__ w,
                                                 float* __restrict__ out,
                                                 int ncols, int in_stride, float eps) {
  int row = blockIdx.x;
  const float* xr = in + (size_t)row * in_stride;
  float ss = 0.f;
  for (int c = threadIdx.x; c < ncols; c += 256) { float v = xr[c]; ss = fmaf(v, v, ss); }
  for (int off = 1; off < 64; off <<= 1) ss += __shfl_xor(ss, off);
  __shared__ float red[4];
  if ((threadIdx.x & 63) == 0) red[threadIdx.x >> 6] = ss;
  __syncthreads();
  float tot = red[0] + red[1] + red[2] + red[3];
  float scale = rsqrtf(tot / (float)ncols + eps);
  for (int c = threadIdx.x; c < ncols; c += 256)
    out[(size_t)row * ncols + c] = xr[c] * scale * w[c];
}

// ---------------- Row RMSNorm, bf16 out ----------------
__global__ __launch_bounds__(256) void k_rmsnorm_b(const float* __restrict__ in,
                                                   const float* __restrict__ w,
                                                   __hip_bfloat16* __restrict__ out,
                                                   int ncols, int in_stride, float eps) {
  int row = blockIdx.x;
  const float* xr = in + (size_t)row * in_stride;
  float ss = 0.f;
  for (int c = threadIdx.x; c < ncols; c += 256) { float v = xr[c]; ss = fmaf(v, v, ss); }
  for (int off = 1; off < 64; off <<= 1) ss += __shfl_xor(ss, off);
  __shared__ float red[4];
  if ((threadIdx.x & 63) == 0) red[threadIdx.x >> 6] = ss;
  __syncthreads();
  float tot = red[0] + red[1] + red[2] + red[3];
  float scale = rsqrtf(tot / (float)ncols + eps);
  for (int c = threadIdx.x; c < ncols; c += 256)
    out[(size_t)row * ncols + c] = __float2bfloat16(xr[c] * scale * w[c]);
}

// ---------------- MFMA GEMM: C[M,N] (+)= A[M,K] @ B[N,K]^T (bf16 in, f32 acc) ----------------
template <int MODE>
__global__ __launch_bounds__(256) void k_gemm_mfma(const __hip_bfloat16* __restrict__ A,
                                                   const __hip_bfloat16* __restrict__ B,
                                                   float* __restrict__ C,
                                                   int M, int N, int K) {
  __shared__ unsigned short Als[128][40];
  __shared__ unsigned short Bls[64][40];
  int bm = blockIdx.y * 128, bn = blockIdx.x * 64;
  int tid = threadIdx.x;
  int wave = tid >> 6, lane = tid & 63;
  int lrow = lane & 15, lgrp = lane >> 4;
  f32x4 acc[2][4] = {};
  for (int k0 = 0; k0 < K; k0 += 32) {
#pragma unroll
    for (int i = 0; i < 2; i++) {          // A: 512 x 16B vectors
      int vecIdx = tid + i * 256;
      int row = vecIdx >> 2, cg = vecIdx & 3;
      u16x8 v = {0, 0, 0, 0, 0, 0, 0, 0};
      int grow = bm + row;
      if (grow < M) v = *reinterpret_cast<const u16x8*>(A + (size_t)grow * K + k0 + cg * 8);
      *reinterpret_cast<u16x8*>(&Als[row][cg * 8]) = v;
    }
    {                                      // B: 256 x 16B vectors
      int row = tid >> 2, cg = tid & 3;
      u16x8 v = {0, 0, 0, 0, 0, 0, 0, 0};
      int gcol = bn + row;
      if (gcol < N) v = *reinterpret_cast<const u16x8*>(B + (size_t)gcol * K + k0 + cg * 8);
      *reinterpret_cast<u16x8*>(&Bls[row][cg * 8]) = v;
    }
    __syncthreads();
    bf16x8 af[2], bfr[4];
#pragma unroll
    for (int mi = 0; mi < 2; mi++)
      af[mi] = *reinterpret_cast<const bf16x8*>(&Als[wave * 32 + mi * 16 + lrow][lgrp * 8]);
#pragma unroll
    for (int ni = 0; ni < 4; ni++)
      bfr[ni] = *reinterpret_cast<const bf16x8*>(&Bls[ni * 16 + lrow][lgrp * 8]);
#pragma unroll
    for (int mi = 0; mi < 2; mi++)
#pragma unroll
      for (int ni = 0; ni < 4; ni++)
        acc[mi][ni] = __builtin_amdgcn_mfma_f32_16x16x32_bf16(af[mi], bfr[ni], acc[mi][ni], 0, 0, 0);
    __syncthreads();
  }
#pragma unroll
  for (int mi = 0; mi < 2; mi++)
#pragma unroll
    for (int ni = 0; ni < 4; ni++)
#pragma unroll
      for (int r = 0; r < 4; r++) {
        int row = bm + wave * 32 + mi * 16 + lgrp * 4 + r;
        int col = bn + ni * 16 + lrow;
        if (row < M && col < N) {
          if (MODE) C[(size_t)row * N + col] += acc[mi][ni][r];
          else      C[(size_t)row * N + col] = acc[mi][ni][r];
        }
      }
}

// ---------------- Scores MFMA: masked+scaled f32 out ----------------
__global__ __launch_bounds__(256) void k_scores_mfma(const __hip_bfloat16* __restrict__ qhb,
                                                     const __hip_bfloat16* __restrict__ khb,
                                                     float* __restrict__ probs, int hh0) {
  __shared__ unsigned short Als[128][72];
  __shared__ unsigned short Bls[64][72];
  int bm = blockIdx.y * 128, bn = blockIdx.x * 64;
  int e = blockIdx.z, hh = hh0 + e;
  const __hip_bfloat16* A = qhb + hh * 48;
  const __hip_bfloat16* B = khb + hh * 48;
  float* C = probs + (size_t)e * Tn * Tn;
  int tid = threadIdx.x;
  int wave = tid >> 6, lane = tid & 63;
  int lrow = lane & 15, lgrp = lane >> 4;
#pragma unroll
  for (int i = 0; i < 4; i++) {
    int vecIdx = tid + i * 256;
    int row = vecIdx >> 3, cg = vecIdx & 7;
    u16x8 v = {0, 0, 0, 0, 0, 0, 0, 0};
    int grow = bm + row;
    if (grow < Tn && cg < 6) v = *reinterpret_cast<const u16x8*>(A + (size_t)grow * 768 + cg * 8);
    *reinterpret_cast<u16x8*>(&Als[row][cg * 8]) = v;
  }
#pragma unroll
  for (int i = 0; i < 2; i++) {
    int vecIdx = tid + i * 256;
    int row = vecIdx >> 3, cg = vecIdx & 7;
    u16x8 v = {0, 0, 0, 0, 0, 0, 0, 0};
    int gcol = bn + row;
    if (gcol < Tn && cg < 6) v = *reinterpret_cast<const u16x8*>(B + (size_t)gcol * 768 + cg * 8);
    *reinterpret_cast<u16x8*>(&Bls[row][cg * 8]) = v;
  }
  __syncthreads();
  f32x4 acc[2][4] = {};
#pragma unroll
  for (int ks = 0; ks < 2; ks++) {
    bf16x8 af[2], bfr[4];
#pragma unroll
    for (int mi = 0; mi < 2; mi++)
      af[mi] = *reinterpret_cast<const bf16x8*>(&Als[wave * 32 + mi * 16 + lrow][ks * 32 + lgrp * 8]);
#pragma unroll
    for (int ni = 0; ni < 4; ni++)
      bfr[ni] = *reinterpret_cast<const bf16x8*>(&Bls[ni * 16 + lrow][ks * 32 + lgrp * 8]);
#pragma unroll
    for (int mi = 0; mi < 2; mi++)
#pragma unroll
      for (int ni = 0; ni < 4; ni++)
        acc[mi][ni] = __builtin_amdgcn_mfma_f32_16x16x32_bf16(af[mi], bfr[ni], acc[mi][ni], 0, 0, 0);
  }
#pragma unroll
  for (int mi = 0; mi < 2; mi++)
#pragma unroll
    for (int ni = 0; ni < 4; ni++)
#pragma unroll
      for (int r = 0; r < 4; r++) {
        int row = bm + wave * 32 + mi * 16 + lgrp * 4 + r;
        int col = bn + ni * 16 + lrow;
        if (row < Tn && col < Tn) {
          float sv = ((col % LPn) > (row % LPn)) ? -1e9f : acc[mi][ni][r] * SCALING_C;
          C[(size_t)row * Tn + col] = sv;
        }
      }
}

// ---------------- Assemble q/k (partial RoPE, bf16 out) and v (f32) ----------------
__global__ __launch_bounds__(256) void k_qkv(const float* __restrict__ qf,
                                             const float* __restrict__ kvb,
                                             const float* __restrict__ ckv,
                                             const float* __restrict__ cosb,
                                             const float* __restrict__ sinb,
                                             __hip_bfloat16* __restrict__ qhb,
                                             __hip_bfloat16* __restrict__ khb,
                                             float* __restrict__ vb) {
  int t = blockIdx.x;
  int l = t >> 3;
  for (int idx = threadIdx.x; idx < 768; idx += 256) {
    int hh = idx / 48, dc = idx % 48;
    int hd = hh >> 1, e = hh & 1;
    float qv, kvv;
    if (dc < 32) {
      qv  = qf [(size_t)t * 768  + hd * 96  + e * 32 + dc];
      kvv = kvb[(size_t)t * 1024 + hd * 128 + e * 32 + dc];
    } else {
      int rj = dc - 32;            // 0..15
      int p = rj >> 1; int isim = rj & 1;
      float xr_q = qf[(size_t)t * 768 + hd * 96 + 64 + e * 16 + p * 2];
      float xi_q = qf[(size_t)t * 768 + hd * 96 + 64 + e * 16 + p * 2 + 1];
      float xr_k = ckv[(size_t)t * 160 + 128 + e * 16 + p * 2];
      float xi_k = ckv[(size_t)t * 160 + 128 + e * 16 + p * 2 + 1];
      if (l == 0) {
        qv  = isim ? xi_q : xr_q;
        kvv = isim ? xi_k : xr_k;
      } else {
        float c = cosb[(l - 1) * 8 + p], s = sinb[(l - 1) * 8 + p];
        if (!isim) { qv = xr_q * c - xi_q * s; kvv = xr_k * c - xi_k * s; }
        else       { qv = xr_q * s + xi_q * c; kvv = xr_k * s + xi_k * c; }
      }
    }
    qhb[(size_t)t * 768 + idx] = __float2bfloat16(qv);
    khb[(size_t)t * 768 + idx] = __float2bfloat16(kvv);
  }
  for (int idx = threadIdx.x; idx < 512; idx += 256) {
    int hd = idx >> 6, dv = idx & 63;
    vb[(size_t)t * 512 + idx] = kvb[(size_t)t * 1024 + hd * 128 + 64 + dv];
  }
}

// ---------------- lambda scalar ----------------
__global__ void k_lam(const float* __restrict__ lq1, const float* __restrict__ lk1,
                      const float* __restrict__ lq2, const float* __restrict__ lk2,
                      float lamc, float* __restrict__ out) {
  float d1 = 0.f, d2 = 0.f;
  for (int k = 0; k < 32; k++) { d1 = fmaf(lq1[k], lk1[k], d1); d2 = fmaf(lq2[k], lk2[k], d2); }
  out[0] = expf(d1) - expf(d2) + lamc;
}

// ---------------- Row softmax in-place (2 heads) ----------------
__global__ __launch_bounds__(256) void k_softmax_rows(float* __restrict__ probs) {
  float* prow = probs + ((size_t)blockIdx.y * Tn + blockIdx.x) * Tn;
  int tid = threadIdx.x;
  float v[9];
  float lmax = -3.4e38f;
#pragma unroll
  for (int it = 0; it < 9; it++) {
    int j = tid + it * 256;
    v[it] = (j < Tn) ? prow[j] : -3.4e38f;
    lmax = fmaxf(lmax, v[it]);
  }
  for (int off = 1; off < 64; off <<= 1) lmax = fmaxf(lmax, __shfl_xor(lmax, off));
  __shared__ float red[4];
  if ((tid & 63) == 0) red[tid >> 6] = lmax;
  __syncthreads();
  float gmax = fmaxf(fmaxf(red[0], red[1]), fmaxf(red[2], red[3]));
  __syncthreads();
  float lsum = 0.f;
#pragma unroll
  for (int it = 0; it < 9; it++) { v[it] = expf(v[it] - gmax); lsum += v[it]; }
  for (int off = 1; off < 64; off <<= 1) lsum += __shfl_xor(lsum, off);
  if ((tid & 63) == 0) red[tid >> 6] = lsum;
  __syncthreads();
  float inv = 1.f / (red[0] + red[1] + red[2] + red[3]);
#pragma unroll
  for (int it = 0; it < 9; it++) {
    int j = tid + it * 256;
    if (j < Tn) prow[j] = v[it] * inv;
  }
}

// ---------------- Column mean of a1 (two-stage) ----------------
__global__ __launch_bounds__(256) void k_colmean_part(const float* __restrict__ a1,
                                                      float* __restrict__ partial) {
  int j = blockIdx.x * 256 + threadIdx.x;
  int ib = blockIdx.y;
  if (j >= Tn) return;
  int i0 = ib * 64, i1 = min(i0 + 64, Tn);
  float acc = 0.f;
  for (int i = i0; i < i1; i++) acc += a1[(size_t)i * Tn + j];
  partial[(size_t)ib * Tn + j] = acc;
}

__global__ __launch_bounds__(256) void k_colmean2(const float* __restrict__ partial,
                                                  const float* __restrict__ lamp,
                                                  float* __restrict__ g) {
  int j = blockIdx.x * 256 + threadIdx.x;
  if (j >= Tn) return;
  float acc = 0.f;
  for (int ib = 0; ib < 33; ib++) acc += partial[(size_t)ib * Tn + j];
  g[j] = acc * (1.f / (float)Tn) * lamp[0];
}

// ---------------- W[jmod][dv] = sum_k g[jmod+257k] * V[jmod+257k][dv] ----------------
__global__ __launch_bounds__(64) void k_wv(const float* __restrict__ g,
                                           const float* __restrict__ vb,
                                           float* __restrict__ Wb, int ph) {
  int jmod = blockIdx.x;
  int lane = threadIdx.x;
  float acc = 0.f;
#pragma unroll
  for (int k = 0; k < 8; k++) {
    int j = jmod + 257 * k;
    acc = fmaf(g[j], vb[(size_t)j * 512 + ph * 64 + lane], acc);
  }
  Wb[jmod * 64 + lane] = acc;
}

// ---------------- C[c][dv] = sum_{m in 16-chunk c} W[m][dv]  (c = 0..16) ----------------
__global__ __launch_bounds__(64) void k_chunksum(const float* __restrict__ Wb,
                                                 float* __restrict__ Cb) {
  int c = blockIdx.x;            // 0..16
  int lane = threadIdx.x;
  int m0 = c * 16, m1 = min(m0 + 16, LPn);
  float acc = 0.f;
  for (int m = m0; m < m1; m++) acc += Wb[m * 64 + lane];
  Cb[c * 64 + lane] = acc;
}

// ---------------- PV partial GEMM: 16 K-chunks of 128 (last 136) ----------------
__global__ __launch_bounds__(256) void k_pv_part(const float* __restrict__ probs,
                                                 const float* __restrict__ vb,
                                                 const float* __restrict__ lamp,
                                                 float* __restrict__ pvpart, int ph) {
  __shared__ float As[64][17];
  __shared__ float Bs[64][17];
  int bm = blockIdx.x * 64;
  int kc = blockIdx.y;                 // 0..15
  int jbase = kc * 128;
  int jcount = (kc == 15) ? 136 : 128;
  float lam = lamp[0];
  const float* p0 = probs;
  const float* p1 = probs + (size_t)Tn * Tn;
  int tx = threadIdx.x & 15, ty = threadIdx.x >> 4;
  float acc[4][4] = {};
  for (int k0 = 0; k0 < jcount; k0 += 16) {
    for (int i = threadIdx.x; i < 1024; i += 256) {
      int m = i >> 4, kk = i & 15;
      int gm = bm + m;
      int gk = jbase + k0 + kk;
      bool ok = (gm < Tn) && (k0 + kk < jcount);
      As[m][kk] = ok ? fmaf(-lam, p1[(size_t)gm * Tn + gk], p0[(size_t)gm * Tn + gk]) : 0.f;
    }
    for (int i = threadIdx.x; i < 1024; i += 256) {
      int kk = i >> 6, nn = i & 63;
      int gk = jbase + k0 + kk;
      Bs[nn][kk] = (k0 + kk < jcount) ? vb[(size_t)gk * 512 + ph * 64 + nn] : 0.f;
    }
    __syncthreads();
#pragma unroll
    for (int kk = 0; kk < 16; kk++) {
      float a[4], b[4];
#pragma unroll
      for (int i = 0; i < 4; i++) a[i] = As[ty * 4 + i][kk];
#pragma unroll
      for (int j = 0; j < 4; j++) b[j] = Bs[tx * 4 + j][kk];
#pragma unroll
      for (int i = 0; i < 4; i++)
#pragma unroll
        for (int j = 0; j < 4; j++) acc[i][j] = fmaf(a[i], b[j], acc[i][j]);
    }
    __syncthreads();
  }
#pragma unroll
  for (int i = 0; i < 4; i++) {
    int gm = bm + ty * 4 + i;
    if (gm >= Tn) continue;
#pragma unroll
    for (int j = 0; j < 4; j++)
      pvpart[((size_t)kc * Tn + gm) * 64 + tx * 4 + j] = acc[i][j];
  }
}

// ---------------- reduce 16 partials + inline G-prefix + head-RMSNorm -> bf16 ----------------
__global__ __launch_bounds__(256) void k_pv_reduce(const float* __restrict__ pvpart,
                                                   const float* __restrict__ Wb,
                                                   const float* __restrict__ Cb,
                                                   const float* __restrict__ hnw,
                                                   __hip_bfloat16* __restrict__ onormb, int ph) {
  int w = threadIdx.x >> 6, lane = threadIdx.x & 63;
  int i = blockIdx.x * 4 + w;
  int imod = i % LPn;            // wave-uniform
  int cidx = imod >> 4;
  float s = 0.f;
  for (int c = 0; c < cidx; c++) s += Cb[c * 64 + lane];
  for (int m = cidx * 16; m <= imod; m++) s += Wb[m * 64 + lane];
#pragma unroll
  for (int kc = 0; kc < 16; kc++) s += pvpart[((size_t)kc * Tn + i) * 64 + lane];
  float ss = s * s;
  for (int off = 1; off < 64; off <<= 1) ss += __shfl_xor(ss, off);
  float scale = rsqrtf(ss * (1.f / 64.f) + 1e-5f);
  onormb[((size_t)ph * Tn + i) * 64 + lane] = __float2bfloat16(s * scale * hnw[lane]);
}

// ---------------- SwiGLU -> bf16 ----------------
__global__ __launch_bounds__(256) void k_swiglu(const float* __restrict__ uv,
                                                __hip_bfloat16* __restrict__ gatedb) {
  size_t idx = (size_t)blockIdx.x * 256 + threadIdx.x;
  if (idx >= (size_t)Tn * 2048) return;
  size_t t = idx / 2048, f = idx % 2048;
  float u = uv[t * 4096 + f];
  float vv = uv[t * 4096 + 2048 + f];
  float sv = vv / (1.f + expf(-vv));
  gatedb[idx] = __float2bfloat16(u * sv);
}

// ---------------- final head (float32 out) ----------------
__global__ __launch_bounds__(192) void k_final(const float* __restrict__ z,
                                               const float* __restrict__ outW,
                                               float* __restrict__ out) {
  int t = blockIdx.x;
  int p = threadIdx.x >> 6, lane = threadIdx.x & 63;
  float acc = 0.f;
  for (int m = lane; m < 512; m += 64) acc = fmaf(z[(size_t)t * 512 + m], outW[(size_t)p * 512 + m], acc);
  for (int off = 1; off < 64; off <<= 1) acc += __shfl_xor(acc, off);
  if (lane == 0) out[(size_t)t * 3 + p] = acc;
}

extern "C" void kernel_launch(void* const* d_in, const int* in_sizes, int n_in,
                              void* d_out, int out_size, void* d_ws, size_t ws_size,
                              hipStream_t stream) {
  const float* x          = (const float*)d_in[0];
  const float* ticker_emb = (const float*)d_in[1];
  const float* sep_emb    = (const float*)d_in[2];
  const float* shared_W   = (const float*)d_in[3];
  const float* unique_W   = (const float*)d_in[4];
  const float* norm1_w    = (const float*)d_in[5];
  const float* norm2_w    = (const float*)d_in[6];
  const float* kv_down_W  = (const float*)d_in[7];
  const float* q_down_W   = (const float*)d_in[8];
  const float* kv_up_W    = (const float*)d_in[9];
  const float* q_up_W     = (const float*)d_in[10];
  const float* kv_norm_w  = (const float*)d_in[11];
  const float* q_norm_w   = (const float*)d_in[12];
  const float* o_W        = (const float*)d_in[13];
  const float* lam_q1     = (const float*)d_in[14];
  const float* lam_k1     = (const float*)d_in[15];
  const float* lam_q2     = (const float*)d_in[16];
  const float* lam_k2     = (const float*)d_in[17];
  const float* head_norm_w= (const float*)d_in[18];
  const float* ff_in_W    = (const float*)d_in[19];
  const float* ff_out_W   = (const float*)d_in[20];
  const float* final_norm = (const float*)d_in[21];
  const float* out_W      = (const float*)d_in[22];
  const int*   seperator  = (const int*)d_in[23];
  const int*   tickers    = (const int*)d_in[24];
  (void)in_sizes; (void)n_in;

  float* W = (float*)d_ws;
  size_t off = 0;
  auto alloc = [&](size_t n) { float* p = W + off; off += n; return p; };
  float* cosb  = alloc(2048);
  float* sinb  = alloc(2048);
  float* h     = alloc((size_t)Tn * Dn);
  float* xnb_f = alloc((size_t)Tn * 256);         // bf16 T x 512 (also zb)
  float* ckv   = alloc((size_t)Tn * 160);         // + qlat region hosts onormb later
  float* qlat  = alloc((size_t)Tn * 192);
  float* ckvnb_f = alloc((size_t)Tn * 64);        // bf16 T x 128
  float* qlatnb_f = alloc((size_t)Tn * 96);       // bf16 T x 192
  float* ewb_f = alloc(229376);                   // bf16 early weights
  float* kvb   = alloc((size_t)Tn * 1024);        // pvpart + gatedb overlays
  float* qf    = alloc((size_t)Tn * 768);         // zfin overlay
  float* qhb_f = alloc((size_t)Tn * 384);         // bf16 T x 768
  float* khb_f = alloc((size_t)Tn * 384);         // bf16 T x 768
  float* vb    = alloc((size_t)Tn * 512);
  float* g     = alloc(2056);
  float* lam   = alloc(4);
  float* partial = alloc((size_t)33 * Tn);        // also hosts Wb/Cb
  float* probs = alloc((size_t)2 * Tn * Tn);      // also hosts uv

  __hip_bfloat16* xnb    = (__hip_bfloat16*)xnb_f;
  __hip_bfloat16* ckvnb  = (__hip_bfloat16*)ckvnb_f;
  __hip_bfloat16* qlatnb = (__hip_bfloat16*)qlatnb_f;
  __hip_bfloat16* onormb = (__hip_bfloat16*)ckv;     // bf16 T x 512 over ckv+qlat
  __hip_bfloat16* gatedb = (__hip_bfloat16*)kvb;
  __hip_bfloat16* qhb    = (__hip_bfloat16*)qhb_f;
  __hip_bfloat16* khb    = (__hip_bfloat16*)khb_f;
  __hip_bfloat16* ewb    = (__hip_bfloat16*)ewb_f;
  __hip_bfloat16* kvdb = ewb;                 // 160*512
  __hip_bfloat16* kvub = ewb + 81920;         // 1024*128
  __hip_bfloat16* qdb  = ewb + 212992;        // 192*512
  __hip_bfloat16* qub  = ewb + 311296;        // 768*192
  __hip_bfloat16* latewb = (__hip_bfloat16*)qhb_f;   // post-loop: oWb/ffib/ffob
  __hip_bfloat16* oWb  = latewb;
  __hip_bfloat16* ffib = latewb + 262144;
  __hip_bfloat16* ffob = latewb + 2359296;
  float* pvpart = kvb;       // 16*T*64 f32 == T*1024 f32 exactly
  float* zfin   = qf;
  float* Wb     = partial;             // 257*64 = 16448
  float* Cb     = partial + 257 * 64;  // 17*64 = 1088 (total 17536 <= 33*Tn)
  float* uv     = probs;

  size_t needed = off * sizeof(float);            // ~70.8 MB (< 79.5 proven)
  if (ws_size < needed) {
    k_fill42<<<(out_size + 255) / 256, 256, 0, stream>>>((float*)d_out, out_size);
    return;
  }

  k_freqs<<<8, 256, 0, stream>>>(cosb, sinb);
  k_embed<<<dim3(Tn, 2), 256, 0, stream>>>(x, ticker_emb, sep_emb, shared_W, unique_W,
                                           seperator, tickers, h);

  for (int d = 0; d < 2; d++) {
    const float* n1   = norm1_w + d * 512;
    const float* n2   = norm2_w + d * 512;
    const float* kvd  = kv_down_W + (size_t)d * 160 * 512;
    const float* qd   = q_down_W + (size_t)d * 192 * 512;
    const float* kvu  = kv_up_W + (size_t)d * 1024 * 128;
    const float* qu   = q_up_W + (size_t)d * 768 * 192;
    const float* kvnw = kv_norm_w + d * 128;
    const float* qnw  = q_norm_w + d * 192;
    const float* oW   = o_W + (size_t)d * 512 * 512;
    const float* hnw  = head_norm_w + d * 64;
    const float* ffi  = ff_in_W + (size_t)d * 4096 * 512;
    const float* ffo  = ff_out_W + (size_t)d * 512 * 2048;
    float lamc = 0.8f - 0.6f * expf(-0.3f * (float)d);

    k_tobf16<<<320, 256, 0, stream>>>(kvd, kvdb, 81920);
    k_tobf16<<<512, 256, 0, stream>>>(kvu, kvub, 131072);
    k_tobf16<<<384, 256, 0, stream>>>(qd, qdb, 98304);
    k_tobf16<<<576, 256, 0, stream>>>(qu, qub, 147456);

    k_rmsnorm_b<<<Tn, 256, 0, stream>>>(h, n1, xnb, 512, 512, EPS_C);
    k_gemm_mfma<0><<<dim3(3, 17), 256, 0, stream>>>(xnb, kvdb, ckv, Tn, 160, 512);
    k_rmsnorm_b<<<Tn, 256, 0, stream>>>(ckv, kvnw, ckvnb, 128, 160, EPS_C);
    k_gemm_mfma<0><<<dim3(16, 17), 256, 0, stream>>>(ckvnb, kvub, kvb, Tn, 1024, 128);
    k_gemm_mfma<0><<<dim3(3, 17), 256, 0, stream>>>(xnb, qdb, qlat, Tn, 192, 512);
    k_rmsnorm_b<<<Tn, 256, 0, stream>>>(qlat, qnw, qlatnb, 192, 192, EPS_C);
    k_gemm_mfma<0><<<dim3(12, 17), 256, 0, stream>>>(qlatnb, qub, qf, Tn, 768, 192);
    k_qkv<<<Tn, 256, 0, stream>>>(qf, kvb, ckv, cosb, sinb, qhb, khb, vb);
    k_lam<<<1, 1, 0, stream>>>(lam_q1 + d * 32, lam_k1 + d * 32,
                               lam_q2 + d * 32, lam_k2 + d * 32, lamc, lam);

    for (int ph = 0; ph < 8; ph++) {
      k_scores_mfma<<<dim3(33, 17, 2), 256, 0, stream>>>(qhb, khb, probs, 2 * ph);
      k_softmax_rows<<<dim3(Tn, 2), 256, 0, stream>>>(probs);
      k_colmean_part<<<dim3(9, 33), 256, 0, stream>>>(probs, partial);
      k_colmean2<<<9, 256, 0, stream>>>(partial, lam, g);
      k_wv<<<257, 64, 0, stream>>>(g, vb, Wb, ph);
      k_chunksum<<<17, 64, 0, stream>>>(Wb, Cb);
      k_pv_part<<<dim3(33, 16), 256, 0, stream>>>(probs, vb, lam, pvpart, ph);
      k_pv_reduce<<<514, 256, 0, stream>>>(pvpart, Wb, Cb, hnw, onormb, ph);
    }

    k_tobf16<<<1024, 256, 0, stream>>>(oW, oWb, 262144);
    k_tobf16<<<2048, 256, 0, stream>>>(ffi, ffib, 2097152);
    k_tobf16<<<2048, 256, 0, stream>>>(ffo, ffob, 1048576);

    k_gemm_mfma<1><<<dim3(8, 17), 256, 0, stream>>>(onormb, oWb, h, Tn, 512, 512);
    k_rmsnorm_b<<<Tn, 256, 0, stream>>>(h, n2, xnb, 512, 512, EPS_C);
    k_gemm_mfma<0><<<dim3(64, 17), 256, 0, stream>>>(xnb, ffib, uv, Tn, 4096, 512);
    k_swiglu<<<16448, 256, 0, stream>>>(uv, gatedb);
    k_gemm_mfma<1><<<dim3(8, 17), 256, 0, stream>>>(gatedb, ffob, h, Tn, 512, 2048);
  }

  k_rmsnorm<<<Tn, 256, 0, stream>>>(h, final_norm, zfin, 512, 512, EPS_C);
  k_final<<<Tn, 192, 0, stream>>>(zfin, out_W, (float*)d_out);
}

// Round 11
// 1550.740 us; speedup vs baseline: 6.2835x; 1.2828x over previous
//
#include <hip/hip_runtime.h>
#include <hip/hip_bf16.h>

// Money_former MLA DINT — round 11: bf16 probs + MFMA PV (+V^T transpose),
// fused ffi+SwiGLU, 64x64 GEMM tile for small-N projections, on-the-fly
// f32->bf16 weight staging (tobf16 kernels deleted), merged colmean2+wv.
// T=2056, D=512, 2 layers, 16 logical heads (8 pairs) of 48.

#define Tn 2056
#define LPn 257
#define Dn 512

static constexpr float SCALING_C = 0.14433756729740643f;   // 48^-0.5
static constexpr float EPS_C     = 1.1920928955078125e-07f;

typedef float f32x4 __attribute__((ext_vector_type(4)));
typedef short bf16x8 __attribute__((ext_vector_type(8)));
typedef unsigned short u16x8 __attribute__((ext_vector_type(8)));

__device__ __forceinline__ float bu2f(unsigned short u) {
  return __uint_as_float((unsigned int)u << 16);
}
__device__ __forceinline__ unsigned short f2bu(float f) {
  __hip_bfloat16 h = __float2bfloat16(f);
  return *reinterpret_cast<unsigned short*>(&h);
}

// ---------------- sentinel ----------------
__global__ __launch_bounds__(256) void k_fill42(float* __restrict__ out, int n) {
  int i = blockIdx.x * 256 + threadIdx.x;
  if (i < n) out[i] = 42.0f;
}

// ---------------- RoPE tables ----------------
__global__ __launch_bounds__(256) void k_freqs(float* __restrict__ cosb, float* __restrict__ sinb) {
  int idx = blockIdx.x * 256 + threadIdx.x;
  if (idx >= 256 * 8) return;
  int pos = idx >> 3, j = idx & 7;
  float fb = powf(10000.f, -(float)j * 0.125f);            // 1/10000^(j/8)
  float ramp = fminf(fmaxf((float)j * 0.25f, 0.f), 1.f);   // low=0, high=4
  float sm = 1.f - ramp;
  float fr = fb * (1.f / 40.f) * (1.f - sm) + fb * sm;
  float ang = (float)pos * fr;
  cosb[idx] = cosf(ang);
  sinb[idx] = sinf(ang);
}

// ---------------- Embedding ----------------
__global__ __launch_bounds__(256) void k_embed(const float* __restrict__ x,
                                               const float* __restrict__ ticker_emb,
                                               const float* __restrict__ sep_emb,
                                               const float* __restrict__ shared_W,
                                               const float* __restrict__ unique_W,
                                               const int* __restrict__ sep_idx,
                                               const int* __restrict__ tickers,
                                               float* __restrict__ h) {
  int t = blockIdx.x;
  int c = blockIdx.y * 256 + threadIdx.x;
  int l = t >> 3, s = t & 7;
  float val;
  if (l == 0) {
    val = sep_emb[sep_idx[0] * Dn + c];
  } else {
    const float* xr = x + ((size_t)(l - 1) * 8 + s) * 32;
    const float* w = (c < 384) ? (shared_W + (size_t)c * 32)
                               : (unique_W + ((size_t)s * 128 + (c - 384)) * 32);
    float acc = 0.f;
#pragma unroll
    for (int f = 0; f < 32; f++) acc = fmaf(xr[f], w[f], acc);
    val = acc;
  }
  val += ticker_emb[(size_t)tickers[s] * Dn + c];
  h[(size_t)t * Dn + c] = val;
}

// ---------------- Row RMSNorm, f32 out ----------------
__global__ __launch_bounds__(256) void k_rmsnorm(const float* __restrict__ in,
                                                 const float* __restrict__ w,
                                                 float* __restrict__ out,
                                                 int ncols, int in_stride, float eps) {
  int row = blockIdx.x;
  const float* xr = in + (size_t)row * in_stride;
  float ss = 0.f;
  for (int c = threadIdx.x; c < ncols; c += 256) { float v = xr[c]; ss = fmaf(v, v, ss); }
  for (int off = 1; off < 64; off <<= 1) ss += __shfl_xor(ss, off);
  __shared__ float red[4];
  if ((threadIdx.x & 63) == 0) red[threadIdx.x >> 6] = ss;
  __syncthreads();
  float tot = red[0] + red[1] + red[2] + red[3];
  float scale = rsqrtf(tot / (float)ncols + eps);
  for (int c = threadIdx.x; c < ncols; c += 256)
    out[(size_t)row * ncols + c] = xr[c] * scale * w[c];
}

// ---------------- Row RMSNorm, bf16 out ----------------
__global__ __launch_bounds__(256) void k_rmsnorm_b(const float* __restrict__ in,
                                                   const float* __restrict__ w,
                                                   __hip_bfloat16* __restrict__ out,
                                                   int ncols, int in_stride, float eps) {
  int row = blockIdx.x;
  const float* xr = in + (size_t)row * in_stride;
  float ss = 0.f;
  for (int c = threadIdx.x; c < ncols; c += 256) { float v = xr[c]; ss = fmaf(v, v, ss); }
  for (int off = 1; off < 64; off <<= 1) ss += __shfl_xor(ss, off);
  __shared__ float red[4];
  if ((threadIdx.x & 63) == 0) red[threadIdx.x >> 6] = ss;
  __syncthreads();
  float tot = red[0] + red[1] + red[2] + red[3];
  float scale = rsqrtf(tot / (float)ncols + eps);
  for (int c = threadIdx.x; c < ncols; c += 256)
    out[(size_t)row * ncols + c] = __float2bfloat16(xr[c] * scale * w[c]);
}

// ---------------- 64x64 MFMA GEMM: C (+)= A[M,K]bf16 @ (B[N,K]f32)^T ----------------
// B staged with on-the-fly f32->bf16 convert. 4 waves, wave w rows [w*16,+16).
template <int MODE>
__global__ __launch_bounds__(256) void k_gemm64(const __hip_bfloat16* __restrict__ A,
                                                const float* __restrict__ B,
                                                float* __restrict__ C,
                                                int M, int N, int K) {
  __shared__ unsigned short Als[64][40];
  __shared__ unsigned short Bls[64][40];
  int bm = blockIdx.y * 64, bn = blockIdx.x * 64;
  int tid = threadIdx.x;
  int wave = tid >> 6, lane = tid & 63;
  int lrow = lane & 15, lgrp = lane >> 4;
  f32x4 acc[4] = {};
  for (int k0 = 0; k0 < K; k0 += 32) {
    {
      int row = tid >> 2, cg = tid & 3;
      u16x8 v = {0, 0, 0, 0, 0, 0, 0, 0};
      if (bm + row < M)
        v = *reinterpret_cast<const u16x8*>(A + (size_t)(bm + row) * K + k0 + cg * 8);
      *reinterpret_cast<u16x8*>(&Als[row][cg * 8]) = v;
    }
    {
      int row = tid >> 2, cg = tid & 3;
      u16x8 v = {0, 0, 0, 0, 0, 0, 0, 0};
      if (bn + row < N) {
        const float* bp = B + (size_t)(bn + row) * K + k0 + cg * 8;
        f32x4 b0 = *reinterpret_cast<const f32x4*>(bp);
        f32x4 b1 = *reinterpret_cast<const f32x4*>(bp + 4);
#pragma unroll
        for (int e = 0; e < 4; e++) { v[e] = f2bu(b0[e]); v[e + 4] = f2bu(b1[e]); }
      }
      *reinterpret_cast<u16x8*>(&Bls[row][cg * 8]) = v;
    }
    __syncthreads();
    bf16x8 af = *reinterpret_cast<const bf16x8*>(&Als[wave * 16 + lrow][lgrp * 8]);
    bf16x8 bfr[4];
#pragma unroll
    for (int ni = 0; ni < 4; ni++)
      bfr[ni] = *reinterpret_cast<const bf16x8*>(&Bls[ni * 16 + lrow][lgrp * 8]);
#pragma unroll
    for (int ni = 0; ni < 4; ni++)
      acc[ni] = __builtin_amdgcn_mfma_f32_16x16x32_bf16(af, bfr[ni], acc[ni], 0, 0, 0);
    __syncthreads();
  }
#pragma unroll
  for (int ni = 0; ni < 4; ni++)
#pragma unroll
    for (int r = 0; r < 4; r++) {
      int row = bm + wave * 16 + lgrp * 4 + r;
      int col = bn + ni * 16 + lrow;
      if (row < M && col < N) {
        if (MODE) C[(size_t)row * N + col] += acc[ni][r];
        else      C[(size_t)row * N + col] = acc[ni][r];
      }
    }
}

// ---------------- Fused FFN-in + SwiGLU: gated[t][f] = u*silu(v), bf16 out ----------------
// A = z bf16 (T x 512); Bw = ff_in f32 (4096 x 512); tile 128M x 64 gated-cols.
__global__ __launch_bounds__(256) void k_ffn(const __hip_bfloat16* __restrict__ A,
                                             const float* __restrict__ Bw,
                                             __hip_bfloat16* __restrict__ gatedb) {
  __shared__ unsigned short Als[128][40];
  __shared__ unsigned short Bls[128][40];
  int bm = blockIdx.y * 128, bn = blockIdx.x * 64;
  int tid = threadIdx.x;
  int wave = tid >> 6, lane = tid & 63;
  int lrow = lane & 15, lgrp = lane >> 4;
  f32x4 acc[2][8] = {};
  for (int k0 = 0; k0 < 512; k0 += 32) {
#pragma unroll
    for (int i = 0; i < 2; i++) {
      int vecIdx = tid + i * 256;
      int row = vecIdx >> 2, cg = vecIdx & 3;
      u16x8 v = {0, 0, 0, 0, 0, 0, 0, 0};
      if (bm + row < Tn)
        v = *reinterpret_cast<const u16x8*>(A + (size_t)(bm + row) * 512 + k0 + cg * 8);
      *reinterpret_cast<u16x8*>(&Als[row][cg * 8]) = v;
    }
#pragma unroll
    for (int i = 0; i < 2; i++) {
      int vecIdx = tid + i * 256;
      int row = vecIdx >> 2, cg = vecIdx & 3;
      int grow = (row < 64) ? (bn + row) : (2048 + bn + (row - 64));
      const float* bp = Bw + (size_t)grow * 512 + k0 + cg * 8;
      f32x4 b0 = *reinterpret_cast<const f32x4*>(bp);
      f32x4 b1 = *reinterpret_cast<const f32x4*>(bp + 4);
      u16x8 v;
#pragma unroll
      for (int e = 0; e < 4; e++) { v[e] = f2bu(b0[e]); v[e + 4] = f2bu(b1[e]); }
      *reinterpret_cast<u16x8*>(&Bls[row][cg * 8]) = v;
    }
    __syncthreads();
    bf16x8 af[2], bfr[8];
#pragma unroll
    for (int mi = 0; mi < 2; mi++)
      af[mi] = *reinterpret_cast<const bf16x8*>(&Als[wave * 32 + mi * 16 + lrow][lgrp * 8]);
#pragma unroll
    for (int ni = 0; ni < 8; ni++)
      bfr[ni] = *reinterpret_cast<const bf16x8*>(&Bls[ni * 16 + lrow][lgrp * 8]);
#pragma unroll
    for (int mi = 0; mi < 2; mi++)
#pragma unroll
      for (int ni = 0; ni < 8; ni++)
        acc[mi][ni] = __builtin_amdgcn_mfma_f32_16x16x32_bf16(af[mi], bfr[ni], acc[mi][ni], 0, 0, 0);
    __syncthreads();
  }
#pragma unroll
  for (int mi = 0; mi < 2; mi++)
#pragma unroll
    for (int ni = 0; ni < 4; ni++)
#pragma unroll
      for (int r = 0; r < 4; r++) {
        int row = bm + wave * 32 + mi * 16 + lgrp * 4 + r;
        int col = bn + ni * 16 + lrow;
        if (row < Tn) {
          float u = acc[mi][ni][r];
          float vv = acc[mi][ni + 4][r];
          float sv = vv / (1.f + expf(-vv));
          gatedb[(size_t)row * 2048 + col] = __float2bfloat16(u * sv);
        }
      }
}

// ---------------- Scores MFMA: masked+scaled bf16 out ----------------
__global__ __launch_bounds__(256) void k_scores_mfma(const __hip_bfloat16* __restrict__ qhb,
                                                     const __hip_bfloat16* __restrict__ khb,
                                                     unsigned short* __restrict__ probsb, int hh0) {
  __shared__ unsigned short Als[128][72];
  __shared__ unsigned short Bls[64][72];
  int bm = blockIdx.y * 128, bn = blockIdx.x * 64;
  int e = blockIdx.z, hh = hh0 + e;
  const __hip_bfloat16* A = qhb + hh * 48;
  const __hip_bfloat16* B = khb + hh * 48;
  unsigned short* C = probsb + (size_t)e * Tn * Tn;
  int tid = threadIdx.x;
  int wave = tid >> 6, lane = tid & 63;
  int lrow = lane & 15, lgrp = lane >> 4;
#pragma unroll
  for (int i = 0; i < 4; i++) {
    int vecIdx = tid + i * 256;
    int row = vecIdx >> 3, cg = vecIdx & 7;
    u16x8 v = {0, 0, 0, 0, 0, 0, 0, 0};
    int grow = bm + row;
    if (grow < Tn && cg < 6) v = *reinterpret_cast<const u16x8*>(A + (size_t)grow * 768 + cg * 8);
    *reinterpret_cast<u16x8*>(&Als[row][cg * 8]) = v;
  }
#pragma unroll
  for (int i = 0; i < 2; i++) {
    int vecIdx = tid + i * 256;
    int row = vecIdx >> 3, cg = vecIdx & 7;
    u16x8 v = {0, 0, 0, 0, 0, 0, 0, 0};
    int gcol = bn + row;
    if (gcol < Tn && cg < 6) v = *reinterpret_cast<const u16x8*>(B + (size_t)gcol * 768 + cg * 8);
    *reinterpret_cast<u16x8*>(&Bls[row][cg * 8]) = v;
  }
  __syncthreads();
  f32x4 acc[2][4] = {};
#pragma unroll
  for (int ks = 0; ks < 2; ks++) {
    bf16x8 af[2], bfr[4];
#pragma unroll
    for (int mi = 0; mi < 2; mi++)
      af[mi] = *reinterpret_cast<const bf16x8*>(&Als[wave * 32 + mi * 16 + lrow][ks * 32 + lgrp * 8]);
#pragma unroll
    for (int ni = 0; ni < 4; ni++)
      bfr[ni] = *reinterpret_cast<const bf16x8*>(&Bls[ni * 16 + lrow][ks * 32 + lgrp * 8]);
#pragma unroll
    for (int mi = 0; mi < 2; mi++)
#pragma unroll
      for (int ni = 0; ni < 4; ni++)
        acc[mi][ni] = __builtin_amdgcn_mfma_f32_16x16x32_bf16(af[mi], bfr[ni], acc[mi][ni], 0, 0, 0);
  }
#pragma unroll
  for (int mi = 0; mi < 2; mi++)
#pragma unroll
    for (int ni = 0; ni < 4; ni++)
#pragma unroll
      for (int r = 0; r < 4; r++) {
        int row = bm + wave * 32 + mi * 16 + lgrp * 4 + r;
        int col = bn + ni * 16 + lrow;
        if (row < Tn && col < Tn) {
          float sv = ((col % LPn) > (row % LPn)) ? -1e9f : acc[mi][ni][r] * SCALING_C;
          C[(size_t)row * Tn + col] = f2bu(sv);
        }
      }
}

// ---------------- Assemble q/k (partial RoPE, bf16 out) ----------------
__global__ __launch_bounds__(256) void k_qkv(const float* __restrict__ qf,
                                             const float* __restrict__ kvb,
                                             const float* __restrict__ ckv,
                                             const float* __restrict__ cosb,
                                             const float* __restrict__ sinb,
                                             __hip_bfloat16* __restrict__ qhb,
                                             __hip_bfloat16* __restrict__ khb) {
  int t = blockIdx.x;
  int l = t >> 3;
  for (int idx = threadIdx.x; idx < 768; idx += 256) {
    int hh = idx / 48, dc = idx % 48;
    int hd = hh >> 1, e = hh & 1;
    float qv, kvv;
    if (dc < 32) {
      qv  = qf [(size_t)t * 768  + hd * 96  + e * 32 + dc];
      kvv = kvb[(size_t)t * 1024 + hd * 128 + e * 32 + dc];
    } else {
      int rj = dc - 32;            // 0..15
      int p = rj >> 1; int isim = rj & 1;
      float xr_q = qf[(size_t)t * 768 + hd * 96 + 64 + e * 16 + p * 2];
      float xi_q = qf[(size_t)t * 768 + hd * 96 + 64 + e * 16 + p * 2 + 1];
      float xr_k = ckv[(size_t)t * 160 + 128 + e * 16 + p * 2];
      float xi_k = ckv[(size_t)t * 160 + 128 + e * 16 + p * 2 + 1];
      if (l == 0) {
        qv  = isim ? xi_q : xr_q;
        kvv = isim ? xi_k : xr_k;
      } else {
        float c = cosb[(l - 1) * 8 + p], s = sinb[(l - 1) * 8 + p];
        if (!isim) { qv = xr_q * c - xi_q * s; kvv = xr_k * c - xi_k * s; }
        else       { qv = xr_q * s + xi_q * c; kvv = xr_k * s + xi_k * c; }
      }
    }
    qhb[(size_t)t * 768 + idx] = __float2bfloat16(qv);
    khb[(size_t)t * 768 + idx] = __float2bfloat16(kvv);
  }
}

// ---------------- V transpose: vtb[c][t] bf16 = kvb[t][hd*128+64+dv] ----------------
__global__ __launch_bounds__(256) void k_vtrans(const float* __restrict__ kvb,
                                                __hip_bfloat16* __restrict__ vtb) {
  __shared__ float tile[64][65];
  int tt = blockIdx.x, ct = blockIdx.y;    // (33, 8)
  int tid = threadIdx.x;
#pragma unroll
  for (int rep = 0; rep < 16; rep++) {
    int idx = rep * 256 + tid;
    int tr = idx >> 6, cc = idx & 63;
    int t = tt * 64 + tr;
    tile[tr][cc] = (t < Tn) ? kvb[(size_t)t * 1024 + ct * 128 + 64 + cc] : 0.f;
  }
  __syncthreads();
#pragma unroll
  for (int rep = 0; rep < 16; rep++) {
    int idx = rep * 256 + tid;
    int cr = idx >> 6, tc = idx & 63;
    int t = tt * 64 + tc;
    if (t < Tn)
      vtb[(size_t)(ct * 64 + cr) * Tn + t] = __float2bfloat16(tile[tc][cr]);
  }
}

// ---------------- lambda scalar ----------------
__global__ void k_lam(const float* __restrict__ lq1, const float* __restrict__ lk1,
                      const float* __restrict__ lq2, const float* __restrict__ lk2,
                      float lamc, float* __restrict__ out) {
  float d1 = 0.f, d2 = 0.f;
  for (int k = 0; k < 32; k++) { d1 = fmaf(lq1[k], lk1[k], d1); d2 = fmaf(lq2[k], lk2[k], d2); }
  out[0] = expf(d1) - expf(d2) + lamc;
}

// ---------------- Row softmax in-place, bf16 (2 planes) ----------------
__global__ __launch_bounds__(256) void k_softmax_rows(unsigned short* __restrict__ probsb) {
  unsigned short* prow = probsb + ((size_t)blockIdx.y * Tn + blockIdx.x) * Tn;
  int tid = threadIdx.x;
  float v[9];
  float lmax = -3.4e38f;
#pragma unroll
  for (int it = 0; it < 9; it++) {
    int j = tid + it * 256;
    v[it] = (j < Tn) ? bu2f(prow[j]) : -3.4e38f;
    lmax = fmaxf(lmax, v[it]);
  }
  for (int off = 1; off < 64; off <<= 1) lmax = fmaxf(lmax, __shfl_xor(lmax, off));
  __shared__ float red[4];
  if ((tid & 63) == 0) red[tid >> 6] = lmax;
  __syncthreads();
  float gmax = fmaxf(fmaxf(red[0], red[1]), fmaxf(red[2], red[3]));
  __syncthreads();
  float lsum = 0.f;
#pragma unroll
  for (int it = 0; it < 9; it++) { v[it] = expf(v[it] - gmax); lsum += v[it]; }
  for (int off = 1; off < 64; off <<= 1) lsum += __shfl_xor(lsum, off);
  if ((tid & 63) == 0) red[tid >> 6] = lsum;
  __syncthreads();
  float inv = 1.f / (red[0] + red[1] + red[2] + red[3]);
#pragma unroll
  for (int it = 0; it < 9; it++) {
    int j = tid + it * 256;
    if (j < Tn) prow[j] = f2bu(v[it] * inv);
  }
}

// ---------------- Column mean of a1 (stage 1), bf16 in ----------------
__global__ __launch_bounds__(256) void k_colmean_part(const unsigned short* __restrict__ a1,
                                                      float* __restrict__ partial) {
  int j = blockIdx.x * 256 + threadIdx.x;
  int ib = blockIdx.y;
  if (j >= Tn) return;
  int i0 = ib * 64, i1 = min(i0 + 64, Tn);
  float acc = 0.f;
  for (int i = i0; i < i1; i++) acc += bu2f(a1[(size_t)i * Tn + j]);
  partial[(size_t)ib * Tn + j] = acc;
}

// ---------------- merged colmean2 + wv: W[jmod][dv] = sum_k lamg[j_k]*V[j_k][dv] ----------------
__global__ __launch_bounds__(64) void k_gwv(const float* __restrict__ partial,
                                            const __hip_bfloat16* __restrict__ vtb,
                                            const float* __restrict__ lamp,
                                            float* __restrict__ Wb, int ph) {
  int jmod = blockIdx.x;         // 0..256
  int l = threadIdx.x;           // 0..63
  int k = l >> 3, sub = l & 7;
  int jk = jmod + 257 * k;
  float s = 0.f;
  for (int ib = sub; ib < 33; ib += 8) s += partial[(size_t)ib * Tn + jk];
  for (int m = 1; m < 8; m <<= 1) s += __shfl_xor(s, m);
  float gv = s * (1.f / (float)Tn) * lamp[0];   // all lanes in 8-group hold g_k
  const __hip_bfloat16* vrow = vtb + (size_t)(ph * 64 + l) * Tn;
  float acc = 0.f;
#pragma unroll
  for (int kk = 0; kk < 8; kk++) {
    float gk = __shfl(gv, kk * 8);
    acc = fmaf(gk, __bfloat162float(vrow[jmod + 257 * kk]), acc);
  }
  Wb[jmod * 64 + l] = acc;
}

// ---------------- C[c][dv] = sum_{m in 16-chunk c} W[m][dv] ----------------
__global__ __launch_bounds__(64) void k_chunksum(const float* __restrict__ Wb,
                                                 float* __restrict__ Cb) {
  int c = blockIdx.x;            // 0..16
  int lane = threadIdx.x;
  int m0 = c * 16, m1 = min(m0 + 16, LPn);
  float acc = 0.f;
  for (int m = m0; m < m1; m++) acc += Wb[m * 64 + lane];
  Cb[c * 64 + lane] = acc;
}

// ---------------- PV MFMA: pvpart[kc] = (a1-lam*a2)[.,chunk] @ V[chunk,.] ----------------
__global__ __launch_bounds__(256) void k_pv_mfma(const unsigned short* __restrict__ probsb,
                                                 const __hip_bfloat16* __restrict__ vtb,
                                                 const float* __restrict__ lamp,
                                                 float* __restrict__ pvpart, int ph) {
  __shared__ unsigned short Als[128][40];
  __shared__ unsigned short Bls[64][40];
  int bm = blockIdx.x * 128;
  int kc = blockIdx.y;                 // 0..15
  int jbase = kc * 128;
  int jcount = (kc == 15) ? 136 : 128;
  float lam = lamp[0];
  const unsigned short* p0 = probsb;
  const unsigned short* p1 = probsb + (size_t)Tn * Tn;
  const unsigned short* vt = (const unsigned short*)vtb + (size_t)ph * 64 * Tn;
  int tid = threadIdx.x;
  int wave = tid >> 6, lane = tid & 63;
  int lrow = lane & 15, lgrp = lane >> 4;
  f32x4 acc[2][4] = {};
  for (int k0 = 0; k0 < jcount; k0 += 32) {
#pragma unroll
    for (int i = 0; i < 2; i++) {
      int vecIdx = tid + i * 256;
      int row = vecIdx >> 2, cg = vecIdx & 3;
      int gm = bm + row;
      int kk = k0 + cg * 8;
      u16x8 cmb = {0, 0, 0, 0, 0, 0, 0, 0};
      if (gm < Tn && kk < jcount) {
        size_t base = (size_t)gm * Tn + jbase + kk;
        u16x8 a1 = *reinterpret_cast<const u16x8*>(p0 + base);
        u16x8 a2 = *reinterpret_cast<const u16x8*>(p1 + base);
#pragma unroll
        for (int ee = 0; ee < 8; ee++)
          cmb[ee] = f2bu(fmaf(-lam, bu2f(a2[ee]), bu2f(a1[ee])));
      }
      *reinterpret_cast<u16x8*>(&Als[row][cg * 8]) = cmb;
    }
    {
      int row = tid >> 2, cg = tid & 3;
      int kk = k0 + cg * 8;
      u16x8 v = {0, 0, 0, 0, 0, 0, 0, 0};
      if (kk < jcount)
        v = *reinterpret_cast<const u16x8*>(vt + (size_t)row * Tn + jbase + kk);
      *reinterpret_cast<u16x8*>(&Bls[row][cg * 8]) = v;
    }
    __syncthreads();
    bf16x8 af[2], bfr[4];
#pragma unroll
    for (int mi = 0; mi < 2; mi++)
      af[mi] = *reinterpret_cast<const bf16x8*>(&Als[wave * 32 + mi * 16 + lrow][lgrp * 8]);
#pragma unroll
    for (int ni = 0; ni < 4; ni++)
      bfr[ni] = *reinterpret_cast<const bf16x8*>(&Bls[ni * 16 + lrow][lgrp * 8]);
#pragma unroll
    for (int mi = 0; mi < 2; mi++)
#pragma unroll
      for (int ni = 0; ni < 4; ni++)
        acc[mi][ni] = __builtin_amdgcn_mfma_f32_16x16x32_bf16(af[mi], bfr[ni], acc[mi][ni], 0, 0, 0);
    __syncthreads();
  }
#pragma unroll
  for (int mi = 0; mi < 2; mi++)
#pragma unroll
    for (int ni = 0; ni < 4; ni++)
#pragma unroll
      for (int r = 0; r < 4; r++) {
        int row = bm + wave * 32 + mi * 16 + lgrp * 4 + r;
        int col = ni * 16 + lrow;
        if (row < Tn)
          pvpart[((size_t)kc * Tn + row) * 64 + col] = acc[mi][ni][r];
      }
}

// ---------------- reduce 16 partials + inline G-prefix + head-RMSNorm -> bf16 ----------------
__global__ __launch_bounds__(256) void k_pv_reduce(const float* __restrict__ pvpart,
                                                   const float* __restrict__ Wb,
                                                   const float* __restrict__ Cb,
                                                   const float* __restrict__ hnw,
                                                   __hip_bfloat16* __restrict__ onormb, int ph) {
  int w = threadIdx.x >> 6, lane = threadIdx.x & 63;
  int i = blockIdx.x * 4 + w;
  int imod = i % LPn;            // wave-uniform
  int cidx = imod >> 4;
  float s = 0.f;
  for (int c = 0; c < cidx; c++) s += Cb[c * 64 + lane];
  for (int m = cidx * 16; m <= imod; m++) s += Wb[m * 64 + lane];
#pragma unroll
  for (int kc = 0; kc < 16; kc++) s += pvpart[((size_t)kc * Tn + i) * 64 + lane];
  float ss = s * s;
  for (int off = 1; off < 64; off <<= 1) ss += __shfl_xor(ss, off);
  float scale = rsqrtf(ss * (1.f / 64.f) + 1e-5f);
  onormb[((size_t)ph * Tn + i) * 64 + lane] = __float2bfloat16(s * scale * hnw[lane]);
}

// ---------------- final head (float32 out) ----------------
__global__ __launch_bounds__(192) void k_final(const float* __restrict__ z,
                                               const float* __restrict__ outW,
                                               float* __restrict__ out) {
  int t = blockIdx.x;
  int p = threadIdx.x >> 6, lane = threadIdx.x & 63;
  float acc = 0.f;
  for (int m = lane; m < 512; m += 64) acc = fmaf(z[(size_t)t * 512 + m], outW[(size_t)p * 512 + m], acc);
  for (int off = 1; off < 64; off <<= 1) acc += __shfl_xor(acc, off);
  if (lane == 0) out[(size_t)t * 3 + p] = acc;
}

extern "C" void kernel_launch(void* const* d_in, const int* in_sizes, int n_in,
                              void* d_out, int out_size, void* d_ws, size_t ws_size,
                              hipStream_t stream) {
  const float* x          = (const float*)d_in[0];
  const float* ticker_emb = (const float*)d_in[1];
  const float* sep_emb    = (const float*)d_in[2];
  const float* shared_W   = (const float*)d_in[3];
  const float* unique_W   = (const float*)d_in[4];
  const float* norm1_w    = (const float*)d_in[5];
  const float* norm2_w    = (const float*)d_in[6];
  const float* kv_down_W  = (const float*)d_in[7];
  const float* q_down_W   = (const float*)d_in[8];
  const float* kv_up_W    = (const float*)d_in[9];
  const float* q_up_W     = (const float*)d_in[10];
  const float* kv_norm_w  = (const float*)d_in[11];
  const float* q_norm_w   = (const float*)d_in[12];
  const float* o_W        = (const float*)d_in[13];
  const float* lam_q1     = (const float*)d_in[14];
  const float* lam_k1     = (const float*)d_in[15];
  const float* lam_q2     = (const float*)d_in[16];
  const float* lam_k2     = (const float*)d_in[17];
  const float* head_norm_w= (const float*)d_in[18];
  const float* ff_in_W    = (const float*)d_in[19];
  const float* ff_out_W   = (const float*)d_in[20];
  const float* final_norm = (const float*)d_in[21];
  const float* out_W      = (const float*)d_in[22];
  const int*   seperator  = (const int*)d_in[23];
  const int*   tickers    = (const int*)d_in[24];
  (void)in_sizes; (void)n_in;

  float* W = (float*)d_ws;
  size_t off = 0;
  auto alloc = [&](size_t n) { float* p = W + off; off += n; return p; };
  float* cosb  = alloc(2048);
  float* sinb  = alloc(2048);
  float* h     = alloc((size_t)Tn * Dn);
  float* xnb_f = alloc((size_t)Tn * 256);         // bf16 T x 512 (also z)
  float* ckv   = alloc((size_t)Tn * 160);         // ckv+qlat host onormb later
  float* qlat  = alloc((size_t)Tn * 192);
  float* ckvnb_f = alloc((size_t)Tn * 64);        // bf16 T x 128
  float* qlatnb_f = alloc((size_t)Tn * 96);       // bf16 T x 192
  float* kvb   = alloc((size_t)Tn * 1024);        // pvpart / gatedb overlays
  float* qf    = alloc((size_t)Tn * 768);         // zfin overlay
  float* qhb_f = alloc((size_t)Tn * 384);         // bf16 T x 768
  float* khb_f = alloc((size_t)Tn * 384);         // bf16 T x 768
  float* vtb_f = alloc((size_t)Tn * 256);         // bf16 512 x T (transposed V)
  float* lam   = alloc(4);
  float* partial = alloc((size_t)33 * Tn);        // also hosts Wb/Cb
  float* probs_f = alloc((size_t)Tn * Tn);        // bf16 2 planes x T^2

  __hip_bfloat16* xnb    = (__hip_bfloat16*)xnb_f;
  __hip_bfloat16* ckvnb  = (__hip_bfloat16*)ckvnb_f;
  __hip_bfloat16* qlatnb = (__hip_bfloat16*)qlatnb_f;
  __hip_bfloat16* onormb = (__hip_bfloat16*)ckv;     // bf16 T x 512 over ckv+qlat
  __hip_bfloat16* gatedb = (__hip_bfloat16*)kvb;     // bf16 T x 2048
  __hip_bfloat16* qhb    = (__hip_bfloat16*)qhb_f;
  __hip_bfloat16* khb    = (__hip_bfloat16*)khb_f;
  __hip_bfloat16* vtb    = (__hip_bfloat16*)vtb_f;
  unsigned short* probsb = (unsigned short*)probs_f;
  float* pvpart = kvb;       // 16*T*64 f32 == T*1024 f32
  float* zfin   = qf;
  float* Wb     = partial;             // 257*64
  float* Cb     = partial + 257 * 64;  // 17*64

  size_t needed = off * sizeof(float);            // ~50.9 MB (< 79.5 proven)
  if (ws_size < needed) {
    k_fill42<<<(out_size + 255) / 256, 256, 0, stream>>>((float*)d_out, out_size);
    return;
  }

  k_freqs<<<8, 256, 0, stream>>>(cosb, sinb);
  k_embed<<<dim3(Tn, 2), 256, 0, stream>>>(x, ticker_emb, sep_emb, shared_W, unique_W,
                                           seperator, tickers, h);

  for (int d = 0; d < 2; d++) {
    const float* n1   = norm1_w + d * 512;
    const float* n2   = norm2_w + d * 512;
    const float* kvd  = kv_down_W + (size_t)d * 160 * 512;
    const float* qd   = q_down_W + (size_t)d * 192 * 512;
    const float* kvu  = kv_up_W + (size_t)d * 1024 * 128;
    const float* qu   = q_up_W + (size_t)d * 768 * 192;
    const float* kvnw = kv_norm_w + d * 128;
    const float* qnw  = q_norm_w + d * 192;
    const float* oW   = o_W + (size_t)d * 512 * 512;
    const float* hnw  = head_norm_w + d * 64;
    const float* ffi  = ff_in_W + (size_t)d * 4096 * 512;
    const float* ffo  = ff_out_W + (size_t)d * 512 * 2048;
    float lamc = 0.8f - 0.6f * expf(-0.3f * (float)d);

    k_rmsnorm_b<<<Tn, 256, 0, stream>>>(h, n1, xnb, 512, 512, EPS_C);
    k_gemm64<0><<<dim3(3, 33), 256, 0, stream>>>(xnb, kvd, ckv, Tn, 160, 512);
    k_rmsnorm_b<<<Tn, 256, 0, stream>>>(ckv, kvnw, ckvnb, 128, 160, EPS_C);
    k_gemm64<0><<<dim3(16, 33), 256, 0, stream>>>(ckvnb, kvu, kvb, Tn, 1024, 128);
    k_gemm64<0><<<dim3(3, 33), 256, 0, stream>>>(xnb, qd, qlat, Tn, 192, 512);
    k_rmsnorm_b<<<Tn, 256, 0, stream>>>(qlat, qnw, qlatnb, 192, 192, EPS_C);
    k_gemm64<0><<<dim3(12, 33), 256, 0, stream>>>(qlatnb, qu, qf, Tn, 768, 192);
    k_qkv<<<Tn, 256, 0, stream>>>(qf, kvb, ckv, cosb, sinb, qhb, khb);
    k_vtrans<<<dim3(33, 8), 256, 0, stream>>>(kvb, vtb);
    k_lam<<<1, 1, 0, stream>>>(lam_q1 + d * 32, lam_k1 + d * 32,
                               lam_q2 + d * 32, lam_k2 + d * 32, lamc, lam);

    for (int ph = 0; ph < 8; ph++) {
      k_scores_mfma<<<dim3(33, 17, 2), 256, 0, stream>>>(qhb, khb, probsb, 2 * ph);
      k_softmax_rows<<<dim3(Tn, 2), 256, 0, stream>>>(probsb);
      k_colmean_part<<<dim3(9, 33), 256, 0, stream>>>(probsb, partial);
      k_gwv<<<257, 64, 0, stream>>>(partial, vtb, lam, Wb, ph);
      k_chunksum<<<17, 64, 0, stream>>>(Wb, Cb);
      k_pv_mfma<<<dim3(17, 16), 256, 0, stream>>>(probsb, vtb, lam, pvpart, ph);
      k_pv_reduce<<<514, 256, 0, stream>>>(pvpart, Wb, Cb, hnw, onormb, ph);
    }

    k_gemm64<1><<<dim3(8, 33), 256, 0, stream>>>(onormb, oW, h, Tn, 512, 512);   // h += o-proj
    k_rmsnorm_b<<<Tn, 256, 0, stream>>>(h, n2, xnb, 512, 512, EPS_C);
    k_ffn<<<dim3(32, 17), 256, 0, stream>>>(xnb, ffi, gatedb);
    k_gemm64<1><<<dim3(8, 33), 256, 0, stream>>>(gatedb, ffo, h, Tn, 512, 2048); // h += ffn
  }

  k_rmsnorm<<<Tn, 256, 0, stream>>>(h, final_norm, zfin, 512, 512, EPS_C);
  k_final<<<Tn, 192, 0, stream>>>(zfin, out_W, (float*)d_out);
}

// Round 12
// 867.943 us; speedup vs baseline: 11.2266x; 1.7867x over previous
//
#include <hip/hip_runtime.h>
#include <hip/hip_bf16.h>

// Money_former MLA DINT — round 12: fused 2-pass attention (no T^2 probs buffer).
// pass1: online row max/sum per head (MFMA scores, register state).
// pass2: recompute scores, P = a1 - lam*a2 via LDS tile, PV MFMA accumulated in
// registers over all j-tiles + colsum partials for the g-term.
// gwv/chunksum/pv_out batched over pairs. T=2056, D=512, 2 layers.

#define Tn 2056
#define LPn 257
#define Dn 512
#define TP 2112   // padded T (33*64)

static constexpr float SCALING_C = 0.14433756729740643f;   // 48^-0.5
static constexpr float EPS_C     = 1.1920928955078125e-07f;

typedef float f32x4 __attribute__((ext_vector_type(4)));
typedef short bf16x8 __attribute__((ext_vector_type(8)));
typedef unsigned short u16x8 __attribute__((ext_vector_type(8)));

__device__ __forceinline__ unsigned short f2bu(float f) {
  __hip_bfloat16 h = __float2bfloat16(f);
  return *reinterpret_cast<unsigned short*>(&h);
}

// ---------------- sentinel ----------------
__global__ __launch_bounds__(256) void k_fill42(float* __restrict__ out, int n) {
  int i = blockIdx.x * 256 + threadIdx.x;
  if (i < n) out[i] = 42.0f;
}

// ---------------- RoPE tables ----------------
__global__ __launch_bounds__(256) void k_freqs(float* __restrict__ cosb, float* __restrict__ sinb) {
  int idx = blockIdx.x * 256 + threadIdx.x;
  if (idx >= 256 * 8) return;
  int pos = idx >> 3, j = idx & 7;
  float fb = powf(10000.f, -(float)j * 0.125f);            // 1/10000^(j/8)
  float ramp = fminf(fmaxf((float)j * 0.25f, 0.f), 1.f);   // low=0, high=4
  float sm = 1.f - ramp;
  float fr = fb * (1.f / 40.f) * (1.f - sm) + fb * sm;
  float ang = (float)pos * fr;
  cosb[idx] = cosf(ang);
  sinb[idx] = sinf(ang);
}

// ---------------- Embedding ----------------
__global__ __launch_bounds__(256) void k_embed(const float* __restrict__ x,
                                               const float* __restrict__ ticker_emb,
                                               const float* __restrict__ sep_emb,
                                               const float* __restrict__ shared_W,
                                               const float* __restrict__ unique_W,
                                               const int* __restrict__ sep_idx,
                                               const int* __restrict__ tickers,
                                               float* __restrict__ h) {
  int t = blockIdx.x;
  int c = blockIdx.y * 256 + threadIdx.x;
  int l = t >> 3, s = t & 7;
  float val;
  if (l == 0) {
    val = sep_emb[sep_idx[0] * Dn + c];
  } else {
    const float* xr = x + ((size_t)(l - 1) * 8 + s) * 32;
    const float* w = (c < 384) ? (shared_W + (size_t)c * 32)
                               : (unique_W + ((size_t)s * 128 + (c - 384)) * 32);
    float acc = 0.f;
#pragma unroll
    for (int f = 0; f < 32; f++) acc = fmaf(xr[f], w[f], acc);
    val = acc;
  }
  val += ticker_emb[(size_t)tickers[s] * Dn + c];
  h[(size_t)t * Dn + c] = val;
}

// ---------------- Row RMSNorm, f32 out ----------------
__global__ __launch_bounds__(256) void k_rmsnorm(const float* __restrict__ in,
                                                 const float* __restrict__ w,
                                                 float* __restrict__ out,
                                                 int ncols, int in_stride, float eps) {
  int row = blockIdx.x;
  const float* xr = in + (size_t)row * in_stride;
  float ss = 0.f;
  for (int c = threadIdx.x; c < ncols; c += 256) { float v = xr[c]; ss = fmaf(v, v, ss); }
  for (int off = 1; off < 64; off <<= 1) ss += __shfl_xor(ss, off);
  __shared__ float red[4];
  if ((threadIdx.x & 63) == 0) red[threadIdx.x >> 6] = ss;
  __syncthreads();
  float tot = red[0] + red[1] + red[2] + red[3];
  float scale = rsqrtf(tot / (float)ncols + eps);
  for (int c = threadIdx.x; c < ncols; c += 256)
    out[(size_t)row * ncols + c] = xr[c] * scale * w[c];
}

// ---------------- Row RMSNorm, bf16 out ----------------
__global__ __launch_bounds__(256) void k_rmsnorm_b(const float* __restrict__ in,
                                                   const float* __restrict__ w,
                                                   __hip_bfloat16* __restrict__ out,
                                                   int ncols, int in_stride, float eps) {
  int row = blockIdx.x;
  const float* xr = in + (size_t)row * in_stride;
  float ss = 0.f;
  for (int c = threadIdx.x; c < ncols; c += 256) { float v = xr[c]; ss = fmaf(v, v, ss); }
  for (int off = 1; off < 64; off <<= 1) ss += __shfl_xor(ss, off);
  __shared__ float red[4];
  if ((threadIdx.x & 63) == 0) red[threadIdx.x >> 6] = ss;
  __syncthreads();
  float tot = red[0] + red[1] + red[2] + red[3];
  float scale = rsqrtf(tot / (float)ncols + eps);
  for (int c = threadIdx.x; c < ncols; c += 256)
    out[(size_t)row * ncols + c] = __float2bfloat16(xr[c] * scale * w[c]);
}

// ---------------- 64x64 MFMA GEMM: C (+)= A[M,K]bf16 @ (B[N,K]f32)^T ----------------
template <int MODE>
__global__ __launch_bounds__(256) void k_gemm64(const __hip_bfloat16* __restrict__ A,
                                                const float* __restrict__ B,
                                                float* __restrict__ C,
                                                int M, int N, int K) {
  __shared__ unsigned short Als[64][40];
  __shared__ unsigned short Bls[64][40];
  int bm = blockIdx.y * 64, bn = blockIdx.x * 64;
  int tid = threadIdx.x;
  int wave = tid >> 6, lane = tid & 63;
  int lrow = lane & 15, lgrp = lane >> 4;
  f32x4 acc[4] = {};
  for (int k0 = 0; k0 < K; k0 += 32) {
    {
      int row = tid >> 2, cg = tid & 3;
      u16x8 v = {0, 0, 0, 0, 0, 0, 0, 0};
      if (bm + row < M)
        v = *reinterpret_cast<const u16x8*>(A + (size_t)(bm + row) * K + k0 + cg * 8);
      *reinterpret_cast<u16x8*>(&Als[row][cg * 8]) = v;
    }
    {
      int row = tid >> 2, cg = tid & 3;
      u16x8 v = {0, 0, 0, 0, 0, 0, 0, 0};
      if (bn + row < N) {
        const float* bp = B + (size_t)(bn + row) * K + k0 + cg * 8;
        f32x4 b0 = *reinterpret_cast<const f32x4*>(bp);
        f32x4 b1 = *reinterpret_cast<const f32x4*>(bp + 4);
#pragma unroll
        for (int e = 0; e < 4; e++) { v[e] = f2bu(b0[e]); v[e + 4] = f2bu(b1[e]); }
      }
      *reinterpret_cast<u16x8*>(&Bls[row][cg * 8]) = v;
    }
    __syncthreads();
    bf16x8 af = *reinterpret_cast<const bf16x8*>(&Als[wave * 16 + lrow][lgrp * 8]);
    bf16x8 bfr[4];
#pragma unroll
    for (int ni = 0; ni < 4; ni++)
      bfr[ni] = *reinterpret_cast<const bf16x8*>(&Bls[ni * 16 + lrow][lgrp * 8]);
#pragma unroll
    for (int ni = 0; ni < 4; ni++)
      acc[ni] = __builtin_amdgcn_mfma_f32_16x16x32_bf16(af, bfr[ni], acc[ni], 0, 0, 0);
    __syncthreads();
  }
#pragma unroll
  for (int ni = 0; ni < 4; ni++)
#pragma unroll
    for (int r = 0; r < 4; r++) {
      int row = bm + wave * 16 + lgrp * 4 + r;
      int col = bn + ni * 16 + lrow;
      if (row < M && col < N) {
        if (MODE) C[(size_t)row * N + col] += acc[ni][r];
        else      C[(size_t)row * N + col] = acc[ni][r];
      }
    }
}

// ---------------- Fused FFN-in + SwiGLU ----------------
__global__ __launch_bounds__(256) void k_ffn(const __hip_bfloat16* __restrict__ A,
                                             const float* __restrict__ Bw,
                                             __hip_bfloat16* __restrict__ gatedb) {
  __shared__ unsigned short Als[128][40];
  __shared__ unsigned short Bls[128][40];
  int bm = blockIdx.y * 128, bn = blockIdx.x * 64;
  int tid = threadIdx.x;
  int wave = tid >> 6, lane = tid & 63;
  int lrow = lane & 15, lgrp = lane >> 4;
  f32x4 acc[2][8] = {};
  for (int k0 = 0; k0 < 512; k0 += 32) {
#pragma unroll
    for (int i = 0; i < 2; i++) {
      int vecIdx = tid + i * 256;
      int row = vecIdx >> 2, cg = vecIdx & 3;
      u16x8 v = {0, 0, 0, 0, 0, 0, 0, 0};
      if (bm + row < Tn)
        v = *reinterpret_cast<const u16x8*>(A + (size_t)(bm + row) * 512 + k0 + cg * 8);
      *reinterpret_cast<u16x8*>(&Als[row][cg * 8]) = v;
    }
#pragma unroll
    for (int i = 0; i < 2; i++) {
      int vecIdx = tid + i * 256;
      int row = vecIdx >> 2, cg = vecIdx & 3;
      int grow = (row < 64) ? (bn + row) : (2048 + bn + (row - 64));
      const float* bp = Bw + (size_t)grow * 512 + k0 + cg * 8;
      f32x4 b0 = *reinterpret_cast<const f32x4*>(bp);
      f32x4 b1 = *reinterpret_cast<const f32x4*>(bp + 4);
      u16x8 v;
#pragma unroll
      for (int e = 0; e < 4; e++) { v[e] = f2bu(b0[e]); v[e + 4] = f2bu(b1[e]); }
      *reinterpret_cast<u16x8*>(&Bls[row][cg * 8]) = v;
    }
    __syncthreads();
    bf16x8 af[2], bfr[8];
#pragma unroll
    for (int mi = 0; mi < 2; mi++)
      af[mi] = *reinterpret_cast<const bf16x8*>(&Als[wave * 32 + mi * 16 + lrow][lgrp * 8]);
#pragma unroll
    for (int ni = 0; ni < 8; ni++)
      bfr[ni] = *reinterpret_cast<const bf16x8*>(&Bls[ni * 16 + lrow][lgrp * 8]);
#pragma unroll
    for (int mi = 0; mi < 2; mi++)
#pragma unroll
      for (int ni = 0; ni < 8; ni++)
        acc[mi][ni] = __builtin_amdgcn_mfma_f32_16x16x32_bf16(af[mi], bfr[ni], acc[mi][ni], 0, 0, 0);
    __syncthreads();
  }
#pragma unroll
  for (int mi = 0; mi < 2; mi++)
#pragma unroll
    for (int ni = 0; ni < 4; ni++)
#pragma unroll
      for (int r = 0; r < 4; r++) {
        int row = bm + wave * 32 + mi * 16 + lgrp * 4 + r;
        int col = bn + ni * 16 + lrow;
        if (row < Tn) {
          float u = acc[mi][ni][r];
          float vv = acc[mi][ni + 4][r];
          float sv = vv / (1.f + expf(-vv));
          gatedb[(size_t)row * 2048 + col] = __float2bfloat16(u * sv);
        }
      }
}

// ---------------- Assemble q/k (partial RoPE, bf16 out) ----------------
__global__ __launch_bounds__(256) void k_qkv(const float* __restrict__ qf,
                                             const float* __restrict__ kvb,
                                             const float* __restrict__ ckv,
                                             const float* __restrict__ cosb,
                                             const float* __restrict__ sinb,
                                             __hip_bfloat16* __restrict__ qhb,
                                             __hip_bfloat16* __restrict__ khb) {
  int t = blockIdx.x;
  int l = t >> 3;
  for (int idx = threadIdx.x; idx < 768; idx += 256) {
    int hh = idx / 48, dc = idx % 48;
    int hd = hh >> 1, e = hh & 1;
    float qv, kvv;
    if (dc < 32) {
      qv  = qf [(size_t)t * 768  + hd * 96  + e * 32 + dc];
      kvv = kvb[(size_t)t * 1024 + hd * 128 + e * 32 + dc];
    } else {
      int rj = dc - 32;            // 0..15
      int p = rj >> 1; int isim = rj & 1;
      float xr_q = qf[(size_t)t * 768 + hd * 96 + 64 + e * 16 + p * 2];
      float xi_q = qf[(size_t)t * 768 + hd * 96 + 64 + e * 16 + p * 2 + 1];
      float xr_k = ckv[(size_t)t * 160 + 128 + e * 16 + p * 2];
      float xi_k = ckv[(size_t)t * 160 + 128 + e * 16 + p * 2 + 1];
      if (l == 0) {
        qv  = isim ? xi_q : xr_q;
        kvv = isim ? xi_k : xr_k;
      } else {
        float c = cosb[(l - 1) * 8 + p], s = sinb[(l - 1) * 8 + p];
        if (!isim) { qv = xr_q * c - xi_q * s; kvv = xr_k * c - xi_k * s; }
        else       { qv = xr_q * s + xi_q * c; kvv = xr_k * s + xi_k * c; }
      }
    }
    qhb[(size_t)t * 768 + idx] = __float2bfloat16(qv);
    khb[(size_t)t * 768 + idx] = __float2bfloat16(kvv);
  }
}

// ---------------- V transpose: vtb[c][t] bf16 ----------------
__global__ __launch_bounds__(256) void k_vtrans(const float* __restrict__ kvb,
                                                __hip_bfloat16* __restrict__ vtb) {
  __shared__ float tile[64][65];
  int tt = blockIdx.x, ct = blockIdx.y;    // (33, 8)
  int tid = threadIdx.x;
#pragma unroll
  for (int rep = 0; rep < 16; rep++) {
    int idx = rep * 256 + tid;
    int tr = idx >> 6, cc = idx & 63;
    int t = tt * 64 + tr;
    tile[tr][cc] = (t < Tn) ? kvb[(size_t)t * 1024 + ct * 128 + 64 + cc] : 0.f;
  }
  __syncthreads();
#pragma unroll
  for (int rep = 0; rep < 16; rep++) {
    int idx = rep * 256 + tid;
    int cr = idx >> 6, tc = idx & 63;
    int t = tt * 64 + tc;
    if (t < Tn)
      vtb[(size_t)(ct * 64 + cr) * Tn + t] = __float2bfloat16(tile[tc][cr]);
  }
}

// ---------------- lambda scalar ----------------
__global__ void k_lam(const float* __restrict__ lq1, const float* __restrict__ lk1,
                      const float* __restrict__ lq2, const float* __restrict__ lk2,
                      float lamc, float* __restrict__ out) {
  float d1 = 0.f, d2 = 0.f;
  for (int k = 0; k < 32; k++) { d1 = fmaf(lq1[k], lk1[k], d1); d2 = fmaf(lq2[k], lk2[k], d2); }
  out[0] = expf(d1) - expf(d2) + lamc;
}

// ---------------- attention pass 1: per-head online row max/sum ----------------
// grid (33, 16); block 256. Writes mrow[hh][i], linv[hh][i].
__global__ __launch_bounds__(256) void k_attn_pass1(const __hip_bfloat16* __restrict__ qhb,
                                                    const __hip_bfloat16* __restrict__ khb,
                                                    float* __restrict__ mrow,
                                                    float* __restrict__ linv) {
  __shared__ unsigned short Qs[64][72];
  __shared__ unsigned short Ks[64][72];
  int bm = blockIdx.x * 64, hh = blockIdx.y;
  int tid = threadIdx.x;
  int wave = tid >> 6, lane = tid & 63;
  int lrow = lane & 15, lgrp = lane >> 4;
  // stage Q once
#pragma unroll
  for (int i = 0; i < 2; i++) {
    int vecIdx = tid + i * 256;
    int row = vecIdx >> 3, cg = vecIdx & 7;
    u16x8 v = {0, 0, 0, 0, 0, 0, 0, 0};
    int grow = bm + row;
    if (grow < Tn && cg < 6)
      v = *reinterpret_cast<const u16x8*>(qhb + (size_t)grow * 768 + hh * 48 + cg * 8);
    *reinterpret_cast<u16x8*>(&Qs[row][cg * 8]) = v;
  }
  float m_run[4], l_run[4];
#pragma unroll
  for (int r = 0; r < 4; r++) { m_run[r] = -3.4e38f; l_run[r] = 0.f; }
  int irow[4];
#pragma unroll
  for (int r = 0; r < 4; r++) irow[r] = bm + wave * 16 + lgrp * 4 + r;

  for (int jt = 0; jt < 33; jt++) {
    __syncthreads();
#pragma unroll
    for (int i = 0; i < 2; i++) {
      int vecIdx = tid + i * 256;
      int row = vecIdx >> 3, cg = vecIdx & 7;
      u16x8 v = {0, 0, 0, 0, 0, 0, 0, 0};
      int gj = jt * 64 + row;
      if (gj < Tn && cg < 6)
        v = *reinterpret_cast<const u16x8*>(khb + (size_t)gj * 768 + hh * 48 + cg * 8);
      *reinterpret_cast<u16x8*>(&Ks[row][cg * 8]) = v;
    }
    __syncthreads();
    f32x4 acc[4] = {};
#pragma unroll
    for (int ks = 0; ks < 2; ks++) {
      bf16x8 af = *reinterpret_cast<const bf16x8*>(&Qs[wave * 16 + lrow][ks * 32 + lgrp * 8]);
#pragma unroll
      for (int ni = 0; ni < 4; ni++) {
        bf16x8 bfr = *reinterpret_cast<const bf16x8*>(&Ks[ni * 16 + lrow][ks * 32 + lgrp * 8]);
        acc[ni] = __builtin_amdgcn_mfma_f32_16x16x32_bf16(af, bfr, acc[ni], 0, 0, 0);
      }
    }
    // per-row online update
#pragma unroll
    for (int r = 0; r < 4; r++) {
      int imod = irow[r] % LPn;
      float sv[4];
      float tmax = -3.4e38f;
#pragma unroll
      for (int ni = 0; ni < 4; ni++) {
        int j = jt * 64 + ni * 16 + lrow;
        sv[ni] = (j >= Tn || (j % LPn) > imod) ? -1e9f : acc[ni][r] * SCALING_C;
        tmax = fmaxf(tmax, sv[ni]);
      }
      for (int mk = 1; mk < 16; mk <<= 1) tmax = fmaxf(tmax, __shfl_xor(tmax, mk));
      float m_new = fmaxf(m_run[r], tmax);
      float ps = 0.f;
#pragma unroll
      for (int ni = 0; ni < 4; ni++) ps += expf(sv[ni] - m_new);
      for (int mk = 1; mk < 16; mk <<= 1) ps += __shfl_xor(ps, mk);
      l_run[r] = l_run[r] * expf(m_run[r] - m_new) + ps;
      m_run[r] = m_new;
    }
  }
  if (lrow == 0) {
#pragma unroll
    for (int r = 0; r < 4; r++) {
      if (irow[r] < Tn) {
        mrow[(size_t)hh * TP + irow[r]] = m_run[r];
        linv[(size_t)hh * TP + irow[r]] = 1.f / l_run[r];
      }
    }
  }
}

// ---------------- attention pass 2: P=a1-lam*a2, PV in registers, colsum ----------------
// grid (33, 8); block 256. Writes opv[p][i][dv], colsum_p[p][rb4][j].
__global__ __launch_bounds__(256) void k_attn_pass2(const __hip_bfloat16* __restrict__ qhb,
                                                    const __hip_bfloat16* __restrict__ khb,
                                                    const __hip_bfloat16* __restrict__ vtb,
                                                    const float* __restrict__ mrow,
                                                    const float* __restrict__ linv,
                                                    const float* __restrict__ lamp,
                                                    float* __restrict__ opv,
                                                    float* __restrict__ colsum_p) {
  __shared__ unsigned short Q1[64][72];
  __shared__ unsigned short Q2[64][72];
  __shared__ unsigned short K1s[64][72];
  __shared__ unsigned short K2s[64][72];
  __shared__ unsigned short Ps[64][72];
  __shared__ unsigned short Bv[64][72];
  int bm = blockIdx.x * 64, p = blockIdx.y;
  int hh1 = 2 * p, hh2 = 2 * p + 1;
  float lam = lamp[0];
  int tid = threadIdx.x;
  int wave = tid >> 6, lane = tid & 63;
  int lrow = lane & 15, lgrp = lane >> 4;
  const unsigned short* vt = (const unsigned short*)vtb + (size_t)p * 64 * Tn;
  // stage Q for both heads
#pragma unroll
  for (int i = 0; i < 2; i++) {
    int vecIdx = tid + i * 256;
    int row = vecIdx >> 3, cg = vecIdx & 7;
    u16x8 v1 = {0, 0, 0, 0, 0, 0, 0, 0}, v2 = v1;
    int grow = bm + row;
    if (grow < Tn && cg < 6) {
      v1 = *reinterpret_cast<const u16x8*>(qhb + (size_t)grow * 768 + hh1 * 48 + cg * 8);
      v2 = *reinterpret_cast<const u16x8*>(qhb + (size_t)grow * 768 + hh2 * 48 + cg * 8);
    }
    *reinterpret_cast<u16x8*>(&Q1[row][cg * 8]) = v1;
    *reinterpret_cast<u16x8*>(&Q2[row][cg * 8]) = v2;
  }
  // per-lane row stats
  int irow[4]; float m1[4], li1[4], m2[4], li2[4];
#pragma unroll
  for (int r = 0; r < 4; r++) {
    irow[r] = bm + wave * 16 + lgrp * 4 + r;
    if (irow[r] < Tn) {
      m1[r] = mrow[(size_t)hh1 * TP + irow[r]]; li1[r] = linv[(size_t)hh1 * TP + irow[r]];
      m2[r] = mrow[(size_t)hh2 * TP + irow[r]]; li2[r] = linv[(size_t)hh2 * TP + irow[r]];
    } else { m1[r] = 0.f; li1[r] = 0.f; m2[r] = 0.f; li2[r] = 0.f; }
  }
  f32x4 accpv[4] = {};
  for (int jt = 0; jt < 33; jt++) {
    __syncthreads();
    // stage K1, K2, Bv
#pragma unroll
    for (int i = 0; i < 2; i++) {
      int vecIdx = tid + i * 256;
      int row = vecIdx >> 3, cg = vecIdx & 7;
      u16x8 v1 = {0, 0, 0, 0, 0, 0, 0, 0}, v2 = v1, vv = v1;
      int gj = jt * 64 + row;
      if (gj < Tn && cg < 6) {
        v1 = *reinterpret_cast<const u16x8*>(khb + (size_t)gj * 768 + hh1 * 48 + cg * 8);
        v2 = *reinterpret_cast<const u16x8*>(khb + (size_t)gj * 768 + hh2 * 48 + cg * 8);
      }
      int jc = jt * 64 + cg * 8;
      if (jc + 8 <= Tn)
        vv = *reinterpret_cast<const u16x8*>(vt + (size_t)row * Tn + jc);
      *reinterpret_cast<u16x8*>(&K1s[row][cg * 8]) = v1;
      *reinterpret_cast<u16x8*>(&K2s[row][cg * 8]) = v2;
      *reinterpret_cast<u16x8*>(&Bv[row][cg * 8]) = vv;
    }
    __syncthreads();
    // scores both heads
    f32x4 a1c[4] = {}, a2c[4] = {};
#pragma unroll
    for (int ks = 0; ks < 2; ks++) {
      bf16x8 af1 = *reinterpret_cast<const bf16x8*>(&Q1[wave * 16 + lrow][ks * 32 + lgrp * 8]);
      bf16x8 af2 = *reinterpret_cast<const bf16x8*>(&Q2[wave * 16 + lrow][ks * 32 + lgrp * 8]);
#pragma unroll
      for (int ni = 0; ni < 4; ni++) {
        bf16x8 b1 = *reinterpret_cast<const bf16x8*>(&K1s[ni * 16 + lrow][ks * 32 + lgrp * 8]);
        bf16x8 b2 = *reinterpret_cast<const bf16x8*>(&K2s[ni * 16 + lrow][ks * 32 + lgrp * 8]);
        a1c[ni] = __builtin_amdgcn_mfma_f32_16x16x32_bf16(af1, b1, a1c[ni], 0, 0, 0);
        a2c[ni] = __builtin_amdgcn_mfma_f32_16x16x32_bf16(af2, b2, a2c[ni], 0, 0, 0);
      }
    }
    // combine -> P tile + colsum
    float cs[4];
#pragma unroll
    for (int ni = 0; ni < 4; ni++) cs[ni] = 0.f;
#pragma unroll
    for (int ni = 0; ni < 4; ni++) {
      int j = jt * 64 + ni * 16 + lrow;
      int jmod = j % LPn;
      bool jok = (j < Tn);
#pragma unroll
      for (int r = 0; r < 4; r++) {
        int imod = irow[r] % LPn;
        bool masked = (!jok) || (jmod > imod);
        float sv1 = masked ? -1e9f : a1c[ni][r] * SCALING_C;
        float sv2 = masked ? -1e9f : a2c[ni][r] * SCALING_C;
        float a1 = expf(sv1 - m1[r]) * li1[r];
        float a2 = expf(sv2 - m2[r]) * li2[r];
        float c = fmaf(-lam, a2, a1);
        Ps[wave * 16 + lgrp * 4 + r][ni * 16 + lrow] = f2bu(c);
        cs[ni] += a1;
      }
    }
    // colsum reduce across wave rows (lgrp): xor 16, 32
#pragma unroll
    for (int ni = 0; ni < 4; ni++) {
      cs[ni] += __shfl_xor(cs[ni], 16);
      cs[ni] += __shfl_xor(cs[ni], 32);
    }
    {
      float mine = (lgrp == 0) ? cs[0] : (lgrp == 1) ? cs[1] : (lgrp == 2) ? cs[2] : cs[3];
      colsum_p[((size_t)p * 132 + blockIdx.x * 4 + wave) * TP + jt * 64 + lgrp * 16 + lrow] = mine;
    }
    __syncthreads();
    // PV MFMA
#pragma unroll
    for (int ks = 0; ks < 2; ks++) {
      bf16x8 af = *reinterpret_cast<const bf16x8*>(&Ps[wave * 16 + lrow][ks * 32 + lgrp * 8]);
#pragma unroll
      for (int ni = 0; ni < 4; ni++) {
        bf16x8 bfr = *reinterpret_cast<const bf16x8*>(&Bv[ni * 16 + lrow][ks * 32 + lgrp * 8]);
        accpv[ni] = __builtin_amdgcn_mfma_f32_16x16x32_bf16(af, bfr, accpv[ni], 0, 0, 0);
      }
    }
  }
#pragma unroll
  for (int ni = 0; ni < 4; ni++)
#pragma unroll
    for (int r = 0; r < 4; r++) {
      int row = bm + wave * 16 + lgrp * 4 + r;
      int col = ni * 16 + lrow;
      if (row < Tn) opv[((size_t)p * Tn + row) * 64 + col] = accpv[ni][r];
    }
}

// ---------------- batched gwv: W[p][jmod][dv] ----------------
__global__ __launch_bounds__(64) void k_gwv(const float* __restrict__ colsum_p,
                                            const __hip_bfloat16* __restrict__ vtb,
                                            const float* __restrict__ lamp,
                                            float* __restrict__ Wb) {
  int jmod = blockIdx.x, p = blockIdx.y;
  int l = threadIdx.x;
  int k = l >> 3, sub = l & 7;
  int jk = jmod + 257 * k;
  float s = 0.f;
  for (int ib = sub; ib < 132; ib += 8) s += colsum_p[((size_t)p * 132 + ib) * TP + jk];
  for (int m = 1; m < 8; m <<= 1) s += __shfl_xor(s, m);
  float gv = s * (1.f / (float)Tn) * lamp[0];
  const __hip_bfloat16* vrow = vtb + (size_t)(p * 64 + l) * Tn;
  float acc = 0.f;
#pragma unroll
  for (int kk = 0; kk < 8; kk++) {
    float gk = __shfl(gv, kk * 8);
    acc = fmaf(gk, __bfloat162float(vrow[jmod + 257 * kk]), acc);
  }
  Wb[((size_t)p * 257 + jmod) * 64 + l] = acc;
}

// ---------------- batched chunksum ----------------
__global__ __launch_bounds__(64) void k_chunksum(const float* __restrict__ Wb,
                                                 float* __restrict__ Cb) {
  int c = blockIdx.x, p = blockIdx.y;
  int lane = threadIdx.x;
  int m0 = c * 16, m1 = min(m0 + 16, LPn);
  float acc = 0.f;
  for (int m = m0; m < m1; m++) acc += Wb[((size_t)p * 257 + m) * 64 + lane];
  Cb[((size_t)p * 17 + c) * 64 + lane] = acc;
}

// ---------------- pv_out: opv + G-prefix + head-RMSNorm -> bf16 ----------------
__global__ __launch_bounds__(256) void k_pv_out(const float* __restrict__ opv,
                                                const float* __restrict__ Wb,
                                                const float* __restrict__ Cb,
                                                const float* __restrict__ hnw,
                                                __hip_bfloat16* __restrict__ onormb) {
  int w = threadIdx.x >> 6, lane = threadIdx.x & 63;
  int i = blockIdx.x * 4 + w;
  int p = blockIdx.y;
  int imod = i % LPn;
  int cidx = imod >> 4;
  float s = opv[((size_t)p * Tn + i) * 64 + lane];
  for (int c = 0; c < cidx; c++) s += Cb[((size_t)p * 17 + c) * 64 + lane];
  for (int m = cidx * 16; m <= imod; m++) s += Wb[((size_t)p * 257 + m) * 64 + lane];
  float ss = s * s;
  for (int off = 1; off < 64; off <<= 1) ss += __shfl_xor(ss, off);
  float scale = rsqrtf(ss * (1.f / 64.f) + 1e-5f);
  onormb[((size_t)p * Tn + i) * 64 + lane] = __float2bfloat16(s * scale * hnw[lane]);
}

// ---------------- final head (float32 out) ----------------
__global__ __launch_bounds__(192) void k_final(const float* __restrict__ z,
                                               const float* __restrict__ outW,
                                               float* __restrict__ out) {
  int t = blockIdx.x;
  int p = threadIdx.x >> 6, lane = threadIdx.x & 63;
  float acc = 0.f;
  for (int m = lane; m < 512; m += 64) acc = fmaf(z[(size_t)t * 512 + m], outW[(size_t)p * 512 + m], acc);
  for (int off = 1; off < 64; off <<= 1) acc += __shfl_xor(acc, off);
  if (lane == 0) out[(size_t)t * 3 + p] = acc;
}

extern "C" void kernel_launch(void* const* d_in, const int* in_sizes, int n_in,
                              void* d_out, int out_size, void* d_ws, size_t ws_size,
                              hipStream_t stream) {
  const float* x          = (const float*)d_in[0];
  const float* ticker_emb = (const float*)d_in[1];
  const float* sep_emb    = (const float*)d_in[2];
  const float* shared_W   = (const float*)d_in[3];
  const float* unique_W   = (const float*)d_in[4];
  const float* norm1_w    = (const float*)d_in[5];
  const float* norm2_w    = (const float*)d_in[6];
  const float* kv_down_W  = (const float*)d_in[7];
  const float* q_down_W   = (const float*)d_in[8];
  const float* kv_up_W    = (const float*)d_in[9];
  const float* q_up_W     = (const float*)d_in[10];
  const float* kv_norm_w  = (const float*)d_in[11];
  const float* q_norm_w   = (const float*)d_in[12];
  const float* o_W        = (const float*)d_in[13];
  const float* lam_q1     = (const float*)d_in[14];
  const float* lam_k1     = (const float*)d_in[15];
  const float* lam_q2     = (const float*)d_in[16];
  const float* lam_k2     = (const float*)d_in[17];
  const float* head_norm_w= (const float*)d_in[18];
  const float* ff_in_W    = (const float*)d_in[19];
  const float* ff_out_W   = (const float*)d_in[20];
  const float* final_norm = (const float*)d_in[21];
  const float* out_W      = (const float*)d_in[22];
  const int*   seperator  = (const int*)d_in[23];
  const int*   tickers    = (const int*)d_in[24];
  (void)in_sizes; (void)n_in;

  float* W = (float*)d_ws;
  size_t off = 0;
  auto alloc = [&](size_t n) { float* p = W + off; off += n; return p; };
  float* cosb  = alloc(2048);
  float* sinb  = alloc(2048);
  float* h     = alloc((size_t)Tn * Dn);
  float* xnb_f = alloc((size_t)Tn * 256);         // bf16 T x 512 (also z)
  float* ckv   = alloc((size_t)Tn * 160);         // ckv+qlat host onormb later
  float* qlat  = alloc((size_t)Tn * 192);
  float* ckvnb_f = alloc((size_t)Tn * 64);        // bf16 T x 128
  float* qlatnb_f = alloc((size_t)Tn * 96);       // bf16 T x 192
  float* kvb   = alloc((size_t)Tn * 1024);        // opv / gatedb overlays
  float* qf    = alloc((size_t)Tn * 768);         // zfin overlay
  float* qhb_f = alloc((size_t)Tn * 384);         // bf16 T x 768
  float* khb_f = alloc((size_t)Tn * 384);         // bf16 T x 768
  float* vtb_f = alloc((size_t)Tn * 256);         // bf16 512 x T
  float* mrow  = alloc((size_t)16 * TP);
  float* linvb = alloc((size_t)16 * TP);
  float* lam   = alloc(4);
  float* colsum_p = alloc((size_t)8 * 132 * TP);  // 2.23M floats
  float* Wb    = alloc((size_t)8 * 257 * 64);
  float* Cb    = alloc((size_t)8 * 17 * 64);

  __hip_bfloat16* xnb    = (__hip_bfloat16*)xnb_f;
  __hip_bfloat16* ckvnb  = (__hip_bfloat16*)ckvnb_f;
  __hip_bfloat16* qlatnb = (__hip_bfloat16*)qlatnb_f;
  __hip_bfloat16* onormb = (__hip_bfloat16*)ckv;     // bf16 T x 512 over ckv+qlat
  __hip_bfloat16* gatedb = (__hip_bfloat16*)kvb;     // bf16 T x 2048
  __hip_bfloat16* qhb    = (__hip_bfloat16*)qhb_f;
  __hip_bfloat16* khb    = (__hip_bfloat16*)khb_f;
  __hip_bfloat16* vtb    = (__hip_bfloat16*)vtb_f;
  float* opv   = kvb;        // 8*T*64 f32 = T*512 f32 (kvb dead post-vtrans)
  float* zfin  = qf;

  size_t needed = off * sizeof(float);            // ~43.6 MB (< 79.5 proven)
  if (ws_size < needed) {
    k_fill42<<<(out_size + 255) / 256, 256, 0, stream>>>((float*)d_out, out_size);
    return;
  }

  k_freqs<<<8, 256, 0, stream>>>(cosb, sinb);
  k_embed<<<dim3(Tn, 2), 256, 0, stream>>>(x, ticker_emb, sep_emb, shared_W, unique_W,
                                           seperator, tickers, h);

  for (int d = 0; d < 2; d++) {
    const float* n1   = norm1_w + d * 512;
    const float* n2   = norm2_w + d * 512;
    const float* kvd  = kv_down_W + (size_t)d * 160 * 512;
    const float* qd   = q_down_W + (size_t)d * 192 * 512;
    const float* kvu  = kv_up_W + (size_t)d * 1024 * 128;
    const float* qu   = q_up_W + (size_t)d * 768 * 192;
    const float* kvnw = kv_norm_w + d * 128;
    const float* qnw  = q_norm_w + d * 192;
    const float* oW   = o_W + (size_t)d * 512 * 512;
    const float* hnw  = head_norm_w + d * 64;
    const float* ffi  = ff_in_W + (size_t)d * 4096 * 512;
    const float* ffo  = ff_out_W + (size_t)d * 512 * 2048;
    float lamc = 0.8f - 0.6f * expf(-0.3f * (float)d);

    k_rmsnorm_b<<<Tn, 256, 0, stream>>>(h, n1, xnb, 512, 512, EPS_C);
    k_gemm64<0><<<dim3(3, 33), 256, 0, stream>>>(xnb, kvd, ckv, Tn, 160, 512);
    k_rmsnorm_b<<<Tn, 256, 0, stream>>>(ckv, kvnw, ckvnb, 128, 160, EPS_C);
    k_gemm64<0><<<dim3(16, 33), 256, 0, stream>>>(ckvnb, kvu, kvb, Tn, 1024, 128);
    k_gemm64<0><<<dim3(3, 33), 256, 0, stream>>>(xnb, qd, qlat, Tn, 192, 512);
    k_rmsnorm_b<<<Tn, 256, 0, stream>>>(qlat, qnw, qlatnb, 192, 192, EPS_C);
    k_gemm64<0><<<dim3(12, 33), 256, 0, stream>>>(qlatnb, qu, qf, Tn, 768, 192);
    k_qkv<<<Tn, 256, 0, stream>>>(qf, kvb, ckv, cosb, sinb, qhb, khb);
    k_vtrans<<<dim3(33, 8), 256, 0, stream>>>(kvb, vtb);
    k_lam<<<1, 1, 0, stream>>>(lam_q1 + d * 32, lam_k1 + d * 32,
                               lam_q2 + d * 32, lam_k2 + d * 32, lamc, lam);

    k_attn_pass1<<<dim3(33, 16), 256, 0, stream>>>(qhb, khb, mrow, linvb);
    k_attn_pass2<<<dim3(33, 8), 256, 0, stream>>>(qhb, khb, vtb, mrow, linvb, lam,
                                                  opv, colsum_p);
    k_gwv<<<dim3(257, 8), 64, 0, stream>>>(colsum_p, vtb, lam, Wb);
    k_chunksum<<<dim3(17, 8), 64, 0, stream>>>(Wb, Cb);
    k_pv_out<<<dim3(514, 8), 256, 0, stream>>>(opv, Wb, Cb, hnw, onormb);

    k_gemm64<1><<<dim3(8, 33), 256, 0, stream>>>(onormb, oW, h, Tn, 512, 512);   // h += o-proj
    k_rmsnorm_b<<<Tn, 256, 0, stream>>>(h, n2, xnb, 512, 512, EPS_C);
    k_ffn<<<dim3(32, 17), 256, 0, stream>>>(xnb, ffi, gatedb);
    k_gemm64<1><<<dim3(8, 33), 256, 0, stream>>>(gatedb, ffo, h, Tn, 512, 2048); // h += ffn
  }

  k_rmsnorm<<<Tn, 256, 0, stream>>>(h, final_norm, zfin, 512, 512, EPS_C);
  k_final<<<Tn, 192, 0, stream>>>(zfin, out_W, (float*)d_out);
}

// Round 13
// 681.575 us; speedup vs baseline: 14.2963x; 1.2734x over previous
//
#include <hip/hip_runtime.h>
#include <hip/hip_bf16.h>

// Money_former MLA DINT — round 13: occupancy via loop-splitting.
// pass1/pass2 jt-split x2 (grids 1056/528 blocks; pass2 merges per-half m/l);
// o-proj and ffo K-split (k_gemm64p partials + deterministic k_addred);
// __expf in attention. T=2056, D=512, 2 layers, 16 logical heads of 48.

#define Tn 2056
#define LPn 257
#define Dn 512
#define TP 2112   // padded T (33*64)

static constexpr float SCALING_C = 0.14433756729740643f;   // 48^-0.5
static constexpr float EPS_C     = 1.1920928955078125e-07f;

typedef float f32x4 __attribute__((ext_vector_type(4)));
typedef short bf16x8 __attribute__((ext_vector_type(8)));
typedef unsigned short u16x8 __attribute__((ext_vector_type(8)));

__device__ __forceinline__ unsigned short f2bu(float f) {
  __hip_bfloat16 h = __float2bfloat16(f);
  return *reinterpret_cast<unsigned short*>(&h);
}

// ---------------- sentinel ----------------
__global__ __launch_bounds__(256) void k_fill42(float* __restrict__ out, int n) {
  int i = blockIdx.x * 256 + threadIdx.x;
  if (i < n) out[i] = 42.0f;
}

// ---------------- RoPE tables ----------------
__global__ __launch_bounds__(256) void k_freqs(float* __restrict__ cosb, float* __restrict__ sinb) {
  int idx = blockIdx.x * 256 + threadIdx.x;
  if (idx >= 256 * 8) return;
  int pos = idx >> 3, j = idx & 7;
  float fb = powf(10000.f, -(float)j * 0.125f);            // 1/10000^(j/8)
  float ramp = fminf(fmaxf((float)j * 0.25f, 0.f), 1.f);   // low=0, high=4
  float sm = 1.f - ramp;
  float fr = fb * (1.f / 40.f) * (1.f - sm) + fb * sm;
  float ang = (float)pos * fr;
  cosb[idx] = cosf(ang);
  sinb[idx] = sinf(ang);
}

// ---------------- Embedding ----------------
__global__ __launch_bounds__(256) void k_embed(const float* __restrict__ x,
                                               const float* __restrict__ ticker_emb,
                                               const float* __restrict__ sep_emb,
                                               const float* __restrict__ shared_W,
                                               const float* __restrict__ unique_W,
                                               const int* __restrict__ sep_idx,
                                               const int* __restrict__ tickers,
                                               float* __restrict__ h) {
  int t = blockIdx.x;
  int c = blockIdx.y * 256 + threadIdx.x;
  int l = t >> 3, s = t & 7;
  float val;
  if (l == 0) {
    val = sep_emb[sep_idx[0] * Dn + c];
  } else {
    const float* xr = x + ((size_t)(l - 1) * 8 + s) * 32;
    const float* w = (c < 384) ? (shared_W + (size_t)c * 32)
                               : (unique_W + ((size_t)s * 128 + (c - 384)) * 32);
    float acc = 0.f;
#pragma unroll
    for (int f = 0; f < 32; f++) acc = fmaf(xr[f], w[f], acc);
    val = acc;
  }
  val += ticker_emb[(size_t)tickers[s] * Dn + c];
  h[(size_t)t * Dn + c] = val;
}

// ---------------- Row RMSNorm, f32 out ----------------
__global__ __launch_bounds__(256) void k_rmsnorm(const float* __restrict__ in,
                                                 const float* __restrict__ w,
                                                 float* __restrict__ out,
                                                 int ncols, int in_stride, float eps) {
  int row = blockIdx.x;
  const float* xr = in + (size_t)row * in_stride;
  float ss = 0.f;
  for (int c = threadIdx.x; c < ncols; c += 256) { float v = xr[c]; ss = fmaf(v, v, ss); }
  for (int off = 1; off < 64; off <<= 1) ss += __shfl_xor(ss, off);
  __shared__ float red[4];
  if ((threadIdx.x & 63) == 0) red[threadIdx.x >> 6] = ss;
  __syncthreads();
  float tot = red[0] + red[1] + red[2] + red[3];
  float scale = rsqrtf(tot / (float)ncols + eps);
  for (int c = threadIdx.x; c < ncols; c += 256)
    out[(size_t)row * ncols + c] = xr[c] * scale * w[c];
}

// ---------------- Row RMSNorm, bf16 out ----------------
__global__ __launch_bounds__(256) void k_rmsnorm_b(const float* __restrict__ in,
                                                   const float* __restrict__ w,
                                                   __hip_bfloat16* __restrict__ out,
                                                   int ncols, int in_stride, float eps) {
  int row = blockIdx.x;
  const float* xr = in + (size_t)row * in_stride;
  float ss = 0.f;
  for (int c = threadIdx.x; c < ncols; c += 256) { float v = xr[c]; ss = fmaf(v, v, ss); }
  for (int off = 1; off < 64; off <<= 1) ss += __shfl_xor(ss, off);
  __shared__ float red[4];
  if ((threadIdx.x & 63) == 0) red[threadIdx.x >> 6] = ss;
  __syncthreads();
  float tot = red[0] + red[1] + red[2] + red[3];
  float scale = rsqrtf(tot / (float)ncols + eps);
  for (int c = threadIdx.x; c < ncols; c += 256)
    out[(size_t)row * ncols + c] = __float2bfloat16(xr[c] * scale * w[c]);
}

// ---------------- 64x64 MFMA GEMM: C (+)= A[M,K]bf16 @ (B[N,K]f32)^T ----------------
template <int MODE>
__global__ __launch_bounds__(256) void k_gemm64(const __hip_bfloat16* __restrict__ A,
                                                const float* __restrict__ B,
                                                float* __restrict__ C,
                                                int M, int N, int K) {
  __shared__ unsigned short Als[64][40];
  __shared__ unsigned short Bls[64][40];
  int bm = blockIdx.y * 64, bn = blockIdx.x * 64;
  int tid = threadIdx.x;
  int wave = tid >> 6, lane = tid & 63;
  int lrow = lane & 15, lgrp = lane >> 4;
  f32x4 acc[4] = {};
  for (int k0 = 0; k0 < K; k0 += 32) {
    {
      int row = tid >> 2, cg = tid & 3;
      u16x8 v = {0, 0, 0, 0, 0, 0, 0, 0};
      if (bm + row < M)
        v = *reinterpret_cast<const u16x8*>(A + (size_t)(bm + row) * K + k0 + cg * 8);
      *reinterpret_cast<u16x8*>(&Als[row][cg * 8]) = v;
    }
    {
      int row = tid >> 2, cg = tid & 3;
      u16x8 v = {0, 0, 0, 0, 0, 0, 0, 0};
      if (bn + row < N) {
        const float* bp = B + (size_t)(bn + row) * K + k0 + cg * 8;
        f32x4 b0 = *reinterpret_cast<const f32x4*>(bp);
        f32x4 b1 = *reinterpret_cast<const f32x4*>(bp + 4);
#pragma unroll
        for (int e = 0; e < 4; e++) { v[e] = f2bu(b0[e]); v[e + 4] = f2bu(b1[e]); }
      }
      *reinterpret_cast<u16x8*>(&Bls[row][cg * 8]) = v;
    }
    __syncthreads();
    bf16x8 af = *reinterpret_cast<const bf16x8*>(&Als[wave * 16 + lrow][lgrp * 8]);
    bf16x8 bfr[4];
#pragma unroll
    for (int ni = 0; ni < 4; ni++)
      bfr[ni] = *reinterpret_cast<const bf16x8*>(&Bls[ni * 16 + lrow][lgrp * 8]);
#pragma unroll
    for (int ni = 0; ni < 4; ni++)
      acc[ni] = __builtin_amdgcn_mfma_f32_16x16x32_bf16(af, bfr[ni], acc[ni], 0, 0, 0);
    __syncthreads();
  }
#pragma unroll
  for (int ni = 0; ni < 4; ni++)
#pragma unroll
    for (int r = 0; r < 4; r++) {
      int row = bm + wave * 16 + lgrp * 4 + r;
      int col = bn + ni * 16 + lrow;
      if (row < M && col < N) {
        if (MODE) C[(size_t)row * N + col] += acc[ni][r];
        else      C[(size_t)row * N + col] = acc[ni][r];
      }
    }
}

// ---------------- K-split 64x64 MFMA GEMM -> partial buffer pp[kc] ----------------
__global__ __launch_bounds__(256) void k_gemm64p(const __hip_bfloat16* __restrict__ A,
                                                 const float* __restrict__ B,
                                                 float* __restrict__ pp,
                                                 int M, int N, int kchunk) {
  __shared__ unsigned short Als[64][40];
  __shared__ unsigned short Bls[64][40];
  int bm = blockIdx.y * 64, bn = blockIdx.x * 64;
  int kc = blockIdx.z;
  int K = kchunk * gridDim.z;
  int kbase = kc * kchunk;
  int tid = threadIdx.x;
  int wave = tid >> 6, lane = tid & 63;
  int lrow = lane & 15, lgrp = lane >> 4;
  f32x4 acc[4] = {};
  for (int k0 = kbase; k0 < kbase + kchunk; k0 += 32) {
    {
      int row = tid >> 2, cg = tid & 3;
      u16x8 v = {0, 0, 0, 0, 0, 0, 0, 0};
      if (bm + row < M)
        v = *reinterpret_cast<const u16x8*>(A + (size_t)(bm + row) * K + k0 + cg * 8);
      *reinterpret_cast<u16x8*>(&Als[row][cg * 8]) = v;
    }
    {
      int row = tid >> 2, cg = tid & 3;
      u16x8 v = {0, 0, 0, 0, 0, 0, 0, 0};
      if (bn + row < N) {
        const float* bp = B + (size_t)(bn + row) * K + k0 + cg * 8;
        f32x4 b0 = *reinterpret_cast<const f32x4*>(bp);
        f32x4 b1 = *reinterpret_cast<const f32x4*>(bp + 4);
#pragma unroll
        for (int e = 0; e < 4; e++) { v[e] = f2bu(b0[e]); v[e + 4] = f2bu(b1[e]); }
      }
      *reinterpret_cast<u16x8*>(&Bls[row][cg * 8]) = v;
    }
    __syncthreads();
    bf16x8 af = *reinterpret_cast<const bf16x8*>(&Als[wave * 16 + lrow][lgrp * 8]);
    bf16x8 bfr[4];
#pragma unroll
    for (int ni = 0; ni < 4; ni++)
      bfr[ni] = *reinterpret_cast<const bf16x8*>(&Bls[ni * 16 + lrow][lgrp * 8]);
#pragma unroll
    for (int ni = 0; ni < 4; ni++)
      acc[ni] = __builtin_amdgcn_mfma_f32_16x16x32_bf16(af, bfr[ni], acc[ni], 0, 0, 0);
    __syncthreads();
  }
#pragma unroll
  for (int ni = 0; ni < 4; ni++)
#pragma unroll
    for (int r = 0; r < 4; r++) {
      int row = bm + wave * 16 + lgrp * 4 + r;
      int col = bn + ni * 16 + lrow;
      if (row < M && col < N)
        pp[(size_t)kc * M * N + (size_t)row * N + col] = acc[ni][r];
    }
}

// ---------------- C += sum of nsplit partials (fixed order, deterministic) ----------------
__global__ __launch_bounds__(256) void k_addred(float* __restrict__ C,
                                                const float* __restrict__ pp,
                                                long n, int nsplit) {
  long i = (long)blockIdx.x * 256 + threadIdx.x;
  if (i >= n) return;
  float s = 0.f;
  for (int k = 0; k < nsplit; k++) s += pp[(size_t)k * n + i];
  C[i] += s;
}

// ---------------- Fused FFN-in + SwiGLU ----------------
__global__ __launch_bounds__(256) void k_ffn(const __hip_bfloat16* __restrict__ A,
                                             const float* __restrict__ Bw,
                                             __hip_bfloat16* __restrict__ gatedb) {
  __shared__ unsigned short Als[128][40];
  __shared__ unsigned short Bls[128][40];
  int bm = blockIdx.y * 128, bn = blockIdx.x * 64;
  int tid = threadIdx.x;
  int wave = tid >> 6, lane = tid & 63;
  int lrow = lane & 15, lgrp = lane >> 4;
  f32x4 acc[2][8] = {};
  for (int k0 = 0; k0 < 512; k0 += 32) {
#pragma unroll
    for (int i = 0; i < 2; i++) {
      int vecIdx = tid + i * 256;
      int row = vecIdx >> 2, cg = vecIdx & 3;
      u16x8 v = {0, 0, 0, 0, 0, 0, 0, 0};
      if (bm + row < Tn)
        v = *reinterpret_cast<const u16x8*>(A + (size_t)(bm + row) * 512 + k0 + cg * 8);
      *reinterpret_cast<u16x8*>(&Als[row][cg * 8]) = v;
    }
#pragma unroll
    for (int i = 0; i < 2; i++) {
      int vecIdx = tid + i * 256;
      int row = vecIdx >> 2, cg = vecIdx & 3;
      int grow = (row < 64) ? (bn + row) : (2048 + bn + (row - 64));
      const float* bp = Bw + (size_t)grow * 512 + k0 + cg * 8;
      f32x4 b0 = *reinterpret_cast<const f32x4*>(bp);
      f32x4 b1 = *reinterpret_cast<const f32x4*>(bp + 4);
      u16x8 v;
#pragma unroll
      for (int e = 0; e < 4; e++) { v[e] = f2bu(b0[e]); v[e + 4] = f2bu(b1[e]); }
      *reinterpret_cast<u16x8*>(&Bls[row][cg * 8]) = v;
    }
    __syncthreads();
    bf16x8 af[2], bfr[8];
#pragma unroll
    for (int mi = 0; mi < 2; mi++)
      af[mi] = *reinterpret_cast<const bf16x8*>(&Als[wave * 32 + mi * 16 + lrow][lgrp * 8]);
#pragma unroll
    for (int ni = 0; ni < 8; ni++)
      bfr[ni] = *reinterpret_cast<const bf16x8*>(&Bls[ni * 16 + lrow][lgrp * 8]);
#pragma unroll
    for (int mi = 0; mi < 2; mi++)
#pragma unroll
      for (int ni = 0; ni < 8; ni++)
        acc[mi][ni] = __builtin_amdgcn_mfma_f32_16x16x32_bf16(af[mi], bfr[ni], acc[mi][ni], 0, 0, 0);
    __syncthreads();
  }
#pragma unroll
  for (int mi = 0; mi < 2; mi++)
#pragma unroll
    for (int ni = 0; ni < 4; ni++)
#pragma unroll
      for (int r = 0; r < 4; r++) {
        int row = bm + wave * 32 + mi * 16 + lgrp * 4 + r;
        int col = bn + ni * 16 + lrow;
        if (row < Tn) {
          float u = acc[mi][ni][r];
          float vv = acc[mi][ni + 4][r];
          float sv = vv / (1.f + __expf(-vv));
          gatedb[(size_t)row * 2048 + col] = __float2bfloat16(u * sv);
        }
      }
}

// ---------------- Assemble q/k (partial RoPE, bf16 out) ----------------
__global__ __launch_bounds__(256) void k_qkv(const float* __restrict__ qf,
                                             const float* __restrict__ kvb,
                                             const float* __restrict__ ckv,
                                             const float* __restrict__ cosb,
                                             const float* __restrict__ sinb,
                                             __hip_bfloat16* __restrict__ qhb,
                                             __hip_bfloat16* __restrict__ khb) {
  int t = blockIdx.x;
  int l = t >> 3;
  for (int idx = threadIdx.x; idx < 768; idx += 256) {
    int hh = idx / 48, dc = idx % 48;
    int hd = hh >> 1, e = hh & 1;
    float qv, kvv;
    if (dc < 32) {
      qv  = qf [(size_t)t * 768  + hd * 96  + e * 32 + dc];
      kvv = kvb[(size_t)t * 1024 + hd * 128 + e * 32 + dc];
    } else {
      int rj = dc - 32;            // 0..15
      int p = rj >> 1; int isim = rj & 1;
      float xr_q = qf[(size_t)t * 768 + hd * 96 + 64 + e * 16 + p * 2];
      float xi_q = qf[(size_t)t * 768 + hd * 96 + 64 + e * 16 + p * 2 + 1];
      float xr_k = ckv[(size_t)t * 160 + 128 + e * 16 + p * 2];
      float xi_k = ckv[(size_t)t * 160 + 128 + e * 16 + p * 2 + 1];
      if (l == 0) {
        qv  = isim ? xi_q : xr_q;
        kvv = isim ? xi_k : xr_k;
      } else {
        float c = cosb[(l - 1) * 8 + p], s = sinb[(l - 1) * 8 + p];
        if (!isim) { qv = xr_q * c - xi_q * s; kvv = xr_k * c - xi_k * s; }
        else       { qv = xr_q * s + xi_q * c; kvv = xr_k * s + xi_k * c; }
      }
    }
    qhb[(size_t)t * 768 + idx] = __float2bfloat16(qv);
    khb[(size_t)t * 768 + idx] = __float2bfloat16(kvv);
  }
}

// ---------------- V transpose: vtb[c][t] bf16 ----------------
__global__ __launch_bounds__(256) void k_vtrans(const float* __restrict__ kvb,
                                                __hip_bfloat16* __restrict__ vtb) {
  __shared__ float tile[64][65];
  int tt = blockIdx.x, ct = blockIdx.y;    // (33, 8)
  int tid = threadIdx.x;
#pragma unroll
  for (int rep = 0; rep < 16; rep++) {
    int idx = rep * 256 + tid;
    int tr = idx >> 6, cc = idx & 63;
    int t = tt * 64 + tr;
    tile[tr][cc] = (t < Tn) ? kvb[(size_t)t * 1024 + ct * 128 + 64 + cc] : 0.f;
  }
  __syncthreads();
#pragma unroll
  for (int rep = 0; rep < 16; rep++) {
    int idx = rep * 256 + tid;
    int cr = idx >> 6, tc = idx & 63;
    int t = tt * 64 + tc;
    if (t < Tn)
      vtb[(size_t)(ct * 64 + cr) * Tn + t] = __float2bfloat16(tile[tc][cr]);
  }
}

// ---------------- lambda scalar ----------------
__global__ void k_lam(const float* __restrict__ lq1, const float* __restrict__ lk1,
                      const float* __restrict__ lq2, const float* __restrict__ lk2,
                      float lamc, float* __restrict__ out) {
  float d1 = 0.f, d2 = 0.f;
  for (int k = 0; k < 32; k++) { d1 = fmaf(lq1[k], lk1[k], d1); d2 = fmaf(lq2[k], lk2[k], d2); }
  out[0] = expf(d1) - expf(d2) + lamc;
}

// ---------------- attention pass 1 (jt-split x2): per-head per-half m,l ----------------
// grid (33, 16, 2). Writes mrow[(hf*16+hh)*TP+i], lsum[(hf*16+hh)*TP+i] (raw sum).
__global__ __launch_bounds__(256) void k_attn_pass1(const __hip_bfloat16* __restrict__ qhb,
                                                    const __hip_bfloat16* __restrict__ khb,
                                                    float* __restrict__ mrow,
                                                    float* __restrict__ lsum) {
  __shared__ unsigned short Qs[64][72];
  __shared__ unsigned short Ks[64][72];
  int bm = blockIdx.x * 64, hh = blockIdx.y, hf = blockIdx.z;
  int jt0 = hf * 17, jt1 = min(33, jt0 + 17);
  int tid = threadIdx.x;
  int wave = tid >> 6, lane = tid & 63;
  int lrow = lane & 15, lgrp = lane >> 4;
#pragma unroll
  for (int i = 0; i < 2; i++) {
    int vecIdx = tid + i * 256;
    int row = vecIdx >> 3, cg = vecIdx & 7;
    u16x8 v = {0, 0, 0, 0, 0, 0, 0, 0};
    int grow = bm + row;
    if (grow < Tn && cg < 6)
      v = *reinterpret_cast<const u16x8*>(qhb + (size_t)grow * 768 + hh * 48 + cg * 8);
    *reinterpret_cast<u16x8*>(&Qs[row][cg * 8]) = v;
  }
  float m_run[4], l_run[4];
#pragma unroll
  for (int r = 0; r < 4; r++) { m_run[r] = -3.4e38f; l_run[r] = 0.f; }
  int irow[4];
#pragma unroll
  for (int r = 0; r < 4; r++) irow[r] = bm + wave * 16 + lgrp * 4 + r;

  for (int jt = jt0; jt < jt1; jt++) {
    __syncthreads();
#pragma unroll
    for (int i = 0; i < 2; i++) {
      int vecIdx = tid + i * 256;
      int row = vecIdx >> 3, cg = vecIdx & 7;
      u16x8 v = {0, 0, 0, 0, 0, 0, 0, 0};
      int gj = jt * 64 + row;
      if (gj < Tn && cg < 6)
        v = *reinterpret_cast<const u16x8*>(khb + (size_t)gj * 768 + hh * 48 + cg * 8);
      *reinterpret_cast<u16x8*>(&Ks[row][cg * 8]) = v;
    }
    __syncthreads();
    f32x4 acc[4] = {};
#pragma unroll
    for (int ks = 0; ks < 2; ks++) {
      bf16x8 af = *reinterpret_cast<const bf16x8*>(&Qs[wave * 16 + lrow][ks * 32 + lgrp * 8]);
#pragma unroll
      for (int ni = 0; ni < 4; ni++) {
        bf16x8 bfr = *reinterpret_cast<const bf16x8*>(&Ks[ni * 16 + lrow][ks * 32 + lgrp * 8]);
        acc[ni] = __builtin_amdgcn_mfma_f32_16x16x32_bf16(af, bfr, acc[ni], 0, 0, 0);
      }
    }
#pragma unroll
    for (int r = 0; r < 4; r++) {
      int imod = irow[r] % LPn;
      float sv[4];
      float tmax = -3.4e38f;
#pragma unroll
      for (int ni = 0; ni < 4; ni++) {
        int j = jt * 64 + ni * 16 + lrow;
        sv[ni] = (j >= Tn || (j % LPn) > imod) ? -1e9f : acc[ni][r] * SCALING_C;
        tmax = fmaxf(tmax, sv[ni]);
      }
      for (int mk = 1; mk < 16; mk <<= 1) tmax = fmaxf(tmax, __shfl_xor(tmax, mk));
      float m_new = fmaxf(m_run[r], tmax);
      float ps = 0.f;
#pragma unroll
      for (int ni = 0; ni < 4; ni++) ps += __expf(sv[ni] - m_new);
      for (int mk = 1; mk < 16; mk <<= 1) ps += __shfl_xor(ps, mk);
      l_run[r] = l_run[r] * __expf(m_run[r] - m_new) + ps;
      m_run[r] = m_new;
    }
  }
  if (lrow == 0) {
#pragma unroll
    for (int r = 0; r < 4; r++) {
      if (irow[r] < Tn) {
        mrow[(size_t)(hf * 16 + blockIdx.y) * TP + irow[r]] = m_run[r];
        lsum[(size_t)(hf * 16 + blockIdx.y) * TP + irow[r]] = l_run[r];
      }
    }
  }
}

// ---------------- attention pass 2 (jt-split x2): P, PV partials, colsum ----------------
// grid (33, 8, 2). opv[((hf*8+p)*Tn+row)*64+col]; colsum halves write disjoint jt cols.
__global__ __launch_bounds__(256) void k_attn_pass2(const __hip_bfloat16* __restrict__ qhb,
                                                    const __hip_bfloat16* __restrict__ khb,
                                                    const __hip_bfloat16* __restrict__ vtb,
                                                    const float* __restrict__ mrow,
                                                    const float* __restrict__ lsum,
                                                    const float* __restrict__ lamp,
                                                    float* __restrict__ opv,
                                                    float* __restrict__ colsum_p) {
  __shared__ unsigned short Q1[64][72];
  __shared__ unsigned short Q2[64][72];
  __shared__ unsigned short K1s[64][72];
  __shared__ unsigned short K2s[64][72];
  __shared__ unsigned short Ps[64][72];
  __shared__ unsigned short Bv[64][72];
  int bm = blockIdx.x * 64, p = blockIdx.y, hf = blockIdx.z;
  int jt0 = hf * 17, jt1 = min(33, jt0 + 17);
  int hh1 = 2 * p, hh2 = 2 * p + 1;
  float lam = lamp[0];
  int tid = threadIdx.x;
  int wave = tid >> 6, lane = tid & 63;
  int lrow = lane & 15, lgrp = lane >> 4;
  const unsigned short* vt = (const unsigned short*)vtb + (size_t)p * 64 * Tn;
#pragma unroll
  for (int i = 0; i < 2; i++) {
    int vecIdx = tid + i * 256;
    int row = vecIdx >> 3, cg = vecIdx & 7;
    u16x8 v1 = {0, 0, 0, 0, 0, 0, 0, 0}, v2 = v1;
    int grow = bm + row;
    if (grow < Tn && cg < 6) {
      v1 = *reinterpret_cast<const u16x8*>(qhb + (size_t)grow * 768 + hh1 * 48 + cg * 8);
      v2 = *reinterpret_cast<const u16x8*>(qhb + (size_t)grow * 768 + hh2 * 48 + cg * 8);
    }
    *reinterpret_cast<u16x8*>(&Q1[row][cg * 8]) = v1;
    *reinterpret_cast<u16x8*>(&Q2[row][cg * 8]) = v2;
  }
  // per-lane row stats: merge the two jt-halves' (m,l)
  int irow[4]; float m1[4], li1[4], m2[4], li2[4];
#pragma unroll
  for (int r = 0; r < 4; r++) {
    irow[r] = bm + wave * 16 + lgrp * 4 + r;
    if (irow[r] < Tn) {
      float ma = mrow[(size_t)hh1 * TP + irow[r]],        la = lsum[(size_t)hh1 * TP + irow[r]];
      float mb = mrow[(size_t)(16 + hh1) * TP + irow[r]], lb = lsum[(size_t)(16 + hh1) * TP + irow[r]];
      float m = fmaxf(ma, mb);
      m1[r] = m; li1[r] = 1.f / (la * __expf(ma - m) + lb * __expf(mb - m));
      ma = mrow[(size_t)hh2 * TP + irow[r]];        la = lsum[(size_t)hh2 * TP + irow[r]];
      mb = mrow[(size_t)(16 + hh2) * TP + irow[r]]; lb = lsum[(size_t)(16 + hh2) * TP + irow[r]];
      m = fmaxf(ma, mb);
      m2[r] = m; li2[r] = 1.f / (la * __expf(ma - m) + lb * __expf(mb - m));
    } else { m1[r] = 0.f; li1[r] = 0.f; m2[r] = 0.f; li2[r] = 0.f; }
  }
  f32x4 accpv[4] = {};
  for (int jt = jt0; jt < jt1; jt++) {
    __syncthreads();
#pragma unroll
    for (int i = 0; i < 2; i++) {
      int vecIdx = tid + i * 256;
      int row = vecIdx >> 3, cg = vecIdx & 7;
      u16x8 v1 = {0, 0, 0, 0, 0, 0, 0, 0}, v2 = v1, vv = v1;
      int gj = jt * 64 + row;
      if (gj < Tn && cg < 6) {
        v1 = *reinterpret_cast<const u16x8*>(khb + (size_t)gj * 768 + hh1 * 48 + cg * 8);
        v2 = *reinterpret_cast<const u16x8*>(khb + (size_t)gj * 768 + hh2 * 48 + cg * 8);
      }
      int jc = jt * 64 + cg * 8;
      if (jc + 8 <= Tn)
        vv = *reinterpret_cast<const u16x8*>(vt + (size_t)row * Tn + jc);
      *reinterpret_cast<u16x8*>(&K1s[row][cg * 8]) = v1;
      *reinterpret_cast<u16x8*>(&K2s[row][cg * 8]) = v2;
      *reinterpret_cast<u16x8*>(&Bv[row][cg * 8]) = vv;
    }
    __syncthreads();
    f32x4 a1c[4] = {}, a2c[4] = {};
#pragma unroll
    for (int ks = 0; ks < 2; ks++) {
      bf16x8 af1 = *reinterpret_cast<const bf16x8*>(&Q1[wave * 16 + lrow][ks * 32 + lgrp * 8]);
      bf16x8 af2 = *reinterpret_cast<const bf16x8*>(&Q2[wave * 16 + lrow][ks * 32 + lgrp * 8]);
#pragma unroll
      for (int ni = 0; ni < 4; ni++) {
        bf16x8 b1 = *reinterpret_cast<const bf16x8*>(&K1s[ni * 16 + lrow][ks * 32 + lgrp * 8]);
        bf16x8 b2 = *reinterpret_cast<const bf16x8*>(&K2s[ni * 16 + lrow][ks * 32 + lgrp * 8]);
        a1c[ni] = __builtin_amdgcn_mfma_f32_16x16x32_bf16(af1, b1, a1c[ni], 0, 0, 0);
        a2c[ni] = __builtin_amdgcn_mfma_f32_16x16x32_bf16(af2, b2, a2c[ni], 0, 0, 0);
      }
    }
    float cs[4];
#pragma unroll
    for (int ni = 0; ni < 4; ni++) cs[ni] = 0.f;
#pragma unroll
    for (int ni = 0; ni < 4; ni++) {
      int j = jt * 64 + ni * 16 + lrow;
      int jmod = j % LPn;
      bool jok = (j < Tn);
#pragma unroll
      for (int r = 0; r < 4; r++) {
        int imod = irow[r] % LPn;
        bool masked = (!jok) || (jmod > imod);
        float sv1 = masked ? -1e9f : a1c[ni][r] * SCALING_C;
        float sv2 = masked ? -1e9f : a2c[ni][r] * SCALING_C;
        float a1 = __expf(sv1 - m1[r]) * li1[r];
        float a2 = __expf(sv2 - m2[r]) * li2[r];
        float c = fmaf(-lam, a2, a1);
        Ps[wave * 16 + lgrp * 4 + r][ni * 16 + lrow] = f2bu(c);
        cs[ni] += a1;
      }
    }
#pragma unroll
    for (int ni = 0; ni < 4; ni++) {
      cs[ni] += __shfl_xor(cs[ni], 16);
      cs[ni] += __shfl_xor(cs[ni], 32);
    }
    {
      float mine = (lgrp == 0) ? cs[0] : (lgrp == 1) ? cs[1] : (lgrp == 2) ? cs[2] : cs[3];
      colsum_p[((size_t)p * 132 + blockIdx.x * 4 + wave) * TP + jt * 64 + lgrp * 16 + lrow] = mine;
    }
    __syncthreads();
#pragma unroll
    for (int ks = 0; ks < 2; ks++) {
      bf16x8 af = *reinterpret_cast<const bf16x8*>(&Ps[wave * 16 + lrow][ks * 32 + lgrp * 8]);
#pragma unroll
      for (int ni = 0; ni < 4; ni++) {
        bf16x8 bfr = *reinterpret_cast<const bf16x8*>(&Bv[ni * 16 + lrow][ks * 32 + lgrp * 8]);
        accpv[ni] = __builtin_amdgcn_mfma_f32_16x16x32_bf16(af, bfr, accpv[ni], 0, 0, 0);
      }
    }
  }
#pragma unroll
  for (int ni = 0; ni < 4; ni++)
#pragma unroll
    for (int r = 0; r < 4; r++) {
      int row = bm + wave * 16 + lgrp * 4 + r;
      int col = ni * 16 + lrow;
      if (row < Tn) opv[((size_t)(hf * 8 + p) * Tn + row) * 64 + col] = accpv[ni][r];
    }
}

// ---------------- batched gwv: W[p][jmod][dv] ----------------
__global__ __launch_bounds__(64) void k_gwv(const float* __restrict__ colsum_p,
                                            const __hip_bfloat16* __restrict__ vtb,
                                            const float* __restrict__ lamp,
                                            float* __restrict__ Wb) {
  int jmod = blockIdx.x, p = blockIdx.y;
  int l = threadIdx.x;
  int k = l >> 3, sub = l & 7;
  int jk = jmod + 257 * k;
  float s = 0.f;
  for (int ib = sub; ib < 132; ib += 8) s += colsum_p[((size_t)p * 132 + ib) * TP + jk];
  for (int m = 1; m < 8; m <<= 1) s += __shfl_xor(s, m);
  float gv = s * (1.f / (float)Tn) * lamp[0];
  const __hip_bfloat16* vrow = vtb + (size_t)(p * 64 + l) * Tn;
  float acc = 0.f;
#pragma unroll
  for (int kk = 0; kk < 8; kk++) {
    float gk = __shfl(gv, kk * 8);
    acc = fmaf(gk, __bfloat162float(vrow[jmod + 257 * kk]), acc);
  }
  Wb[((size_t)p * 257 + jmod) * 64 + l] = acc;
}

// ---------------- batched chunksum ----------------
__global__ __launch_bounds__(64) void k_chunksum(const float* __restrict__ Wb,
                                                 float* __restrict__ Cb) {
  int c = blockIdx.x, p = blockIdx.y;
  int lane = threadIdx.x;
  int m0 = c * 16, m1 = min(m0 + 16, LPn);
  float acc = 0.f;
  for (int m = m0; m < m1; m++) acc += Wb[((size_t)p * 257 + m) * 64 + lane];
  Cb[((size_t)p * 17 + c) * 64 + lane] = acc;
}

// ---------------- pv_out: sum 2 opv halves + G-prefix + head-RMSNorm -> bf16 ----------------
__global__ __launch_bounds__(256) void k_pv_out(const float* __restrict__ opv,
                                                const float* __restrict__ Wb,
                                                const float* __restrict__ Cb,
                                                const float* __restrict__ hnw,
                                                __hip_bfloat16* __restrict__ onormb) {
  int w = threadIdx.x >> 6, lane = threadIdx.x & 63;
  int i = blockIdx.x * 4 + w;
  int p = blockIdx.y;
  int imod = i % LPn;
  int cidx = imod >> 4;
  float s = opv[((size_t)p * Tn + i) * 64 + lane]
          + opv[((size_t)(8 + p) * Tn + i) * 64 + lane];
  for (int c = 0; c < cidx; c++) s += Cb[((size_t)p * 17 + c) * 64 + lane];
  for (int m = cidx * 16; m <= imod; m++) s += Wb[((size_t)p * 257 + m) * 64 + lane];
  float ss = s * s;
  for (int off = 1; off < 64; off <<= 1) ss += __shfl_xor(ss, off);
  float scale = rsqrtf(ss * (1.f / 64.f) + 1e-5f);
  onormb[((size_t)p * Tn + i) * 64 + lane] = __float2bfloat16(s * scale * hnw[lane]);
}

// ---------------- final head (float32 out) ----------------
__global__ __launch_bounds__(192) void k_final(const float* __restrict__ z,
                                               const float* __restrict__ outW,
                                               float* __restrict__ out) {
  int t = blockIdx.x;
  int p = threadIdx.x >> 6, lane = threadIdx.x & 63;
  float acc = 0.f;
  for (int m = lane; m < 512; m += 64) acc = fmaf(z[(size_t)t * 512 + m], outW[(size_t)p * 512 + m], acc);
  for (int off = 1; off < 64; off <<= 1) acc += __shfl_xor(acc, off);
  if (lane == 0) out[(size_t)t * 3 + p] = acc;
}

extern "C" void kernel_launch(void* const* d_in, const int* in_sizes, int n_in,
                              void* d_out, int out_size, void* d_ws, size_t ws_size,
                              hipStream_t stream) {
  const float* x          = (const float*)d_in[0];
  const float* ticker_emb = (const float*)d_in[1];
  const float* sep_emb    = (const float*)d_in[2];
  const float* shared_W   = (const float*)d_in[3];
  const float* unique_W   = (const float*)d_in[4];
  const float* norm1_w    = (const float*)d_in[5];
  const float* norm2_w    = (const float*)d_in[6];
  const float* kv_down_W  = (const float*)d_in[7];
  const float* q_down_W   = (const float*)d_in[8];
  const float* kv_up_W    = (const float*)d_in[9];
  const float* q_up_W     = (const float*)d_in[10];
  const float* kv_norm_w  = (const float*)d_in[11];
  const float* q_norm_w   = (const float*)d_in[12];
  const float* o_W        = (const float*)d_in[13];
  const float* lam_q1     = (const float*)d_in[14];
  const float* lam_k1     = (const float*)d_in[15];
  const float* lam_q2     = (const float*)d_in[16];
  const float* lam_k2     = (const float*)d_in[17];
  const float* head_norm_w= (const float*)d_in[18];
  const float* ff_in_W    = (const float*)d_in[19];
  const float* ff_out_W   = (const float*)d_in[20];
  const float* final_norm = (const float*)d_in[21];
  const float* out_W      = (const float*)d_in[22];
  const int*   seperator  = (const int*)d_in[23];
  const int*   tickers    = (const int*)d_in[24];
  (void)in_sizes; (void)n_in;

  float* W = (float*)d_ws;
  size_t off = 0;
  auto alloc = [&](size_t n) { float* p = W + off; off += n; return p; };
  float* cosb  = alloc(2048);
  float* sinb  = alloc(2048);
  float* h     = alloc((size_t)Tn * Dn);
  float* xnb_f = alloc((size_t)Tn * 256);         // bf16 T x 512 (also z)
  float* ckv   = alloc((size_t)Tn * 160);         // ckv+qlat host onormb later
  float* qlat  = alloc((size_t)Tn * 192);
  float* ckvnb_f = alloc((size_t)Tn * 64);        // bf16 T x 128
  float* qlatnb_f = alloc((size_t)Tn * 96);       // bf16 T x 192
  float* kvb   = alloc((size_t)Tn * 1024);        // opv(2x8xTx64) / gatedb overlays
  float* qf    = alloc((size_t)Tn * 768);         // zfin overlay
  float* qhb_f = alloc((size_t)Tn * 384);         // bf16 T x 768
  float* khb_f = alloc((size_t)Tn * 384);         // bf16 T x 768
  float* vtb_f = alloc((size_t)Tn * 256);         // bf16 512 x T
  float* mrow  = alloc((size_t)32 * TP);          // [hf][16][TP]
  float* lsumb = alloc((size_t)32 * TP);
  float* lam   = alloc(4);
  float* colsum_p = alloc((size_t)8 * 132 * TP);
  float* Wb    = alloc((size_t)8 * 257 * 64);
  float* Cb    = alloc((size_t)8 * 17 * 64);
  float* pp    = alloc((size_t)4 * Tn * 512);     // K-split GEMM partials

  __hip_bfloat16* xnb    = (__hip_bfloat16*)xnb_f;
  __hip_bfloat16* ckvnb  = (__hip_bfloat16*)ckvnb_f;
  __hip_bfloat16* qlatnb = (__hip_bfloat16*)qlatnb_f;
  __hip_bfloat16* onormb = (__hip_bfloat16*)ckv;     // bf16 T x 512 over ckv+qlat
  __hip_bfloat16* gatedb = (__hip_bfloat16*)kvb;     // bf16 T x 2048
  __hip_bfloat16* qhb    = (__hip_bfloat16*)qhb_f;
  __hip_bfloat16* khb    = (__hip_bfloat16*)khb_f;
  __hip_bfloat16* vtb    = (__hip_bfloat16*)vtb_f;
  float* opv   = kvb;        // 2x8xTx64 f32 = T*1024 f32 exactly
  float* zfin  = qf;

  size_t needed = off * sizeof(float);            // ~60.8 MB (< 79.5 proven)
  if (ws_size < needed) {
    k_fill42<<<(out_size + 255) / 256, 256, 0, stream>>>((float*)d_out, out_size);
    return;
  }

  k_freqs<<<8, 256, 0, stream>>>(cosb, sinb);
  k_embed<<<dim3(Tn, 2), 256, 0, stream>>>(x, ticker_emb, sep_emb, shared_W, unique_W,
                                           seperator, tickers, h);

  for (int d = 0; d < 2; d++) {
    const float* n1   = norm1_w + d * 512;
    const float* n2   = norm2_w + d * 512;
    const float* kvd  = kv_down_W + (size_t)d * 160 * 512;
    const float* qd   = q_down_W + (size_t)d * 192 * 512;
    const float* kvu  = kv_up_W + (size_t)d * 1024 * 128;
    const float* qu   = q_up_W + (size_t)d * 768 * 192;
    const float* kvnw = kv_norm_w + d * 128;
    const float* qnw  = q_norm_w + d * 192;
    const float* oW   = o_W + (size_t)d * 512 * 512;
    const float* hnw  = head_norm_w + d * 64;
    const float* ffi  = ff_in_W + (size_t)d * 4096 * 512;
    const float* ffo  = ff_out_W + (size_t)d * 512 * 2048;
    float lamc = 0.8f - 0.6f * expf(-0.3f * (float)d);

    k_rmsnorm_b<<<Tn, 256, 0, stream>>>(h, n1, xnb, 512, 512, EPS_C);
    k_gemm64<0><<<dim3(3, 33), 256, 0, stream>>>(xnb, kvd, ckv, Tn, 160, 512);
    k_rmsnorm_b<<<Tn, 256, 0, stream>>>(ckv, kvnw, ckvnb, 128, 160, EPS_C);
    k_gemm64<0><<<dim3(16, 33), 256, 0, stream>>>(ckvnb, kvu, kvb, Tn, 1024, 128);
    k_gemm64<0><<<dim3(3, 33), 256, 0, stream>>>(xnb, qd, qlat, Tn, 192, 512);
    k_rmsnorm_b<<<Tn, 256, 0, stream>>>(qlat, qnw, qlatnb, 192, 192, EPS_C);
    k_gemm64<0><<<dim3(12, 33), 256, 0, stream>>>(qlatnb, qu, qf, Tn, 768, 192);
    k_qkv<<<Tn, 256, 0, stream>>>(qf, kvb, ckv, cosb, sinb, qhb, khb);
    k_vtrans<<<dim3(33, 8), 256, 0, stream>>>(kvb, vtb);
    k_lam<<<1, 1, 0, stream>>>(lam_q1 + d * 32, lam_k1 + d * 32,
                               lam_q2 + d * 32, lam_k2 + d * 32, lamc, lam);

    k_attn_pass1<<<dim3(33, 16, 2), 256, 0, stream>>>(qhb, khb, mrow, lsumb);
    k_attn_pass2<<<dim3(33, 8, 2), 256, 0, stream>>>(qhb, khb, vtb, mrow, lsumb, lam,
                                                     opv, colsum_p);
    k_gwv<<<dim3(257, 8), 64, 0, stream>>>(colsum_p, vtb, lam, Wb);
    k_chunksum<<<dim3(17, 8), 64, 0, stream>>>(Wb, Cb);
    k_pv_out<<<dim3(514, 8), 256, 0, stream>>>(opv, Wb, Cb, hnw, onormb);

    // o-proj: K=512 split x2 -> partials -> h +=
    k_gemm64p<<<dim3(8, 33, 2), 256, 0, stream>>>(onormb, oW, pp, Tn, 512, 256);
    k_addred<<<(Tn * 512 + 255) / 256, 256, 0, stream>>>(h, pp, (long)Tn * 512, 2);
    k_rmsnorm_b<<<Tn, 256, 0, stream>>>(h, n2, xnb, 512, 512, EPS_C);
    k_ffn<<<dim3(32, 17), 256, 0, stream>>>(xnb, ffi, gatedb);
    // ffo: K=2048 split x4 -> partials -> h +=
    k_gemm64p<<<dim3(8, 33, 4), 256, 0, stream>>>(gatedb, ffo, pp, Tn, 512, 512);
    k_addred<<<(Tn * 512 + 255) / 256, 256, 0, stream>>>(h, pp, (long)Tn * 512, 4);
  }

  k_rmsnorm<<<Tn, 256, 0, stream>>>(h, final_norm, zfin, 512, 512, EPS_C);
  k_final<<<Tn, 192, 0, stream>>>(zfin, out_W, (float*)d_out);
}

// Round 14
// 630.076 us; speedup vs baseline: 15.4648x; 1.0817x over previous
//
#include <hip/hip_runtime.h>
#include <hip/hip_bf16.h>

// Money_former MLA DINT — round 14: pass2 occupancy surgery.
// LDS 55->42.5 KB (pad 72->68, Ps aliases K1s w/ extra sync), jt-split x4
// (grid 1056, PV partials in pp = 4x8xTx64), pv_out sums 4 halves.
// T=2056, D=512, 2 layers, 16 logical heads (8 pairs) of 48.

#define Tn 2056
#define LPn 257
#define Dn 512
#define TP 2112   // padded T (33*64)

static constexpr float SCALING_C = 0.14433756729740643f;   // 48^-0.5
static constexpr float EPS_C     = 1.1920928955078125e-07f;

typedef float f32x4 __attribute__((ext_vector_type(4)));
typedef short bf16x8 __attribute__((ext_vector_type(8)));
typedef unsigned short u16x8 __attribute__((ext_vector_type(8)));

__device__ __forceinline__ unsigned short f2bu(float f) {
  __hip_bfloat16 h = __float2bfloat16(f);
  return *reinterpret_cast<unsigned short*>(&h);
}

// ---------------- sentinel ----------------
__global__ __launch_bounds__(256) void k_fill42(float* __restrict__ out, int n) {
  int i = blockIdx.x * 256 + threadIdx.x;
  if (i < n) out[i] = 42.0f;
}

// ---------------- RoPE tables ----------------
__global__ __launch_bounds__(256) void k_freqs(float* __restrict__ cosb, float* __restrict__ sinb) {
  int idx = blockIdx.x * 256 + threadIdx.x;
  if (idx >= 256 * 8) return;
  int pos = idx >> 3, j = idx & 7;
  float fb = powf(10000.f, -(float)j * 0.125f);            // 1/10000^(j/8)
  float ramp = fminf(fmaxf((float)j * 0.25f, 0.f), 1.f);   // low=0, high=4
  float sm = 1.f - ramp;
  float fr = fb * (1.f / 40.f) * (1.f - sm) + fb * sm;
  float ang = (float)pos * fr;
  cosb[idx] = cosf(ang);
  sinb[idx] = sinf(ang);
}

// ---------------- Embedding ----------------
__global__ __launch_bounds__(256) void k_embed(const float* __restrict__ x,
                                               const float* __restrict__ ticker_emb,
                                               const float* __restrict__ sep_emb,
                                               const float* __restrict__ shared_W,
                                               const float* __restrict__ unique_W,
                                               const int* __restrict__ sep_idx,
                                               const int* __restrict__ tickers,
                                               float* __restrict__ h) {
  int t = blockIdx.x;
  int c = blockIdx.y * 256 + threadIdx.x;
  int l = t >> 3, s = t & 7;
  float val;
  if (l == 0) {
    val = sep_emb[sep_idx[0] * Dn + c];
  } else {
    const float* xr = x + ((size_t)(l - 1) * 8 + s) * 32;
    const float* w = (c < 384) ? (shared_W + (size_t)c * 32)
                               : (unique_W + ((size_t)s * 128 + (c - 384)) * 32);
    float acc = 0.f;
#pragma unroll
    for (int f = 0; f < 32; f++) acc = fmaf(xr[f], w[f], acc);
    val = acc;
  }
  val += ticker_emb[(size_t)tickers[s] * Dn + c];
  h[(size_t)t * Dn + c] = val;
}

// ---------------- Row RMSNorm, f32 out ----------------
__global__ __launch_bounds__(256) void k_rmsnorm(const float* __restrict__ in,
                                                 const float* __restrict__ w,
                                                 float* __restrict__ out,
                                                 int ncols, int in_stride, float eps) {
  int row = blockIdx.x;
  const float* xr = in + (size_t)row * in_stride;
  float ss = 0.f;
  for (int c = threadIdx.x; c < ncols; c += 256) { float v = xr[c]; ss = fmaf(v, v, ss); }
  for (int off = 1; off < 64; off <<= 1) ss += __shfl_xor(ss, off);
  __shared__ float red[4];
  if ((threadIdx.x & 63) == 0) red[threadIdx.x >> 6] = ss;
  __syncthreads();
  float tot = red[0] + red[1] + red[2] + red[3];
  float scale = rsqrtf(tot / (float)ncols + eps);
  for (int c = threadIdx.x; c < ncols; c += 256)
    out[(size_t)row * ncols + c] = xr[c] * scale * w[c];
}

// ---------------- Row RMSNorm, bf16 out ----------------
__global__ __launch_bounds__(256) void k_rmsnorm_b(const float* __restrict__ in,
                                                   const float* __restrict__ w,
                                                   __hip_bfloat16* __restrict__ out,
                                                   int ncols, int in_stride, float eps) {
  int row = blockIdx.x;
  const float* xr = in + (size_t)row * in_stride;
  float ss = 0.f;
  for (int c = threadIdx.x; c < ncols; c += 256) { float v = xr[c]; ss = fmaf(v, v, ss); }
  for (int off = 1; off < 64; off <<= 1) ss += __shfl_xor(ss, off);
  __shared__ float red[4];
  if ((threadIdx.x & 63) == 0) red[threadIdx.x >> 6] = ss;
  __syncthreads();
  float tot = red[0] + red[1] + red[2] + red[3];
  float scale = rsqrtf(tot / (float)ncols + eps);
  for (int c = threadIdx.x; c < ncols; c += 256)
    out[(size_t)row * ncols + c] = __float2bfloat16(xr[c] * scale * w[c]);
}

// ---------------- 64x64 MFMA GEMM: C (+)= A[M,K]bf16 @ (B[N,K]f32)^T ----------------
template <int MODE>
__global__ __launch_bounds__(256) void k_gemm64(const __hip_bfloat16* __restrict__ A,
                                                const float* __restrict__ B,
                                                float* __restrict__ C,
                                                int M, int N, int K) {
  __shared__ unsigned short Als[64][40];
  __shared__ unsigned short Bls[64][40];
  int bm = blockIdx.y * 64, bn = blockIdx.x * 64;
  int tid = threadIdx.x;
  int wave = tid >> 6, lane = tid & 63;
  int lrow = lane & 15, lgrp = lane >> 4;
  f32x4 acc[4] = {};
  for (int k0 = 0; k0 < K; k0 += 32) {
    {
      int row = tid >> 2, cg = tid & 3;
      u16x8 v = {0, 0, 0, 0, 0, 0, 0, 0};
      if (bm + row < M)
        v = *reinterpret_cast<const u16x8*>(A + (size_t)(bm + row) * K + k0 + cg * 8);
      *reinterpret_cast<u16x8*>(&Als[row][cg * 8]) = v;
    }
    {
      int row = tid >> 2, cg = tid & 3;
      u16x8 v = {0, 0, 0, 0, 0, 0, 0, 0};
      if (bn + row < N) {
        const float* bp = B + (size_t)(bn + row) * K + k0 + cg * 8;
        f32x4 b0 = *reinterpret_cast<const f32x4*>(bp);
        f32x4 b1 = *reinterpret_cast<const f32x4*>(bp + 4);
#pragma unroll
        for (int e = 0; e < 4; e++) { v[e] = f2bu(b0[e]); v[e + 4] = f2bu(b1[e]); }
      }
      *reinterpret_cast<u16x8*>(&Bls[row][cg * 8]) = v;
    }
    __syncthreads();
    bf16x8 af = *reinterpret_cast<const bf16x8*>(&Als[wave * 16 + lrow][lgrp * 8]);
    bf16x8 bfr[4];
#pragma unroll
    for (int ni = 0; ni < 4; ni++)
      bfr[ni] = *reinterpret_cast<const bf16x8*>(&Bls[ni * 16 + lrow][lgrp * 8]);
#pragma unroll
    for (int ni = 0; ni < 4; ni++)
      acc[ni] = __builtin_amdgcn_mfma_f32_16x16x32_bf16(af, bfr[ni], acc[ni], 0, 0, 0);
    __syncthreads();
  }
#pragma unroll
  for (int ni = 0; ni < 4; ni++)
#pragma unroll
    for (int r = 0; r < 4; r++) {
      int row = bm + wave * 16 + lgrp * 4 + r;
      int col = bn + ni * 16 + lrow;
      if (row < M && col < N) {
        if (MODE) C[(size_t)row * N + col] += acc[ni][r];
        else      C[(size_t)row * N + col] = acc[ni][r];
      }
    }
}

// ---------------- K-split 64x64 MFMA GEMM -> partial buffer pp[kc] ----------------
__global__ __launch_bounds__(256) void k_gemm64p(const __hip_bfloat16* __restrict__ A,
                                                 const float* __restrict__ B,
                                                 float* __restrict__ pp,
                                                 int M, int N, int kchunk) {
  __shared__ unsigned short Als[64][40];
  __shared__ unsigned short Bls[64][40];
  int bm = blockIdx.y * 64, bn = blockIdx.x * 64;
  int kc = blockIdx.z;
  int K = kchunk * gridDim.z;
  int kbase = kc * kchunk;
  int tid = threadIdx.x;
  int wave = tid >> 6, lane = tid & 63;
  int lrow = lane & 15, lgrp = lane >> 4;
  f32x4 acc[4] = {};
  for (int k0 = kbase; k0 < kbase + kchunk; k0 += 32) {
    {
      int row = tid >> 2, cg = tid & 3;
      u16x8 v = {0, 0, 0, 0, 0, 0, 0, 0};
      if (bm + row < M)
        v = *reinterpret_cast<const u16x8*>(A + (size_t)(bm + row) * K + k0 + cg * 8);
      *reinterpret_cast<u16x8*>(&Als[row][cg * 8]) = v;
    }
    {
      int row = tid >> 2, cg = tid & 3;
      u16x8 v = {0, 0, 0, 0, 0, 0, 0, 0};
      if (bn + row < N) {
        const float* bp = B + (size_t)(bn + row) * K + k0 + cg * 8;
        f32x4 b0 = *reinterpret_cast<const f32x4*>(bp);
        f32x4 b1 = *reinterpret_cast<const f32x4*>(bp + 4);
#pragma unroll
        for (int e = 0; e < 4; e++) { v[e] = f2bu(b0[e]); v[e + 4] = f2bu(b1[e]); }
      }
      *reinterpret_cast<u16x8*>(&Bls[row][cg * 8]) = v;
    }
    __syncthreads();
    bf16x8 af = *reinterpret_cast<const bf16x8*>(&Als[wave * 16 + lrow][lgrp * 8]);
    bf16x8 bfr[4];
#pragma unroll
    for (int ni = 0; ni < 4; ni++)
      bfr[ni] = *reinterpret_cast<const bf16x8*>(&Bls[ni * 16 + lrow][lgrp * 8]);
#pragma unroll
    for (int ni = 0; ni < 4; ni++)
      acc[ni] = __builtin_amdgcn_mfma_f32_16x16x32_bf16(af, bfr[ni], acc[ni], 0, 0, 0);
    __syncthreads();
  }
#pragma unroll
  for (int ni = 0; ni < 4; ni++)
#pragma unroll
    for (int r = 0; r < 4; r++) {
      int row = bm + wave * 16 + lgrp * 4 + r;
      int col = bn + ni * 16 + lrow;
      if (row < M && col < N)
        pp[(size_t)kc * M * N + (size_t)row * N + col] = acc[ni][r];
    }
}

// ---------------- C += sum of nsplit partials ----------------
__global__ __launch_bounds__(256) void k_addred(float* __restrict__ C,
                                                const float* __restrict__ pp,
                                                long n, int nsplit) {
  long i = (long)blockIdx.x * 256 + threadIdx.x;
  if (i >= n) return;
  float s = 0.f;
  for (int k = 0; k < nsplit; k++) s += pp[(size_t)k * n + i];
  C[i] += s;
}

// ---------------- Fused FFN-in + SwiGLU ----------------
__global__ __launch_bounds__(256) void k_ffn(const __hip_bfloat16* __restrict__ A,
                                             const float* __restrict__ Bw,
                                             __hip_bfloat16* __restrict__ gatedb) {
  __shared__ unsigned short Als[128][40];
  __shared__ unsigned short Bls[128][40];
  int bm = blockIdx.y * 128, bn = blockIdx.x * 64;
  int tid = threadIdx.x;
  int wave = tid >> 6, lane = tid & 63;
  int lrow = lane & 15, lgrp = lane >> 4;
  f32x4 acc[2][8] = {};
  for (int k0 = 0; k0 < 512; k0 += 32) {
#pragma unroll
    for (int i = 0; i < 2; i++) {
      int vecIdx = tid + i * 256;
      int row = vecIdx >> 2, cg = vecIdx & 3;
      u16x8 v = {0, 0, 0, 0, 0, 0, 0, 0};
      if (bm + row < Tn)
        v = *reinterpret_cast<const u16x8*>(A + (size_t)(bm + row) * 512 + k0 + cg * 8);
      *reinterpret_cast<u16x8*>(&Als[row][cg * 8]) = v;
    }
#pragma unroll
    for (int i = 0; i < 2; i++) {
      int vecIdx = tid + i * 256;
      int row = vecIdx >> 2, cg = vecIdx & 3;
      int grow = (row < 64) ? (bn + row) : (2048 + bn + (row - 64));
      const float* bp = Bw + (size_t)grow * 512 + k0 + cg * 8;
      f32x4 b0 = *reinterpret_cast<const f32x4*>(bp);
      f32x4 b1 = *reinterpret_cast<const f32x4*>(bp + 4);
      u16x8 v;
#pragma unroll
      for (int e = 0; e < 4; e++) { v[e] = f2bu(b0[e]); v[e + 4] = f2bu(b1[e]); }
      *reinterpret_cast<u16x8*>(&Bls[row][cg * 8]) = v;
    }
    __syncthreads();
    bf16x8 af[2], bfr[8];
#pragma unroll
    for (int mi = 0; mi < 2; mi++)
      af[mi] = *reinterpret_cast<const bf16x8*>(&Als[wave * 32 + mi * 16 + lrow][lgrp * 8]);
#pragma unroll
    for (int ni = 0; ni < 8; ni++)
      bfr[ni] = *reinterpret_cast<const bf16x8*>(&Bls[ni * 16 + lrow][lgrp * 8]);
#pragma unroll
    for (int mi = 0; mi < 2; mi++)
#pragma unroll
      for (int ni = 0; ni < 8; ni++)
        acc[mi][ni] = __builtin_amdgcn_mfma_f32_16x16x32_bf16(af[mi], bfr[ni], acc[mi][ni], 0, 0, 0);
    __syncthreads();
  }
#pragma unroll
  for (int mi = 0; mi < 2; mi++)
#pragma unroll
    for (int ni = 0; ni < 4; ni++)
#pragma unroll
      for (int r = 0; r < 4; r++) {
        int row = bm + wave * 32 + mi * 16 + lgrp * 4 + r;
        int col = bn + ni * 16 + lrow;
        if (row < Tn) {
          float u = acc[mi][ni][r];
          float vv = acc[mi][ni + 4][r];
          float sv = vv / (1.f + __expf(-vv));
          gatedb[(size_t)row * 2048 + col] = __float2bfloat16(u * sv);
        }
      }
}

// ---------------- Assemble q/k (partial RoPE, bf16 out) ----------------
__global__ __launch_bounds__(256) void k_qkv(const float* __restrict__ qf,
                                             const float* __restrict__ kvb,
                                             const float* __restrict__ ckv,
                                             const float* __restrict__ cosb,
                                             const float* __restrict__ sinb,
                                             __hip_bfloat16* __restrict__ qhb,
                                             __hip_bfloat16* __restrict__ khb) {
  int t = blockIdx.x;
  int l = t >> 3;
  for (int idx = threadIdx.x; idx < 768; idx += 256) {
    int hh = idx / 48, dc = idx % 48;
    int hd = hh >> 1, e = hh & 1;
    float qv, kvv;
    if (dc < 32) {
      qv  = qf [(size_t)t * 768  + hd * 96  + e * 32 + dc];
      kvv = kvb[(size_t)t * 1024 + hd * 128 + e * 32 + dc];
    } else {
      int rj = dc - 32;            // 0..15
      int p = rj >> 1; int isim = rj & 1;
      float xr_q = qf[(size_t)t * 768 + hd * 96 + 64 + e * 16 + p * 2];
      float xi_q = qf[(size_t)t * 768 + hd * 96 + 64 + e * 16 + p * 2 + 1];
      float xr_k = ckv[(size_t)t * 160 + 128 + e * 16 + p * 2];
      float xi_k = ckv[(size_t)t * 160 + 128 + e * 16 + p * 2 + 1];
      if (l == 0) {
        qv  = isim ? xi_q : xr_q;
        kvv = isim ? xi_k : xr_k;
      } else {
        float c = cosb[(l - 1) * 8 + p], s = sinb[(l - 1) * 8 + p];
        if (!isim) { qv = xr_q * c - xi_q * s; kvv = xr_k * c - xi_k * s; }
        else       { qv = xr_q * s + xi_q * c; kvv = xr_k * s + xi_k * c; }
      }
    }
    qhb[(size_t)t * 768 + idx] = __float2bfloat16(qv);
    khb[(size_t)t * 768 + idx] = __float2bfloat16(kvv);
  }
}

// ---------------- V transpose: vtb[c][t] bf16 ----------------
__global__ __launch_bounds__(256) void k_vtrans(const float* __restrict__ kvb,
                                                __hip_bfloat16* __restrict__ vtb) {
  __shared__ float tile[64][65];
  int tt = blockIdx.x, ct = blockIdx.y;    // (33, 8)
  int tid = threadIdx.x;
#pragma unroll
  for (int rep = 0; rep < 16; rep++) {
    int idx = rep * 256 + tid;
    int tr = idx >> 6, cc = idx & 63;
    int t = tt * 64 + tr;
    tile[tr][cc] = (t < Tn) ? kvb[(size_t)t * 1024 + ct * 128 + 64 + cc] : 0.f;
  }
  __syncthreads();
#pragma unroll
  for (int rep = 0; rep < 16; rep++) {
    int idx = rep * 256 + tid;
    int cr = idx >> 6, tc = idx & 63;
    int t = tt * 64 + tc;
    if (t < Tn)
      vtb[(size_t)(ct * 64 + cr) * Tn + t] = __float2bfloat16(tile[tc][cr]);
  }
}

// ---------------- lambda scalar ----------------
__global__ void k_lam(const float* __restrict__ lq1, const float* __restrict__ lk1,
                      const float* __restrict__ lq2, const float* __restrict__ lk2,
                      float lamc, float* __restrict__ out) {
  float d1 = 0.f, d2 = 0.f;
  for (int k = 0; k < 32; k++) { d1 = fmaf(lq1[k], lk1[k], d1); d2 = fmaf(lq2[k], lk2[k], d2); }
  out[0] = expf(d1) - expf(d2) + lamc;
}

// ---------------- attention pass 1 (jt-split x2): per-head per-half m,l ----------------
__global__ __launch_bounds__(256) void k_attn_pass1(const __hip_bfloat16* __restrict__ qhb,
                                                    const __hip_bfloat16* __restrict__ khb,
                                                    float* __restrict__ mrow,
                                                    float* __restrict__ lsum) {
  __shared__ unsigned short Qs[64][68];
  __shared__ unsigned short Ks[64][68];
  int bm = blockIdx.x * 64, hh = blockIdx.y, hf = blockIdx.z;
  int jt0 = hf * 17, jt1 = min(33, jt0 + 17);
  int tid = threadIdx.x;
  int wave = tid >> 6, lane = tid & 63;
  int lrow = lane & 15, lgrp = lane >> 4;
#pragma unroll
  for (int i = 0; i < 2; i++) {
    int vecIdx = tid + i * 256;
    int row = vecIdx >> 3, cg = vecIdx & 7;
    u16x8 v = {0, 0, 0, 0, 0, 0, 0, 0};
    int grow = bm + row;
    if (grow < Tn && cg < 6)
      v = *reinterpret_cast<const u16x8*>(qhb + (size_t)grow * 768 + hh * 48 + cg * 8);
    *reinterpret_cast<u16x8*>(&Qs[row][cg * 8]) = v;
  }
  float m_run[4], l_run[4];
#pragma unroll
  for (int r = 0; r < 4; r++) { m_run[r] = -3.4e38f; l_run[r] = 0.f; }
  int irow[4];
#pragma unroll
  for (int r = 0; r < 4; r++) irow[r] = bm + wave * 16 + lgrp * 4 + r;

  for (int jt = jt0; jt < jt1; jt++) {
    __syncthreads();
#pragma unroll
    for (int i = 0; i < 2; i++) {
      int vecIdx = tid + i * 256;
      int row = vecIdx >> 3, cg = vecIdx & 7;
      u16x8 v = {0, 0, 0, 0, 0, 0, 0, 0};
      int gj = jt * 64 + row;
      if (gj < Tn && cg < 6)
        v = *reinterpret_cast<const u16x8*>(khb + (size_t)gj * 768 + hh * 48 + cg * 8);
      *reinterpret_cast<u16x8*>(&Ks[row][cg * 8]) = v;
    }
    __syncthreads();
    f32x4 acc[4] = {};
#pragma unroll
    for (int ks = 0; ks < 2; ks++) {
      bf16x8 af = *reinterpret_cast<const bf16x8*>(&Qs[wave * 16 + lrow][ks * 32 + lgrp * 8]);
#pragma unroll
      for (int ni = 0; ni < 4; ni++) {
        bf16x8 bfr = *reinterpret_cast<const bf16x8*>(&Ks[ni * 16 + lrow][ks * 32 + lgrp * 8]);
        acc[ni] = __builtin_amdgcn_mfma_f32_16x16x32_bf16(af, bfr, acc[ni], 0, 0, 0);
      }
    }
#pragma unroll
    for (int r = 0; r < 4; r++) {
      int imod = irow[r] % LPn;
      float sv[4];
      float tmax = -3.4e38f;
#pragma unroll
      for (int ni = 0; ni < 4; ni++) {
        int j = jt * 64 + ni * 16 + lrow;
        sv[ni] = (j >= Tn || (j % LPn) > imod) ? -1e9f : acc[ni][r] * SCALING_C;
        tmax = fmaxf(tmax, sv[ni]);
      }
      for (int mk = 1; mk < 16; mk <<= 1) tmax = fmaxf(tmax, __shfl_xor(tmax, mk));
      float m_new = fmaxf(m_run[r], tmax);
      float ps = 0.f;
#pragma unroll
      for (int ni = 0; ni < 4; ni++) ps += __expf(sv[ni] - m_new);
      for (int mk = 1; mk < 16; mk <<= 1) ps += __shfl_xor(ps, mk);
      l_run[r] = l_run[r] * __expf(m_run[r] - m_new) + ps;
      m_run[r] = m_new;
    }
  }
  if (lrow == 0) {
#pragma unroll
    for (int r = 0; r < 4; r++) {
      if (irow[r] < Tn) {
        mrow[(size_t)(hf * 16 + blockIdx.y) * TP + irow[r]] = m_run[r];
        lsum[(size_t)(hf * 16 + blockIdx.y) * TP + irow[r]] = l_run[r];
      }
    }
  }
}

// ---------------- attention pass 2 (jt-split x4, Ps aliases K1s) ----------------
// grid (33, 8, 4). opv[((hf*8+p)*Tn+row)*64+col] into pp; colsum jt cols disjoint.
__global__ __launch_bounds__(256) void k_attn_pass2(const __hip_bfloat16* __restrict__ qhb,
                                                    const __hip_bfloat16* __restrict__ khb,
                                                    const __hip_bfloat16* __restrict__ vtb,
                                                    const float* __restrict__ mrow,
                                                    const float* __restrict__ lsum,
                                                    const float* __restrict__ lamp,
                                                    float* __restrict__ opv,
                                                    float* __restrict__ colsum_p) {
  __shared__ unsigned short Q1[64][68];
  __shared__ unsigned short Q2[64][68];
  __shared__ unsigned short K1s[64][68];   // Ps aliases this after score MFMAs
  __shared__ unsigned short K2s[64][68];
  __shared__ unsigned short Bv[64][68];
  unsigned short (*Ps)[68] = K1s;
  int bm = blockIdx.x * 64, p = blockIdx.y, hf = blockIdx.z;
  int jt0 = hf * 9, jt1 = min(33, jt0 + 9);
  int hh1 = 2 * p, hh2 = 2 * p + 1;
  float lam = lamp[0];
  int tid = threadIdx.x;
  int wave = tid >> 6, lane = tid & 63;
  int lrow = lane & 15, lgrp = lane >> 4;
  const unsigned short* vt = (const unsigned short*)vtb + (size_t)p * 64 * Tn;
#pragma unroll
  for (int i = 0; i < 2; i++) {
    int vecIdx = tid + i * 256;
    int row = vecIdx >> 3, cg = vecIdx & 7;
    u16x8 v1 = {0, 0, 0, 0, 0, 0, 0, 0}, v2 = v1;
    int grow = bm + row;
    if (grow < Tn && cg < 6) {
      v1 = *reinterpret_cast<const u16x8*>(qhb + (size_t)grow * 768 + hh1 * 48 + cg * 8);
      v2 = *reinterpret_cast<const u16x8*>(qhb + (size_t)grow * 768 + hh2 * 48 + cg * 8);
    }
    *reinterpret_cast<u16x8*>(&Q1[row][cg * 8]) = v1;
    *reinterpret_cast<u16x8*>(&Q2[row][cg * 8]) = v2;
  }
  // merge the two pass1 jt-halves' (m,l)
  int irow[4]; float m1[4], li1[4], m2[4], li2[4];
#pragma unroll
  for (int r = 0; r < 4; r++) {
    irow[r] = bm + wave * 16 + lgrp * 4 + r;
    if (irow[r] < Tn) {
      float ma = mrow[(size_t)hh1 * TP + irow[r]],        la = lsum[(size_t)hh1 * TP + irow[r]];
      float mb = mrow[(size_t)(16 + hh1) * TP + irow[r]], lb = lsum[(size_t)(16 + hh1) * TP + irow[r]];
      float m = fmaxf(ma, mb);
      m1[r] = m; li1[r] = 1.f / (la * __expf(ma - m) + lb * __expf(mb - m));
      ma = mrow[(size_t)hh2 * TP + irow[r]];        la = lsum[(size_t)hh2 * TP + irow[r]];
      mb = mrow[(size_t)(16 + hh2) * TP + irow[r]]; lb = lsum[(size_t)(16 + hh2) * TP + irow[r]];
      m = fmaxf(ma, mb);
      m2[r] = m; li2[r] = 1.f / (la * __expf(ma - m) + lb * __expf(mb - m));
    } else { m1[r] = 0.f; li1[r] = 0.f; m2[r] = 0.f; li2[r] = 0.f; }
  }
  f32x4 accpv[4] = {};
  for (int jt = jt0; jt < jt1; jt++) {
    __syncthreads();            // prior iter's Ps/Bv reads done
#pragma unroll
    for (int i = 0; i < 2; i++) {
      int vecIdx = tid + i * 256;
      int row = vecIdx >> 3, cg = vecIdx & 7;
      u16x8 v1 = {0, 0, 0, 0, 0, 0, 0, 0}, v2 = v1, vv = v1;
      int gj = jt * 64 + row;
      if (gj < Tn && cg < 6) {
        v1 = *reinterpret_cast<const u16x8*>(khb + (size_t)gj * 768 + hh1 * 48 + cg * 8);
        v2 = *reinterpret_cast<const u16x8*>(khb + (size_t)gj * 768 + hh2 * 48 + cg * 8);
      }
      int jc = jt * 64 + cg * 8;
      if (jc + 8 <= Tn)
        vv = *reinterpret_cast<const u16x8*>(vt + (size_t)row * Tn + jc);
      *reinterpret_cast<u16x8*>(&K1s[row][cg * 8]) = v1;
      *reinterpret_cast<u16x8*>(&K2s[row][cg * 8]) = v2;
      *reinterpret_cast<u16x8*>(&Bv[row][cg * 8]) = vv;
    }
    __syncthreads();
    f32x4 a1c[4] = {}, a2c[4] = {};
#pragma unroll
    for (int ks = 0; ks < 2; ks++) {
      bf16x8 af1 = *reinterpret_cast<const bf16x8*>(&Q1[wave * 16 + lrow][ks * 32 + lgrp * 8]);
      bf16x8 af2 = *reinterpret_cast<const bf16x8*>(&Q2[wave * 16 + lrow][ks * 32 + lgrp * 8]);
#pragma unroll
      for (int ni = 0; ni < 4; ni++) {
        bf16x8 b1 = *reinterpret_cast<const bf16x8*>(&K1s[ni * 16 + lrow][ks * 32 + lgrp * 8]);
        bf16x8 b2 = *reinterpret_cast<const bf16x8*>(&K2s[ni * 16 + lrow][ks * 32 + lgrp * 8]);
        a1c[ni] = __builtin_amdgcn_mfma_f32_16x16x32_bf16(af1, b1, a1c[ni], 0, 0, 0);
        a2c[ni] = __builtin_amdgcn_mfma_f32_16x16x32_bf16(af2, b2, a2c[ni], 0, 0, 0);
      }
    }
    __syncthreads();            // all K1s reads done before Ps (alias) writes
    float cs[4];
#pragma unroll
    for (int ni = 0; ni < 4; ni++) cs[ni] = 0.f;
#pragma unroll
    for (int ni = 0; ni < 4; ni++) {
      int j = jt * 64 + ni * 16 + lrow;
      int jmod = j % LPn;
      bool jok = (j < Tn);
#pragma unroll
      for (int r = 0; r < 4; r++) {
        int imod = irow[r] % LPn;
        bool masked = (!jok) || (jmod > imod);
        float sv1 = masked ? -1e9f : a1c[ni][r] * SCALING_C;
        float sv2 = masked ? -1e9f : a2c[ni][r] * SCALING_C;
        float a1 = __expf(sv1 - m1[r]) * li1[r];
        float a2 = __expf(sv2 - m2[r]) * li2[r];
        float c = fmaf(-lam, a2, a1);
        Ps[wave * 16 + lgrp * 4 + r][ni * 16 + lrow] = f2bu(c);
        cs[ni] += a1;
      }
    }
#pragma unroll
    for (int ni = 0; ni < 4; ni++) {
      cs[ni] += __shfl_xor(cs[ni], 16);
      cs[ni] += __shfl_xor(cs[ni], 32);
    }
    {
      float mine = (lgrp == 0) ? cs[0] : (lgrp == 1) ? cs[1] : (lgrp == 2) ? cs[2] : cs[3];
      colsum_p[((size_t)p * 132 + blockIdx.x * 4 + wave) * TP + jt * 64 + lgrp * 16 + lrow] = mine;
    }
    __syncthreads();            // Ps writes visible to all waves
#pragma unroll
    for (int ks = 0; ks < 2; ks++) {
      bf16x8 af = *reinterpret_cast<const bf16x8*>(&Ps[wave * 16 + lrow][ks * 32 + lgrp * 8]);
#pragma unroll
      for (int ni = 0; ni < 4; ni++) {
        bf16x8 bfr = *reinterpret_cast<const bf16x8*>(&Bv[ni * 16 + lrow][ks * 32 + lgrp * 8]);
        accpv[ni] = __builtin_amdgcn_mfma_f32_16x16x32_bf16(af, bfr, accpv[ni], 0, 0, 0);
      }
    }
  }
#pragma unroll
  for (int ni = 0; ni < 4; ni++)
#pragma unroll
    for (int r = 0; r < 4; r++) {
      int row = bm + wave * 16 + lgrp * 4 + r;
      int col = ni * 16 + lrow;
      if (row < Tn) opv[((size_t)(hf * 8 + p) * Tn + row) * 64 + col] = accpv[ni][r];
    }
}

// ---------------- batched gwv: W[p][jmod][dv] ----------------
__global__ __launch_bounds__(64) void k_gwv(const float* __restrict__ colsum_p,
                                            const __hip_bfloat16* __restrict__ vtb,
                                            const float* __restrict__ lamp,
                                            float* __restrict__ Wb) {
  int jmod = blockIdx.x, p = blockIdx.y;
  int l = threadIdx.x;
  int k = l >> 3, sub = l & 7;
  int jk = jmod + 257 * k;
  float s = 0.f;
  for (int ib = sub; ib < 132; ib += 8) s += colsum_p[((size_t)p * 132 + ib) * TP + jk];
  for (int m = 1; m < 8; m <<= 1) s += __shfl_xor(s, m);
  float gv = s * (1.f / (float)Tn) * lamp[0];
  const __hip_bfloat16* vrow = vtb + (size_t)(p * 64 + l) * Tn;
  float acc = 0.f;
#pragma unroll
  for (int kk = 0; kk < 8; kk++) {
    float gk = __shfl(gv, kk * 8);
    acc = fmaf(gk, __bfloat162float(vrow[jmod + 257 * kk]), acc);
  }
  Wb[((size_t)p * 257 + jmod) * 64 + l] = acc;
}

// ---------------- batched chunksum ----------------
__global__ __launch_bounds__(64) void k_chunksum(const float* __restrict__ Wb,
                                                 float* __restrict__ Cb) {
  int c = blockIdx.x, p = blockIdx.y;
  int lane = threadIdx.x;
  int m0 = c * 16, m1 = min(m0 + 16, LPn);
  float acc = 0.f;
  for (int m = m0; m < m1; m++) acc += Wb[((size_t)p * 257 + m) * 64 + lane];
  Cb[((size_t)p * 17 + c) * 64 + lane] = acc;
}

// ---------------- pv_out: sum 4 opv halves + G-prefix + head-RMSNorm -> bf16 ----------------
__global__ __launch_bounds__(256) void k_pv_out(const float* __restrict__ opv,
                                                const float* __restrict__ Wb,
                                                const float* __restrict__ Cb,
                                                const float* __restrict__ hnw,
                                                __hip_bfloat16* __restrict__ onormb) {
  int w = threadIdx.x >> 6, lane = threadIdx.x & 63;
  int i = blockIdx.x * 4 + w;
  int p = blockIdx.y;
  int imod = i % LPn;
  int cidx = imod >> 4;
  float s = 0.f;
#pragma unroll
  for (int hf = 0; hf < 4; hf++) s += opv[((size_t)(hf * 8 + p) * Tn + i) * 64 + lane];
  for (int c = 0; c < cidx; c++) s += Cb[((size_t)p * 17 + c) * 64 + lane];
  for (int m = cidx * 16; m <= imod; m++) s += Wb[((size_t)p * 257 + m) * 64 + lane];
  float ss = s * s;
  for (int off = 1; off < 64; off <<= 1) ss += __shfl_xor(ss, off);
  float scale = rsqrtf(ss * (1.f / 64.f) + 1e-5f);
  onormb[((size_t)p * Tn + i) * 64 + lane] = __float2bfloat16(s * scale * hnw[lane]);
}

// ---------------- final head (float32 out) ----------------
__global__ __launch_bounds__(192) void k_final(const float* __restrict__ z,
                                               const float* __restrict__ outW,
                                               float* __restrict__ out) {
  int t = blockIdx.x;
  int p = threadIdx.x >> 6, lane = threadIdx.x & 63;
  float acc = 0.f;
  for (int m = lane; m < 512; m += 64) acc = fmaf(z[(size_t)t * 512 + m], outW[(size_t)p * 512 + m], acc);
  for (int off = 1; off < 64; off <<= 1) acc += __shfl_xor(acc, off);
  if (lane == 0) out[(size_t)t * 3 + p] = acc;
}

extern "C" void kernel_launch(void* const* d_in, const int* in_sizes, int n_in,
                              void* d_out, int out_size, void* d_ws, size_t ws_size,
                              hipStream_t stream) {
  const float* x          = (const float*)d_in[0];
  const float* ticker_emb = (const float*)d_in[1];
  const float* sep_emb    = (const float*)d_in[2];
  const float* shared_W   = (const float*)d_in[3];
  const float* unique_W   = (const float*)d_in[4];
  const float* norm1_w    = (const float*)d_in[5];
  const float* norm2_w    = (const float*)d_in[6];
  const float* kv_down_W  = (const float*)d_in[7];
  const float* q_down_W   = (const float*)d_in[8];
  const float* kv_up_W    = (const float*)d_in[9];
  const float* q_up_W     = (const float*)d_in[10];
  const float* kv_norm_w  = (const float*)d_in[11];
  const float* q_norm_w   = (const float*)d_in[12];
  const float* o_W        = (const float*)d_in[13];
  const float* lam_q1     = (const float*)d_in[14];
  const float* lam_k1     = (const float*)d_in[15];
  const float* lam_q2     = (const float*)d_in[16];
  const float* lam_k2     = (const float*)d_in[17];
  const float* head_norm_w= (const float*)d_in[18];
  const float* ff_in_W    = (const float*)d_in[19];
  const float* ff_out_W   = (const float*)d_in[20];
  const float* final_norm = (const float*)d_in[21];
  const float* out_W      = (const float*)d_in[22];
  const int*   seperator  = (const int*)d_in[23];
  const int*   tickers    = (const int*)d_in[24];
  (void)in_sizes; (void)n_in;

  float* W = (float*)d_ws;
  size_t off = 0;
  auto alloc = [&](size_t n) { float* p = W + off; off += n; return p; };
  float* cosb  = alloc(2048);
  float* sinb  = alloc(2048);
  float* h     = alloc((size_t)Tn * Dn);
  float* xnb_f = alloc((size_t)Tn * 256);         // bf16 T x 512 (also z)
  float* ckv   = alloc((size_t)Tn * 160);         // ckv+qlat host onormb later
  float* qlat  = alloc((size_t)Tn * 192);
  float* ckvnb_f = alloc((size_t)Tn * 64);        // bf16 T x 128
  float* qlatnb_f = alloc((size_t)Tn * 96);       // bf16 T x 192
  float* kvb   = alloc((size_t)Tn * 1024);        // gatedb overlay
  float* qf    = alloc((size_t)Tn * 768);         // zfin overlay
  float* qhb_f = alloc((size_t)Tn * 384);         // bf16 T x 768
  float* khb_f = alloc((size_t)Tn * 384);         // bf16 T x 768
  float* vtb_f = alloc((size_t)Tn * 256);         // bf16 512 x T
  float* mrow  = alloc((size_t)32 * TP);          // [hf][16][TP]
  float* lsumb = alloc((size_t)32 * TP);
  float* lam   = alloc(4);
  float* colsum_p = alloc((size_t)8 * 132 * TP);
  float* Wb    = alloc((size_t)8 * 257 * 64);
  float* Cb    = alloc((size_t)8 * 17 * 64);
  float* pp    = alloc((size_t)4 * Tn * 512);     // opv (4x8xTx64) / GEMM partials

  __hip_bfloat16* xnb    = (__hip_bfloat16*)xnb_f;
  __hip_bfloat16* ckvnb  = (__hip_bfloat16*)ckvnb_f;
  __hip_bfloat16* qlatnb = (__hip_bfloat16*)qlatnb_f;
  __hip_bfloat16* onormb = (__hip_bfloat16*)ckv;     // bf16 T x 512 over ckv+qlat
  __hip_bfloat16* gatedb = (__hip_bfloat16*)kvb;     // bf16 T x 2048
  __hip_bfloat16* qhb    = (__hip_bfloat16*)qhb_f;
  __hip_bfloat16* khb    = (__hip_bfloat16*)khb_f;
  __hip_bfloat16* vtb    = (__hip_bfloat16*)vtb_f;
  float* opv   = pp;         // 4x8xTx64 f32 == 4xTx512 f32 exactly (disjoint lifetime)
  float* zfin  = qf;

  size_t needed = off * sizeof(float);            // ~60.8 MB (< 79.5 proven)
  if (ws_size < needed) {
    k_fill42<<<(out_size + 255) / 256, 256, 0, stream>>>((float*)d_out, out_size);
    return;
  }

  k_freqs<<<8, 256, 0, stream>>>(cosb, sinb);
  k_embed<<<dim3(Tn, 2), 256, 0, stream>>>(x, ticker_emb, sep_emb, shared_W, unique_W,
                                           seperator, tickers, h);

  for (int d = 0; d < 2; d++) {
    const float* n1   = norm1_w + d * 512;
    const float* n2   = norm2_w + d * 512;
    const float* kvd  = kv_down_W + (size_t)d * 160 * 512;
    const float* qd   = q_down_W + (size_t)d * 192 * 512;
    const float* kvu  = kv_up_W + (size_t)d * 1024 * 128;
    const float* qu   = q_up_W + (size_t)d * 768 * 192;
    const float* kvnw = kv_norm_w + d * 128;
    const float* qnw  = q_norm_w + d * 192;
    const float* oW   = o_W + (size_t)d * 512 * 512;
    const float* hnw  = head_norm_w + d * 64;
    const float* ffi  = ff_in_W + (size_t)d * 4096 * 512;
    const float* ffo  = ff_out_W + (size_t)d * 512 * 2048;
    float lamc = 0.8f - 0.6f * expf(-0.3f * (float)d);

    k_rmsnorm_b<<<Tn, 256, 0, stream>>>(h, n1, xnb, 512, 512, EPS_C);
    k_gemm64<0><<<dim3(3, 33), 256, 0, stream>>>(xnb, kvd, ckv, Tn, 160, 512);
    k_rmsnorm_b<<<Tn, 256, 0, stream>>>(ckv, kvnw, ckvnb, 128, 160, EPS_C);
    k_gemm64<0><<<dim3(16, 33), 256, 0, stream>>>(ckvnb, kvu, kvb, Tn, 1024, 128);
    k_gemm64<0><<<dim3(3, 33), 256, 0, stream>>>(xnb, qd, qlat, Tn, 192, 512);
    k_rmsnorm_b<<<Tn, 256, 0, stream>>>(qlat, qnw, qlatnb, 192, 192, EPS_C);
    k_gemm64<0><<<dim3(12, 33), 256, 0, stream>>>(qlatnb, qu, qf, Tn, 768, 192);
    k_qkv<<<Tn, 256, 0, stream>>>(qf, kvb, ckv, cosb, sinb, qhb, khb);
    k_vtrans<<<dim3(33, 8), 256, 0, stream>>>(kvb, vtb);
    k_lam<<<1, 1, 0, stream>>>(lam_q1 + d * 32, lam_k1 + d * 32,
                               lam_q2 + d * 32, lam_k2 + d * 32, lamc, lam);

    k_attn_pass1<<<dim3(33, 16, 2), 256, 0, stream>>>(qhb, khb, mrow, lsumb);
    k_attn_pass2<<<dim3(33, 8, 4), 256, 0, stream>>>(qhb, khb, vtb, mrow, lsumb, lam,
                                                     opv, colsum_p);
    k_gwv<<<dim3(257, 8), 64, 0, stream>>>(colsum_p, vtb, lam, Wb);
    k_chunksum<<<dim3(17, 8), 64, 0, stream>>>(Wb, Cb);
    k_pv_out<<<dim3(514, 8), 256, 0, stream>>>(opv, Wb, Cb, hnw, onormb);

    // o-proj: K=512 split x2 -> partials -> h +=   (pp free: opv consumed above)
    k_gemm64p<<<dim3(8, 33, 2), 256, 0, stream>>>(onormb, oW, pp, Tn, 512, 256);
    k_addred<<<(Tn * 512 + 255) / 256, 256, 0, stream>>>(h, pp, (long)Tn * 512, 2);
    k_rmsnorm_b<<<Tn, 256, 0, stream>>>(h, n2, xnb, 512, 512, EPS_C);
    k_ffn<<<dim3(32, 17), 256, 0, stream>>>(xnb, ffi, gatedb);
    // ffo: K=2048 split x4 -> partials -> h +=
    k_gemm64p<<<dim3(8, 33, 4), 256, 0, stream>>>(gatedb, ffo, pp, Tn, 512, 512);
    k_addred<<<(Tn * 512 + 255) / 256, 256, 0, stream>>>(h, pp, (long)Tn * 512, 4);
  }

  k_rmsnorm<<<Tn, 256, 0, stream>>>(h, final_norm, zfin, 512, 512, EPS_C);
  k_final<<<Tn, 192, 0, stream>>>(zfin, out_W, (float*)d_out);
}

// Round 15
// 617.396 us; speedup vs baseline: 15.7825x; 1.0205x over previous
//
#include <hip/hip_runtime.h>
#include <hip/hip_bf16.h>

// Money_former MLA DINT — round 15: mask-aware tile skipping (~25% of j-tiles
// fully masked -> skip staging/MFMA/exp in both passes), pass1 pair-merged +
// jt-split x4 (m/l in 4 parts), o-proj addred+rmsnorm fused.
// T=2056, D=512, 2 layers, 16 logical heads (8 pairs) of 48.

#define Tn 2056
#define LPn 257
#define Dn 512
#define TP 2112   // padded T (33*64)

static constexpr float SCALING_C = 0.14433756729740643f;   // 48^-0.5
static constexpr float EPS_C     = 1.1920928955078125e-07f;

typedef float f32x4 __attribute__((ext_vector_type(4)));
typedef short bf16x8 __attribute__((ext_vector_type(8)));
typedef unsigned short u16x8 __attribute__((ext_vector_type(8)));

__device__ __forceinline__ unsigned short f2bu(float f) {
  __hip_bfloat16 h = __float2bfloat16(f);
  return *reinterpret_cast<unsigned short*>(&h);
}

// fully-masked (i-block, j-tile) test: 64-run mod 257 min/max
__device__ __forceinline__ bool tile_masked(int bm, int jt) {
  int jstart = (jt * 64) % LPn;
  int jmin = (jstart + 63 >= LPn) ? 0 : jstart;
  int istart = bm % LPn;
  int imax = (istart + 63 >= LPn) ? (LPn - 1) : (istart + 63);
  return jmin > imax;
}

// ---------------- sentinel ----------------
__global__ __launch_bounds__(256) void k_fill42(float* __restrict__ out, int n) {
  int i = blockIdx.x * 256 + threadIdx.x;
  if (i < n) out[i] = 42.0f;
}

// ---------------- RoPE tables ----------------
__global__ __launch_bounds__(256) void k_freqs(float* __restrict__ cosb, float* __restrict__ sinb) {
  int idx = blockIdx.x * 256 + threadIdx.x;
  if (idx >= 256 * 8) return;
  int pos = idx >> 3, j = idx & 7;
  float fb = powf(10000.f, -(float)j * 0.125f);            // 1/10000^(j/8)
  float ramp = fminf(fmaxf((float)j * 0.25f, 0.f), 1.f);   // low=0, high=4
  float sm = 1.f - ramp;
  float fr = fb * (1.f / 40.f) * (1.f - sm) + fb * sm;
  float ang = (float)pos * fr;
  cosb[idx] = cosf(ang);
  sinb[idx] = sinf(ang);
}

// ---------------- Embedding ----------------
__global__ __launch_bounds__(256) void k_embed(const float* __restrict__ x,
                                               const float* __restrict__ ticker_emb,
                                               const float* __restrict__ sep_emb,
                                               const float* __restrict__ shared_W,
                                               const float* __restrict__ unique_W,
                                               const int* __restrict__ sep_idx,
                                               const int* __restrict__ tickers,
                                               float* __restrict__ h) {
  int t = blockIdx.x;
  int c = blockIdx.y * 256 + threadIdx.x;
  int l = t >> 3, s = t & 7;
  float val;
  if (l == 0) {
    val = sep_emb[sep_idx[0] * Dn + c];
  } else {
    const float* xr = x + ((size_t)(l - 1) * 8 + s) * 32;
    const float* w = (c < 384) ? (shared_W + (size_t)c * 32)
                               : (unique_W + ((size_t)s * 128 + (c - 384)) * 32);
    float acc = 0.f;
#pragma unroll
    for (int f = 0; f < 32; f++) acc = fmaf(xr[f], w[f], acc);
    val = acc;
  }
  val += ticker_emb[(size_t)tickers[s] * Dn + c];
  h[(size_t)t * Dn + c] = val;
}

// ---------------- Row RMSNorm, f32 out ----------------
__global__ __launch_bounds__(256) void k_rmsnorm(const float* __restrict__ in,
                                                 const float* __restrict__ w,
                                                 float* __restrict__ out,
                                                 int ncols, int in_stride, float eps) {
  int row = blockIdx.x;
  const float* xr = in + (size_t)row * in_stride;
  float ss = 0.f;
  for (int c = threadIdx.x; c < ncols; c += 256) { float v = xr[c]; ss = fmaf(v, v, ss); }
  for (int off = 1; off < 64; off <<= 1) ss += __shfl_xor(ss, off);
  __shared__ float red[4];
  if ((threadIdx.x & 63) == 0) red[threadIdx.x >> 6] = ss;
  __syncthreads();
  float tot = red[0] + red[1] + red[2] + red[3];
  float scale = rsqrtf(tot / (float)ncols + eps);
  for (int c = threadIdx.x; c < ncols; c += 256)
    out[(size_t)row * ncols + c] = xr[c] * scale * w[c];
}

// ---------------- Row RMSNorm, bf16 out ----------------
__global__ __launch_bounds__(256) void k_rmsnorm_b(const float* __restrict__ in,
                                                   const float* __restrict__ w,
                                                   __hip_bfloat16* __restrict__ out,
                                                   int ncols, int in_stride, float eps) {
  int row = blockIdx.x;
  const float* xr = in + (size_t)row * in_stride;
  float ss = 0.f;
  for (int c = threadIdx.x; c < ncols; c += 256) { float v = xr[c]; ss = fmaf(v, v, ss); }
  for (int off = 1; off < 64; off <<= 1) ss += __shfl_xor(ss, off);
  __shared__ float red[4];
  if ((threadIdx.x & 63) == 0) red[threadIdx.x >> 6] = ss;
  __syncthreads();
  float tot = red[0] + red[1] + red[2] + red[3];
  float scale = rsqrtf(tot / (float)ncols + eps);
  for (int c = threadIdx.x; c < ncols; c += 256)
    out[(size_t)row * ncols + c] = __float2bfloat16(xr[c] * scale * w[c]);
}

// ---------------- fused: h += sum(pp parts) ; xnb = rmsnorm(h)*w (bf16) ----------------
// grid Tn, block 256 (2 cols per thread over 512).
__global__ __launch_bounds__(256) void k_addred_rms_b(float* __restrict__ h,
                                                      const float* __restrict__ pp,
                                                      const float* __restrict__ w,
                                                      __hip_bfloat16* __restrict__ out,
                                                      int nsplit) {
  int row = blockIdx.x;
  long n = (long)Tn * 512;
  float v[2];
  float ss = 0.f;
#pragma unroll
  for (int cc = 0; cc < 2; cc++) {
    int c = threadIdx.x + cc * 256;
    long idx = (long)row * 512 + c;
    float s = h[idx];
    for (int k = 0; k < nsplit; k++) s += pp[(size_t)k * n + idx];
    h[idx] = s;
    v[cc] = s;
    ss = fmaf(s, s, ss);
  }
  for (int off = 1; off < 64; off <<= 1) ss += __shfl_xor(ss, off);
  __shared__ float red[4];
  if ((threadIdx.x & 63) == 0) red[threadIdx.x >> 6] = ss;
  __syncthreads();
  float tot = red[0] + red[1] + red[2] + red[3];
  float scale = rsqrtf(tot * (1.f / 512.f) + EPS_C);
#pragma unroll
  for (int cc = 0; cc < 2; cc++) {
    int c = threadIdx.x + cc * 256;
    out[(size_t)row * 512 + c] = __float2bfloat16(v[cc] * scale * w[c]);
  }
}

// ---------------- 64x64 MFMA GEMM: C (+)= A[M,K]bf16 @ (B[N,K]f32)^T ----------------
template <int MODE>
__global__ __launch_bounds__(256) void k_gemm64(const __hip_bfloat16* __restrict__ A,
                                                const float* __restrict__ B,
                                                float* __restrict__ C,
                                                int M, int N, int K) {
  __shared__ unsigned short Als[64][40];
  __shared__ unsigned short Bls[64][40];
  int bm = blockIdx.y * 64, bn = blockIdx.x * 64;
  int tid = threadIdx.x;
  int wave = tid >> 6, lane = tid & 63;
  int lrow = lane & 15, lgrp = lane >> 4;
  f32x4 acc[4] = {};
  for (int k0 = 0; k0 < K; k0 += 32) {
    {
      int row = tid >> 2, cg = tid & 3;
      u16x8 v = {0, 0, 0, 0, 0, 0, 0, 0};
      if (bm + row < M)
        v = *reinterpret_cast<const u16x8*>(A + (size_t)(bm + row) * K + k0 + cg * 8);
      *reinterpret_cast<u16x8*>(&Als[row][cg * 8]) = v;
    }
    {
      int row = tid >> 2, cg = tid & 3;
      u16x8 v = {0, 0, 0, 0, 0, 0, 0, 0};
      if (bn + row < N) {
        const float* bp = B + (size_t)(bn + row) * K + k0 + cg * 8;
        f32x4 b0 = *reinterpret_cast<const f32x4*>(bp);
        f32x4 b1 = *reinterpret_cast<const f32x4*>(bp + 4);
#pragma unroll
        for (int e = 0; e < 4; e++) { v[e] = f2bu(b0[e]); v[e + 4] = f2bu(b1[e]); }
      }
      *reinterpret_cast<u16x8*>(&Bls[row][cg * 8]) = v;
    }
    __syncthreads();
    bf16x8 af = *reinterpret_cast<const bf16x8*>(&Als[wave * 16 + lrow][lgrp * 8]);
    bf16x8 bfr[4];
#pragma unroll
    for (int ni = 0; ni < 4; ni++)
      bfr[ni] = *reinterpret_cast<const bf16x8*>(&Bls[ni * 16 + lrow][lgrp * 8]);
#pragma unroll
    for (int ni = 0; ni < 4; ni++)
      acc[ni] = __builtin_amdgcn_mfma_f32_16x16x32_bf16(af, bfr[ni], acc[ni], 0, 0, 0);
    __syncthreads();
  }
#pragma unroll
  for (int ni = 0; ni < 4; ni++)
#pragma unroll
    for (int r = 0; r < 4; r++) {
      int row = bm + wave * 16 + lgrp * 4 + r;
      int col = bn + ni * 16 + lrow;
      if (row < M && col < N) {
        if (MODE) C[(size_t)row * N + col] += acc[ni][r];
        else      C[(size_t)row * N + col] = acc[ni][r];
      }
    }
}

// ---------------- K-split 64x64 MFMA GEMM -> partial buffer pp[kc] ----------------
__global__ __launch_bounds__(256) void k_gemm64p(const __hip_bfloat16* __restrict__ A,
                                                 const float* __restrict__ B,
                                                 float* __restrict__ pp,
                                                 int M, int N, int kchunk) {
  __shared__ unsigned short Als[64][40];
  __shared__ unsigned short Bls[64][40];
  int bm = blockIdx.y * 64, bn = blockIdx.x * 64;
  int kc = blockIdx.z;
  int K = kchunk * gridDim.z;
  int kbase = kc * kchunk;
  int tid = threadIdx.x;
  int wave = tid >> 6, lane = tid & 63;
  int lrow = lane & 15, lgrp = lane >> 4;
  f32x4 acc[4] = {};
  for (int k0 = kbase; k0 < kbase + kchunk; k0 += 32) {
    {
      int row = tid >> 2, cg = tid & 3;
      u16x8 v = {0, 0, 0, 0, 0, 0, 0, 0};
      if (bm + row < M)
        v = *reinterpret_cast<const u16x8*>(A + (size_t)(bm + row) * K + k0 + cg * 8);
      *reinterpret_cast<u16x8*>(&Als[row][cg * 8]) = v;
    }
    {
      int row = tid >> 2, cg = tid & 3;
      u16x8 v = {0, 0, 0, 0, 0, 0, 0, 0};
      if (bn + row < N) {
        const float* bp = B + (size_t)(bn + row) * K + k0 + cg * 8;
        f32x4 b0 = *reinterpret_cast<const f32x4*>(bp);
        f32x4 b1 = *reinterpret_cast<const f32x4*>(bp + 4);
#pragma unroll
        for (int e = 0; e < 4; e++) { v[e] = f2bu(b0[e]); v[e + 4] = f2bu(b1[e]); }
      }
      *reinterpret_cast<u16x8*>(&Bls[row][cg * 8]) = v;
    }
    __syncthreads();
    bf16x8 af = *reinterpret_cast<const bf16x8*>(&Als[wave * 16 + lrow][lgrp * 8]);
    bf16x8 bfr[4];
#pragma unroll
    for (int ni = 0; ni < 4; ni++)
      bfr[ni] = *reinterpret_cast<const bf16x8*>(&Bls[ni * 16 + lrow][lgrp * 8]);
#pragma unroll
    for (int ni = 0; ni < 4; ni++)
      acc[ni] = __builtin_amdgcn_mfma_f32_16x16x32_bf16(af, bfr[ni], acc[ni], 0, 0, 0);
    __syncthreads();
  }
#pragma unroll
  for (int ni = 0; ni < 4; ni++)
#pragma unroll
    for (int r = 0; r < 4; r++) {
      int row = bm + wave * 16 + lgrp * 4 + r;
      int col = bn + ni * 16 + lrow;
      if (row < M && col < N)
        pp[(size_t)kc * M * N + (size_t)row * N + col] = acc[ni][r];
    }
}

// ---------------- C += sum of nsplit partials ----------------
__global__ __launch_bounds__(256) void k_addred(float* __restrict__ C,
                                                const float* __restrict__ pp,
                                                long n, int nsplit) {
  long i = (long)blockIdx.x * 256 + threadIdx.x;
  if (i >= n) return;
  float s = 0.f;
  for (int k = 0; k < nsplit; k++) s += pp[(size_t)k * n + i];
  C[i] += s;
}

// ---------------- Fused FFN-in + SwiGLU ----------------
__global__ __launch_bounds__(256) void k_ffn(const __hip_bfloat16* __restrict__ A,
                                             const float* __restrict__ Bw,
                                             __hip_bfloat16* __restrict__ gatedb) {
  __shared__ unsigned short Als[128][40];
  __shared__ unsigned short Bls[128][40];
  int bm = blockIdx.y * 128, bn = blockIdx.x * 64;
  int tid = threadIdx.x;
  int wave = tid >> 6, lane = tid & 63;
  int lrow = lane & 15, lgrp = lane >> 4;
  f32x4 acc[2][8] = {};
  for (int k0 = 0; k0 < 512; k0 += 32) {
#pragma unroll
    for (int i = 0; i < 2; i++) {
      int vecIdx = tid + i * 256;
      int row = vecIdx >> 2, cg = vecIdx & 3;
      u16x8 v = {0, 0, 0, 0, 0, 0, 0, 0};
      if (bm + row < Tn)
        v = *reinterpret_cast<const u16x8*>(A + (size_t)(bm + row) * 512 + k0 + cg * 8);
      *reinterpret_cast<u16x8*>(&Als[row][cg * 8]) = v;
    }
#pragma unroll
    for (int i = 0; i < 2; i++) {
      int vecIdx = tid + i * 256;
      int row = vecIdx >> 2, cg = vecIdx & 3;
      int grow = (row < 64) ? (bn + row) : (2048 + bn + (row - 64));
      const float* bp = Bw + (size_t)grow * 512 + k0 + cg * 8;
      f32x4 b0 = *reinterpret_cast<const f32x4*>(bp);
      f32x4 b1 = *reinterpret_cast<const f32x4*>(bp + 4);
      u16x8 v;
#pragma unroll
      for (int e = 0; e < 4; e++) { v[e] = f2bu(b0[e]); v[e + 4] = f2bu(b1[e]); }
      *reinterpret_cast<u16x8*>(&Bls[row][cg * 8]) = v;
    }
    __syncthreads();
    bf16x8 af[2], bfr[8];
#pragma unroll
    for (int mi = 0; mi < 2; mi++)
      af[mi] = *reinterpret_cast<const bf16x8*>(&Als[wave * 32 + mi * 16 + lrow][lgrp * 8]);
#pragma unroll
    for (int ni = 0; ni < 8; ni++)
      bfr[ni] = *reinterpret_cast<const bf16x8*>(&Bls[ni * 16 + lrow][lgrp * 8]);
#pragma unroll
    for (int mi = 0; mi < 2; mi++)
#pragma unroll
      for (int ni = 0; ni < 8; ni++)
        acc[mi][ni] = __builtin_amdgcn_mfma_f32_16x16x32_bf16(af[mi], bfr[ni], acc[mi][ni], 0, 0, 0);
    __syncthreads();
  }
#pragma unroll
  for (int mi = 0; mi < 2; mi++)
#pragma unroll
    for (int ni = 0; ni < 4; ni++)
#pragma unroll
      for (int r = 0; r < 4; r++) {
        int row = bm + wave * 32 + mi * 16 + lgrp * 4 + r;
        int col = bn + ni * 16 + lrow;
        if (row < Tn) {
          float u = acc[mi][ni][r];
          float vv = acc[mi][ni + 4][r];
          float sv = vv / (1.f + __expf(-vv));
          gatedb[(size_t)row * 2048 + col] = __float2bfloat16(u * sv);
        }
      }
}

// ---------------- Assemble q/k (partial RoPE, bf16 out) ----------------
__global__ __launch_bounds__(256) void k_qkv(const float* __restrict__ qf,
                                             const float* __restrict__ kvb,
                                             const float* __restrict__ ckv,
                                             const float* __restrict__ cosb,
                                             const float* __restrict__ sinb,
                                             __hip_bfloat16* __restrict__ qhb,
                                             __hip_bfloat16* __restrict__ khb) {
  int t = blockIdx.x;
  int l = t >> 3;
  for (int idx = threadIdx.x; idx < 768; idx += 256) {
    int hh = idx / 48, dc = idx % 48;
    int hd = hh >> 1, e = hh & 1;
    float qv, kvv;
    if (dc < 32) {
      qv  = qf [(size_t)t * 768  + hd * 96  + e * 32 + dc];
      kvv = kvb[(size_t)t * 1024 + hd * 128 + e * 32 + dc];
    } else {
      int rj = dc - 32;            // 0..15
      int p = rj >> 1; int isim = rj & 1;
      float xr_q = qf[(size_t)t * 768 + hd * 96 + 64 + e * 16 + p * 2];
      float xi_q = qf[(size_t)t * 768 + hd * 96 + 64 + e * 16 + p * 2 + 1];
      float xr_k = ckv[(size_t)t * 160 + 128 + e * 16 + p * 2];
      float xi_k = ckv[(size_t)t * 160 + 128 + e * 16 + p * 2 + 1];
      if (l == 0) {
        qv  = isim ? xi_q : xr_q;
        kvv = isim ? xi_k : xr_k;
      } else {
        float c = cosb[(l - 1) * 8 + p], s = sinb[(l - 1) * 8 + p];
        if (!isim) { qv = xr_q * c - xi_q * s; kvv = xr_k * c - xi_k * s; }
        else       { qv = xr_q * s + xi_q * c; kvv = xr_k * s + xi_k * c; }
      }
    }
    qhb[(size_t)t * 768 + idx] = __float2bfloat16(qv);
    khb[(size_t)t * 768 + idx] = __float2bfloat16(kvv);
  }
}

// ---------------- V transpose: vtb[c][t] bf16 ----------------
__global__ __launch_bounds__(256) void k_vtrans(const float* __restrict__ kvb,
                                                __hip_bfloat16* __restrict__ vtb) {
  __shared__ float tile[64][65];
  int tt = blockIdx.x, ct = blockIdx.y;    // (33, 8)
  int tid = threadIdx.x;
#pragma unroll
  for (int rep = 0; rep < 16; rep++) {
    int idx = rep * 256 + tid;
    int tr = idx >> 6, cc = idx & 63;
    int t = tt * 64 + tr;
    tile[tr][cc] = (t < Tn) ? kvb[(size_t)t * 1024 + ct * 128 + 64 + cc] : 0.f;
  }
  __syncthreads();
#pragma unroll
  for (int rep = 0; rep < 16; rep++) {
    int idx = rep * 256 + tid;
    int cr = idx >> 6, tc = idx & 63;
    int t = tt * 64 + tc;
    if (t < Tn)
      vtb[(size_t)(ct * 64 + cr) * Tn + t] = __float2bfloat16(tile[tc][cr]);
  }
}

// ---------------- lambda scalar ----------------
__global__ void k_lam(const float* __restrict__ lq1, const float* __restrict__ lk1,
                      const float* __restrict__ lq2, const float* __restrict__ lk2,
                      float lamc, float* __restrict__ out) {
  float d1 = 0.f, d2 = 0.f;
  for (int k = 0; k < 32; k++) { d1 = fmaf(lq1[k], lk1[k], d1); d2 = fmaf(lq2[k], lk2[k], d2); }
  out[0] = expf(d1) - expf(d2) + lamc;
}

// ---------------- attention pass 1 (pair-merged, jt-split x4, tile-skip) ----------------
// grid (33, 8, 4). Writes m/l for heads 2p,2p+1 at slot (hf*16 + hh).
__global__ __launch_bounds__(256) void k_attn_pass1(const __hip_bfloat16* __restrict__ qhb,
                                                    const __hip_bfloat16* __restrict__ khb,
                                                    float* __restrict__ mrow,
                                                    float* __restrict__ lsum) {
  __shared__ unsigned short Q1[64][68];
  __shared__ unsigned short Q2[64][68];
  __shared__ unsigned short K1s[64][68];
  __shared__ unsigned short K2s[64][68];
  int bm = blockIdx.x * 64, p = blockIdx.y, hf = blockIdx.z;
  int jt0 = hf * 9, jt1 = min(33, jt0 + 9);
  int hh1 = 2 * p, hh2 = 2 * p + 1;
  int tid = threadIdx.x;
  int wave = tid >> 6, lane = tid & 63;
  int lrow = lane & 15, lgrp = lane >> 4;
#pragma unroll
  for (int i = 0; i < 2; i++) {
    int vecIdx = tid + i * 256;
    int row = vecIdx >> 3, cg = vecIdx & 7;
    u16x8 v1 = {0, 0, 0, 0, 0, 0, 0, 0}, v2 = v1;
    int grow = bm + row;
    if (grow < Tn && cg < 6) {
      v1 = *reinterpret_cast<const u16x8*>(qhb + (size_t)grow * 768 + hh1 * 48 + cg * 8);
      v2 = *reinterpret_cast<const u16x8*>(qhb + (size_t)grow * 768 + hh2 * 48 + cg * 8);
    }
    *reinterpret_cast<u16x8*>(&Q1[row][cg * 8]) = v1;
    *reinterpret_cast<u16x8*>(&Q2[row][cg * 8]) = v2;
  }
  float m1r[4], l1r[4], m2r[4], l2r[4];
#pragma unroll
  for (int r = 0; r < 4; r++) { m1r[r] = -3.4e38f; l1r[r] = 0.f; m2r[r] = -3.4e38f; l2r[r] = 0.f; }
  int irow[4];
#pragma unroll
  for (int r = 0; r < 4; r++) irow[r] = bm + wave * 16 + lgrp * 4 + r;

  for (int jt = jt0; jt < jt1; jt++) {
    if (tile_masked(bm, jt)) continue;      // masked tiles contribute exactly 0
    __syncthreads();
#pragma unroll
    for (int i = 0; i < 2; i++) {
      int vecIdx = tid + i * 256;
      int row = vecIdx >> 3, cg = vecIdx & 7;
      u16x8 v1 = {0, 0, 0, 0, 0, 0, 0, 0}, v2 = v1;
      int gj = jt * 64 + row;
      if (gj < Tn && cg < 6) {
        v1 = *reinterpret_cast<const u16x8*>(khb + (size_t)gj * 768 + hh1 * 48 + cg * 8);
        v2 = *reinterpret_cast<const u16x8*>(khb + (size_t)gj * 768 + hh2 * 48 + cg * 8);
      }
      *reinterpret_cast<u16x8*>(&K1s[row][cg * 8]) = v1;
      *reinterpret_cast<u16x8*>(&K2s[row][cg * 8]) = v2;
    }
    __syncthreads();
    f32x4 a1c[4] = {}, a2c[4] = {};
#pragma unroll
    for (int ks = 0; ks < 2; ks++) {
      bf16x8 af1 = *reinterpret_cast<const bf16x8*>(&Q1[wave * 16 + lrow][ks * 32 + lgrp * 8]);
      bf16x8 af2 = *reinterpret_cast<const bf16x8*>(&Q2[wave * 16 + lrow][ks * 32 + lgrp * 8]);
#pragma unroll
      for (int ni = 0; ni < 4; ni++) {
        bf16x8 b1 = *reinterpret_cast<const bf16x8*>(&K1s[ni * 16 + lrow][ks * 32 + lgrp * 8]);
        bf16x8 b2 = *reinterpret_cast<const bf16x8*>(&K2s[ni * 16 + lrow][ks * 32 + lgrp * 8]);
        a1c[ni] = __builtin_amdgcn_mfma_f32_16x16x32_bf16(af1, b1, a1c[ni], 0, 0, 0);
        a2c[ni] = __builtin_amdgcn_mfma_f32_16x16x32_bf16(af2, b2, a2c[ni], 0, 0, 0);
      }
    }
#pragma unroll
    for (int r = 0; r < 4; r++) {
      int imod = irow[r] % LPn;
      float sv1[4], sv2[4];
      float t1 = -3.4e38f, t2 = -3.4e38f;
#pragma unroll
      for (int ni = 0; ni < 4; ni++) {
        int j = jt * 64 + ni * 16 + lrow;
        bool masked = (j >= Tn) || ((j % LPn) > imod);
        sv1[ni] = masked ? -1e9f : a1c[ni][r] * SCALING_C;
        sv2[ni] = masked ? -1e9f : a2c[ni][r] * SCALING_C;
        t1 = fmaxf(t1, sv1[ni]); t2 = fmaxf(t2, sv2[ni]);
      }
      for (int mk = 1; mk < 16; mk <<= 1) {
        t1 = fmaxf(t1, __shfl_xor(t1, mk));
        t2 = fmaxf(t2, __shfl_xor(t2, mk));
      }
      float mn1 = fmaxf(m1r[r], t1), mn2 = fmaxf(m2r[r], t2);
      float p1 = 0.f, p2 = 0.f;
#pragma unroll
      for (int ni = 0; ni < 4; ni++) { p1 += __expf(sv1[ni] - mn1); p2 += __expf(sv2[ni] - mn2); }
      for (int mk = 1; mk < 16; mk <<= 1) { p1 += __shfl_xor(p1, mk); p2 += __shfl_xor(p2, mk); }
      l1r[r] = l1r[r] * __expf(m1r[r] - mn1) + p1; m1r[r] = mn1;
      l2r[r] = l2r[r] * __expf(m2r[r] - mn2) + p2; m2r[r] = mn2;
    }
  }
  if (lrow == 0) {
#pragma unroll
    for (int r = 0; r < 4; r++) {
      if (irow[r] < Tn) {
        mrow[(size_t)(hf * 16 + hh1) * TP + irow[r]] = m1r[r];
        lsum[(size_t)(hf * 16 + hh1) * TP + irow[r]] = l1r[r];
        mrow[(size_t)(hf * 16 + hh2) * TP + irow[r]] = m2r[r];
        lsum[(size_t)(hf * 16 + hh2) * TP + irow[r]] = l2r[r];
      }
    }
  }
}

// ---------------- attention pass 2 (jt-split x4, Ps aliases K1s, tile-skip) ----------------
__global__ __launch_bounds__(256) void k_attn_pass2(const __hip_bfloat16* __restrict__ qhb,
                                                    const __hip_bfloat16* __restrict__ khb,
                                                    const __hip_bfloat16* __restrict__ vtb,
                                                    const float* __restrict__ mrow,
                                                    const float* __restrict__ lsum,
                                                    const float* __restrict__ lamp,
                                                    float* __restrict__ opv,
                                                    float* __restrict__ colsum_p) {
  __shared__ unsigned short Q1[64][68];
  __shared__ unsigned short Q2[64][68];
  __shared__ unsigned short K1s[64][68];   // Ps aliases this after score MFMAs
  __shared__ unsigned short K2s[64][68];
  __shared__ unsigned short Bv[64][68];
  unsigned short (*Ps)[68] = K1s;
  int bm = blockIdx.x * 64, p = blockIdx.y, hf = blockIdx.z;
  int jt0 = hf * 9, jt1 = min(33, jt0 + 9);
  int hh1 = 2 * p, hh2 = 2 * p + 1;
  float lam = lamp[0];
  int tid = threadIdx.x;
  int wave = tid >> 6, lane = tid & 63;
  int lrow = lane & 15, lgrp = lane >> 4;
  const unsigned short* vt = (const unsigned short*)vtb + (size_t)p * 64 * Tn;
#pragma unroll
  for (int i = 0; i < 2; i++) {
    int vecIdx = tid + i * 256;
    int row = vecIdx >> 3, cg = vecIdx & 7;
    u16x8 v1 = {0, 0, 0, 0, 0, 0, 0, 0}, v2 = v1;
    int grow = bm + row;
    if (grow < Tn && cg < 6) {
      v1 = *reinterpret_cast<const u16x8*>(qhb + (size_t)grow * 768 + hh1 * 48 + cg * 8);
      v2 = *reinterpret_cast<const u16x8*>(qhb + (size_t)grow * 768 + hh2 * 48 + cg * 8);
    }
    *reinterpret_cast<u16x8*>(&Q1[row][cg * 8]) = v1;
    *reinterpret_cast<u16x8*>(&Q2[row][cg * 8]) = v2;
  }
  // merge 4 pass1 jt-quarters' (m,l)
  int irow[4]; float m1[4], li1[4], m2[4], li2[4];
#pragma unroll
  for (int r = 0; r < 4; r++) {
    irow[r] = bm + wave * 16 + lgrp * 4 + r;
    if (irow[r] < Tn) {
      float mm = -3.4e38f;
#pragma unroll
      for (int q = 0; q < 4; q++) mm = fmaxf(mm, mrow[(size_t)(q * 16 + hh1) * TP + irow[r]]);
      float ll = 0.f;
#pragma unroll
      for (int q = 0; q < 4; q++)
        ll += lsum[(size_t)(q * 16 + hh1) * TP + irow[r]] *
              __expf(mrow[(size_t)(q * 16 + hh1) * TP + irow[r]] - mm);
      m1[r] = mm; li1[r] = 1.f / ll;
      mm = -3.4e38f;
#pragma unroll
      for (int q = 0; q < 4; q++) mm = fmaxf(mm, mrow[(size_t)(q * 16 + hh2) * TP + irow[r]]);
      ll = 0.f;
#pragma unroll
      for (int q = 0; q < 4; q++)
        ll += lsum[(size_t)(q * 16 + hh2) * TP + irow[r]] *
              __expf(mrow[(size_t)(q * 16 + hh2) * TP + irow[r]] - mm);
      m2[r] = mm; li2[r] = 1.f / ll;
    } else { m1[r] = 0.f; li1[r] = 0.f; m2[r] = 0.f; li2[r] = 0.f; }
  }
  f32x4 accpv[4] = {};
  for (int jt = jt0; jt < jt1; jt++) {
    if (tile_masked(bm, jt)) {
      // P tile is exactly 0: zero the colsum slot, skip all work
      float zero = 0.f;
      colsum_p[((size_t)p * 132 + blockIdx.x * 4 + wave) * TP + jt * 64 + lgrp * 16 + lrow] = zero;
      continue;
    }
    __syncthreads();            // prior iter's Ps/Bv reads done
#pragma unroll
    for (int i = 0; i < 2; i++) {
      int vecIdx = tid + i * 256;
      int row = vecIdx >> 3, cg = vecIdx & 7;
      u16x8 v1 = {0, 0, 0, 0, 0, 0, 0, 0}, v2 = v1, vv = v1;
      int gj = jt * 64 + row;
      if (gj < Tn && cg < 6) {
        v1 = *reinterpret_cast<const u16x8*>(khb + (size_t)gj * 768 + hh1 * 48 + cg * 8);
        v2 = *reinterpret_cast<const u16x8*>(khb + (size_t)gj * 768 + hh2 * 48 + cg * 8);
      }
      int jc = jt * 64 + cg * 8;
      if (jc + 8 <= Tn)
        vv = *reinterpret_cast<const u16x8*>(vt + (size_t)row * Tn + jc);
      *reinterpret_cast<u16x8*>(&K1s[row][cg * 8]) = v1;
      *reinterpret_cast<u16x8*>(&K2s[row][cg * 8]) = v2;
      *reinterpret_cast<u16x8*>(&Bv[row][cg * 8]) = vv;
    }
    __syncthreads();
    f32x4 a1c[4] = {}, a2c[4] = {};
#pragma unroll
    for (int ks = 0; ks < 2; ks++) {
      bf16x8 af1 = *reinterpret_cast<const bf16x8*>(&Q1[wave * 16 + lrow][ks * 32 + lgrp * 8]);
      bf16x8 af2 = *reinterpret_cast<const bf16x8*>(&Q2[wave * 16 + lrow][ks * 32 + lgrp * 8]);
#pragma unroll
      for (int ni = 0; ni < 4; ni++) {
        bf16x8 b1 = *reinterpret_cast<const bf16x8*>(&K1s[ni * 16 + lrow][ks * 32 + lgrp * 8]);
        bf16x8 b2 = *reinterpret_cast<const bf16x8*>(&K2s[ni * 16 + lrow][ks * 32 + lgrp * 8]);
        a1c[ni] = __builtin_amdgcn_mfma_f32_16x16x32_bf16(af1, b1, a1c[ni], 0, 0, 0);
        a2c[ni] = __builtin_amdgcn_mfma_f32_16x16x32_bf16(af2, b2, a2c[ni], 0, 0, 0);
      }
    }
    __syncthreads();            // all K1s reads done before Ps (alias) writes
    float cs[4];
#pragma unroll
    for (int ni = 0; ni < 4; ni++) cs[ni] = 0.f;
#pragma unroll
    for (int ni = 0; ni < 4; ni++) {
      int j = jt * 64 + ni * 16 + lrow;
      int jmod = j % LPn;
      bool jok = (j < Tn);
#pragma unroll
      for (int r = 0; r < 4; r++) {
        int imod = irow[r] % LPn;
        bool masked = (!jok) || (jmod > imod);
        float sv1 = masked ? -1e9f : a1c[ni][r] * SCALING_C;
        float sv2 = masked ? -1e9f : a2c[ni][r] * SCALING_C;
        float a1 = __expf(sv1 - m1[r]) * li1[r];
        float a2 = __expf(sv2 - m2[r]) * li2[r];
        float c = fmaf(-lam, a2, a1);
        Ps[wave * 16 + lgrp * 4 + r][ni * 16 + lrow] = f2bu(c);
        cs[ni] += a1;
      }
    }
#pragma unroll
    for (int ni = 0; ni < 4; ni++) {
      cs[ni] += __shfl_xor(cs[ni], 16);
      cs[ni] += __shfl_xor(cs[ni], 32);
    }
    {
      float mine = (lgrp == 0) ? cs[0] : (lgrp == 1) ? cs[1] : (lgrp == 2) ? cs[2] : cs[3];
      colsum_p[((size_t)p * 132 + blockIdx.x * 4 + wave) * TP + jt * 64 + lgrp * 16 + lrow] = mine;
    }
    __syncthreads();            // Ps writes visible to all waves
#pragma unroll
    for (int ks = 0; ks < 2; ks++) {
      bf16x8 af = *reinterpret_cast<const bf16x8*>(&Ps[wave * 16 + lrow][ks * 32 + lgrp * 8]);
#pragma unroll
      for (int ni = 0; ni < 4; ni++) {
        bf16x8 bfr = *reinterpret_cast<const bf16x8*>(&Bv[ni * 16 + lrow][ks * 32 + lgrp * 8]);
        accpv[ni] = __builtin_amdgcn_mfma_f32_16x16x32_bf16(af, bfr, accpv[ni], 0, 0, 0);
      }
    }
  }
#pragma unroll
  for (int ni = 0; ni < 4; ni++)
#pragma unroll
    for (int r = 0; r < 4; r++) {
      int row = bm + wave * 16 + lgrp * 4 + r;
      int col = ni * 16 + lrow;
      if (row < Tn) opv[((size_t)(hf * 8 + p) * Tn + row) * 64 + col] = accpv[ni][r];
    }
}

// ---------------- batched gwv: W[p][jmod][dv] ----------------
__global__ __launch_bounds__(64) void k_gwv(const float* __restrict__ colsum_p,
                                            const __hip_bfloat16* __restrict__ vtb,
                                            const float* __restrict__ lamp,
                                            float* __restrict__ Wb) {
  int jmod = blockIdx.x, p = blockIdx.y;
  int l = threadIdx.x;
  int k = l >> 3, sub = l & 7;
  int jk = jmod + 257 * k;
  float s = 0.f;
  for (int ib = sub; ib < 132; ib += 8) s += colsum_p[((size_t)p * 132 + ib) * TP + jk];
  for (int m = 1; m < 8; m <<= 1) s += __shfl_xor(s, m);
  float gv = s * (1.f / (float)Tn) * lamp[0];
  const __hip_bfloat16* vrow = vtb + (size_t)(p * 64 + l) * Tn;
  float acc = 0.f;
#pragma unroll
  for (int kk = 0; kk < 8; kk++) {
    float gk = __shfl(gv, kk * 8);
    acc = fmaf(gk, __bfloat162float(vrow[jmod + 257 * kk]), acc);
  }
  Wb[((size_t)p * 257 + jmod) * 64 + l] = acc;
}

// ---------------- batched chunksum ----------------
__global__ __launch_bounds__(64) void k_chunksum(const float* __restrict__ Wb,
                                                 float* __restrict__ Cb) {
  int c = blockIdx.x, p = blockIdx.y;
  int lane = threadIdx.x;
  int m0 = c * 16, m1 = min(m0 + 16, LPn);
  float acc = 0.f;
  for (int m = m0; m < m1; m++) acc += Wb[((size_t)p * 257 + m) * 64 + lane];
  Cb[((size_t)p * 17 + c) * 64 + lane] = acc;
}

// ---------------- pv_out: sum 4 opv parts + G-prefix + head-RMSNorm -> bf16 ----------------
__global__ __launch_bounds__(256) void k_pv_out(const float* __restrict__ opv,
                                                const float* __restrict__ Wb,
                                                const float* __restrict__ Cb,
                                                const float* __restrict__ hnw,
                                                __hip_bfloat16* __restrict__ onormb) {
  int w = threadIdx.x >> 6, lane = threadIdx.x & 63;
  int i = blockIdx.x * 4 + w;
  int p = blockIdx.y;
  int imod = i % LPn;
  int cidx = imod >> 4;
  float s = 0.f;
#pragma unroll
  for (int hf = 0; hf < 4; hf++) s += opv[((size_t)(hf * 8 + p) * Tn + i) * 64 + lane];
  for (int c = 0; c < cidx; c++) s += Cb[((size_t)p * 17 + c) * 64 + lane];
  for (int m = cidx * 16; m <= imod; m++) s += Wb[((size_t)p * 257 + m) * 64 + lane];
  float ss = s * s;
  for (int off = 1; off < 64; off <<= 1) ss += __shfl_xor(ss, off);
  float scale = rsqrtf(ss * (1.f / 64.f) + 1e-5f);
  onormb[((size_t)p * Tn + i) * 64 + lane] = __float2bfloat16(s * scale * hnw[lane]);
}

// ---------------- final head (float32 out) ----------------
__global__ __launch_bounds__(192) void k_final(const float* __restrict__ z,
                                               const float* __restrict__ outW,
                                               float* __restrict__ out) {
  int t = blockIdx.x;
  int p = threadIdx.x >> 6, lane = threadIdx.x & 63;
  float acc = 0.f;
  for (int m = lane; m < 512; m += 64) acc = fmaf(z[(size_t)t * 512 + m], outW[(size_t)p * 512 + m], acc);
  for (int off = 1; off < 64; off <<= 1) acc += __shfl_xor(acc, off);
  if (lane == 0) out[(size_t)t * 3 + p] = acc;
}

extern "C" void kernel_launch(void* const* d_in, const int* in_sizes, int n_in,
                              void* d_out, int out_size, void* d_ws, size_t ws_size,
                              hipStream_t stream) {
  const float* x          = (const float*)d_in[0];
  const float* ticker_emb = (const float*)d_in[1];
  const float* sep_emb    = (const float*)d_in[2];
  const float* shared_W   = (const float*)d_in[3];
  const float* unique_W   = (const float*)d_in[4];
  const float* norm1_w    = (const float*)d_in[5];
  const float* norm2_w    = (const float*)d_in[6];
  const float* kv_down_W  = (const float*)d_in[7];
  const float* q_down_W   = (const float*)d_in[8];
  const float* kv_up_W    = (const float*)d_in[9];
  const float* q_up_W     = (const float*)d_in[10];
  const float* kv_norm_w  = (const float*)d_in[11];
  const float* q_norm_w   = (const float*)d_in[12];
  const float* o_W        = (const float*)d_in[13];
  const float* lam_q1     = (const float*)d_in[14];
  const float* lam_k1     = (const float*)d_in[15];
  const float* lam_q2     = (const float*)d_in[16];
  const float* lam_k2     = (const float*)d_in[17];
  const float* head_norm_w= (const float*)d_in[18];
  const float* ff_in_W    = (const float*)d_in[19];
  const float* ff_out_W   = (const float*)d_in[20];
  const float* final_norm = (const float*)d_in[21];
  const float* out_W      = (const float*)d_in[22];
  const int*   seperator  = (const int*)d_in[23];
  const int*   tickers    = (const int*)d_in[24];
  (void)in_sizes; (void)n_in;

  float* W = (float*)d_ws;
  size_t off = 0;
  auto alloc = [&](size_t n) { float* p = W + off; off += n; return p; };
  float* cosb  = alloc(2048);
  float* sinb  = alloc(2048);
  float* h     = alloc((size_t)Tn * Dn);
  float* xnb_f = alloc((size_t)Tn * 256);         // bf16 T x 512 (also z)
  float* ckv   = alloc((size_t)Tn * 160);         // ckv+qlat host onormb later
  float* qlat  = alloc((size_t)Tn * 192);
  float* ckvnb_f = alloc((size_t)Tn * 64);        // bf16 T x 128
  float* qlatnb_f = alloc((size_t)Tn * 96);       // bf16 T x 192
  float* kvb   = alloc((size_t)Tn * 1024);        // gatedb overlay
  float* qf    = alloc((size_t)Tn * 768);         // zfin overlay
  float* qhb_f = alloc((size_t)Tn * 384);         // bf16 T x 768
  float* khb_f = alloc((size_t)Tn * 384);         // bf16 T x 768
  float* vtb_f = alloc((size_t)Tn * 256);         // bf16 512 x T
  float* mrow  = alloc((size_t)64 * TP);          // [4 quarters][16 heads][TP]
  float* lsumb = alloc((size_t)64 * TP);
  float* lam   = alloc(4);
  float* colsum_p = alloc((size_t)8 * 132 * TP);
  float* Wb    = alloc((size_t)8 * 257 * 64);
  float* Cb    = alloc((size_t)8 * 17 * 64);
  float* pp    = alloc((size_t)4 * Tn * 512);     // opv (4x8xTx64) / GEMM partials

  __hip_bfloat16* xnb    = (__hip_bfloat16*)xnb_f;
  __hip_bfloat16* ckvnb  = (__hip_bfloat16*)ckvnb_f;
  __hip_bfloat16* qlatnb = (__hip_bfloat16*)qlatnb_f;
  __hip_bfloat16* onormb = (__hip_bfloat16*)ckv;     // bf16 T x 512 over ckv+qlat
  __hip_bfloat16* gatedb = (__hip_bfloat16*)kvb;     // bf16 T x 2048
  __hip_bfloat16* qhb    = (__hip_bfloat16*)qhb_f;
  __hip_bfloat16* khb    = (__hip_bfloat16*)khb_f;
  __hip_bfloat16* vtb    = (__hip_bfloat16*)vtb_f;
  float* opv   = pp;         // 4x8xTx64 f32 == 4xTx512 f32 exactly (disjoint lifetime)
  float* zfin  = qf;

  size_t needed = off * sizeof(float);            // ~61 MB (< 79.5 proven)
  if (ws_size < needed) {
    k_fill42<<<(out_size + 255) / 256, 256, 0, stream>>>((float*)d_out, out_size);
    return;
  }

  k_freqs<<<8, 256, 0, stream>>>(cosb, sinb);
  k_embed<<<dim3(Tn, 2), 256, 0, stream>>>(x, ticker_emb, sep_emb, shared_W, unique_W,
                                           seperator, tickers, h);

  for (int d = 0; d < 2; d++) {
    const float* n1   = norm1_w + d * 512;
    const float* n2   = norm2_w + d * 512;
    const float* kvd  = kv_down_W + (size_t)d * 160 * 512;
    const float* qd   = q_down_W + (size_t)d * 192 * 512;
    const float* kvu  = kv_up_W + (size_t)d * 1024 * 128;
    const float* qu   = q_up_W + (size_t)d * 768 * 192;
    const float* kvnw = kv_norm_w + d * 128;
    const float* qnw  = q_norm_w + d * 192;
    const float* oW   = o_W + (size_t)d * 512 * 512;
    const float* hnw  = head_norm_w + d * 64;
    const float* ffi  = ff_in_W + (size_t)d * 4096 * 512;
    const float* ffo  = ff_out_W + (size_t)d * 512 * 2048;
    float lamc = 0.8f - 0.6f * expf(-0.3f * (float)d);

    k_rmsnorm_b<<<Tn, 256, 0, stream>>>(h, n1, xnb, 512, 512, EPS_C);
    k_gemm64<0><<<dim3(3, 33), 256, 0, stream>>>(xnb, kvd, ckv, Tn, 160, 512);
    k_rmsnorm_b<<<Tn, 256, 0, stream>>>(ckv, kvnw, ckvnb, 128, 160, EPS_C);
    k_gemm64<0><<<dim3(16, 33), 256, 0, stream>>>(ckvnb, kvu, kvb, Tn, 1024, 128);
    k_gemm64<0><<<dim3(3, 33), 256, 0, stream>>>(xnb, qd, qlat, Tn, 192, 512);
    k_rmsnorm_b<<<Tn, 256, 0, stream>>>(qlat, qnw, qlatnb, 192, 192, EPS_C);
    k_gemm64<0><<<dim3(12, 33), 256, 0, stream>>>(qlatnb, qu, qf, Tn, 768, 192);
    k_qkv<<<Tn, 256, 0, stream>>>(qf, kvb, ckv, cosb, sinb, qhb, khb);
    k_vtrans<<<dim3(33, 8), 256, 0, stream>>>(kvb, vtb);
    k_lam<<<1, 1, 0, stream>>>(lam_q1 + d * 32, lam_k1 + d * 32,
                               lam_q2 + d * 32, lam_k2 + d * 32, lamc, lam);

    k_attn_pass1<<<dim3(33, 8, 4), 256, 0, stream>>>(qhb, khb, mrow, lsumb);
    k_attn_pass2<<<dim3(33, 8, 4), 256, 0, stream>>>(qhb, khb, vtb, mrow, lsumb, lam,
                                                     opv, colsum_p);
    k_gwv<<<dim3(257, 8), 64, 0, stream>>>(colsum_p, vtb, lam, Wb);
    k_chunksum<<<dim3(17, 8), 64, 0, stream>>>(Wb, Cb);
    k_pv_out<<<dim3(514, 8), 256, 0, stream>>>(opv, Wb, Cb, hnw, onormb);

    // o-proj: K=512 split x2 -> partials -> fused h += & rmsnorm(n2) -> xnb
    k_gemm64p<<<dim3(8, 33, 2), 256, 0, stream>>>(onormb, oW, pp, Tn, 512, 256);
    k_addred_rms_b<<<Tn, 256, 0, stream>>>(h, pp, n2, xnb, 2);
    k_ffn<<<dim3(32, 17), 256, 0, stream>>>(xnb, ffi, gatedb);
    // ffo: K=2048 split x4 -> partials -> h +=
    k_gemm64p<<<dim3(8, 33, 4), 256, 0, stream>>>(gatedb, ffo, pp, Tn, 512, 512);
    k_addred<<<(Tn * 512 + 255) / 256, 256, 0, stream>>>(h, pp, (long)Tn * 512, 4);
  }

  k_rmsnorm<<<Tn, 256, 0, stream>>>(h, final_norm, zfin, 512, 512, EPS_C);
  k_final<<<Tn, 192, 0, stream>>>(zfin, out_W, (float*)d_out);
}